// Round 2
// baseline (16944.928 us; speedup 1.0000x reference)
//
#include <hip/hip_runtime.h>
#include <hip/hip_bf16.h>
#include <math.h>

#define NUM_LAYERS 4
#define D_MODEL 768
#define D_STATE 128
#define D_CONV 4
#define HEADDIM 64
#define D_INNER 1536
#define NHEADS 24
#define CONV_DIM 1792
#define D_PROJ 3352
#define BATCH 4
#define SEQ 2048
#define NROWS (BATCH*SEQ)   /* 8192 */

__device__ __forceinline__ float warp_reduce_sum(float v) {
  v += __shfl_xor(v, 32);
  v += __shfl_xor(v, 16);
  v += __shfl_xor(v, 8);
  v += __shfl_xor(v, 4);
  v += __shfl_xor(v, 2);
  v += __shfl_xor(v, 1);
  return v;
}

// -------------------- rmsnorm over 768 (layer input norm + final norm) ------
__global__ __launch_bounds__(256) void rmsnorm768_kernel(
    const float* __restrict__ in, const float* __restrict__ w,
    float* __restrict__ out, float eps) {
  int row = blockIdx.x;
  const float* x = in + (size_t)row * D_MODEL;
  float* o = out + (size_t)row * D_MODEL;
  int t = threadIdx.x;
  float v0 = x[t], v1 = x[t + 256], v2 = x[t + 512];
  float ss = v0 * v0 + v1 * v1 + v2 * v2;
  __shared__ float sred[4];
  ss = warp_reduce_sum(ss);
  if ((t & 63) == 0) sred[t >> 6] = ss;
  __syncthreads();
  float tot = sred[0] + sred[1] + sred[2] + sred[3];
  float inv = rsqrtf(tot / (float)D_MODEL + eps);
  o[t] = w[t] * v0 * inv;
  o[t + 256] = w[t + 256] * v1 * inv;
  o[t + 512] = w[t + 512] * v2 * inv;
}

// -------------------- fp32 GEMM: C[M][N] = A[M][K] * W[N][K]^T (+res) -------
#define BM 128
#define BN 64
#define BK 16

__global__ __launch_bounds__(256) void gemm_nt_kernel(
    const float* __restrict__ A, const float* __restrict__ W,
    const float* __restrict__ res, float* __restrict__ C,
    int M, int N, int K) {
  __shared__ float As[BK][BM];
  __shared__ float Ws[BK][BN];
  int tid = threadIdx.x;
  int tx = tid & 15;   // n sub-tile
  int ty = tid >> 4;   // m sub-tile
  int m0 = blockIdx.x * BM;
  int n0 = blockIdx.y * BN;
  int ar = tid >> 1;
  int ac = (tid & 1) * 8;
  int wr = tid >> 2;
  int wc = (tid & 3) * 4;
  const float* Aptr = A + (size_t)(m0 + ar) * K + ac;
  bool wvalid = (n0 + wr) < N;
  const float* Wptr = W + (size_t)(n0 + wr) * K + wc;

  float acc[8][4];
#pragma unroll
  for (int i = 0; i < 8; i++)
#pragma unroll
    for (int j = 0; j < 4; j++) acc[i][j] = 0.f;

  for (int k0 = 0; k0 < K; k0 += BK) {
    float4 a0 = *(const float4*)(Aptr + k0);
    float4 a1 = *(const float4*)(Aptr + k0 + 4);
    float4 wv = wvalid ? *(const float4*)(Wptr + k0) : make_float4(0.f, 0.f, 0.f, 0.f);
    As[ac + 0][ar] = a0.x; As[ac + 1][ar] = a0.y; As[ac + 2][ar] = a0.z; As[ac + 3][ar] = a0.w;
    As[ac + 4][ar] = a1.x; As[ac + 5][ar] = a1.y; As[ac + 6][ar] = a1.z; As[ac + 7][ar] = a1.w;
    Ws[wc + 0][wr] = wv.x; Ws[wc + 1][wr] = wv.y; Ws[wc + 2][wr] = wv.z; Ws[wc + 3][wr] = wv.w;
    __syncthreads();
#pragma unroll
    for (int k = 0; k < BK; k++) {
      float4 av0 = *(const float4*)&As[k][ty * 4];
      float4 av1 = *(const float4*)&As[k][64 + ty * 4];
      float4 bv  = *(const float4*)&Ws[k][tx * 4];
      float am[8] = {av0.x, av0.y, av0.z, av0.w, av1.x, av1.y, av1.z, av1.w};
      float bm[4] = {bv.x, bv.y, bv.z, bv.w};
#pragma unroll
      for (int i = 0; i < 8; i++)
#pragma unroll
        for (int j = 0; j < 4; j++)
          acc[i][j] = fmaf(am[i], bm[j], acc[i][j]);
    }
    __syncthreads();
  }

#pragma unroll
  for (int i = 0; i < 8; i++) {
    int m = m0 + ((i < 4) ? (ty * 4 + i) : (64 + ty * 4 + (i - 4)));
#pragma unroll
    for (int j = 0; j < 4; j++) {
      int n = n0 + tx * 4 + j;
      if (n < N) {
        float v = acc[i][j];
        if (res) v += res[(size_t)m * N + n];
        C[(size_t)m * N + n] = v;
      }
    }
  }
}

// ---- SSD scan with FUSED causal conv(k=4)+bias+silu: one block per (b,head)
// Channels per block: 64 x-channels (this head) + 128 B + 128 C = 320.
// 4-deep LDS ring buffer holds raw xBC rows s-3..s; conv computed per step.
__global__ __launch_bounds__(256) void ssd_scan_kernel(
    const float* __restrict__ zx, const float* __restrict__ cw,
    const float* __restrict__ cb, const float* __restrict__ dt_bias,
    const float* __restrict__ A_log, const float* __restrict__ D_skip,
    float* __restrict__ y) {
  int b = blockIdx.x / NHEADS;
  int hd = blockIdx.x % NHEADS;
  int t = threadIdx.x;
  int p = t >> 2;   // headdim index 0..63
  int nq = t & 3;   // n-quarter: n in [nq*32, nq*32+32)
  float Ah = -expf(A_log[hd]);
  float dtb = dt_bias[hd];
  float Dh = D_skip[hd];

  __shared__ float ring[4][320];   // raw (pre-conv) xBC rows, slot = s & 3
  __shared__ float lcw[4][320];    // conv weights, [tap][chan] (conflict-free)
  __shared__ float lcb[320];
  __shared__ float4 sB[32];
  __shared__ float4 sC[32];
  __shared__ float sx[64];
  __shared__ float sdt[2];
  float* sBf = (float*)sB;
  float* sCf = (float*)sC;

  // stage conv weights/bias for this block's 320 channels
  for (int c = t; c < 320; c += 256) {
    int g = (c < 64) ? (hd * HEADDIM + c) : (D_INNER + (c - 64));
    lcb[c] = cb[g];
#pragma unroll
    for (int k = 0; k < 4; k++) lcw[k][c] = cw[g * 4 + k];
  }
  // zero ring (conv zero-padding for s<0)
  for (int i = t; i < 4 * 320; i += 256) ((float*)ring)[i] = 0.f;

  float h[32];
#pragma unroll
  for (int i = 0; i < 32; i++) h[i] = 0.f;

  const float* zxb = zx + (size_t)b * SEQ * D_PROJ;
  const float* dtp = zxb + D_INNER + CONV_DIM + hd;
  float* yrow = y + (size_t)b * SEQ * D_INNER + hd * HEADDIM;

  __syncthreads();  // weights + ring zero visible

  for (int s = 0; s < SEQ; s++) {
    // phase 1: load raw row s into ring slot s&3 (two contiguous segments)
    const float* row = zxb + (size_t)s * D_PROJ + D_INNER;
    int slot = s & 3;
    ring[slot][64 + t] = row[D_INNER + t];               // B then C (256 ch)
    if (t < 64) ring[slot][t] = row[hd * HEADDIM + t];   // x for this head
    if (t == 0) {
      float raw = dtp[(size_t)s * D_PROJ] + dtb;
      sdt[s & 1] = (raw > 20.f) ? raw : log1pf(expf(raw));  // softplus
    }
    __syncthreads();

    // phase 2: conv + silu for channel t (and 256+t for t<64)
    {
      float a0 = lcb[t];
#pragma unroll
      for (int k = 0; k < 4; k++)   // tap k reads row s-3+k -> slot (s+k+1)&3
        a0 = fmaf(ring[(s + k + 1) & 3][t], lcw[k][t], a0);
      a0 = a0 / (1.f + expf(-a0));
      if (t < 64) sx[t] = a0;
      else if (t < 192) sBf[t - 64] = a0;
      else sCf[t - 192] = a0;
      if (t < 64) {
        int c2 = 256 + t;
        float a2 = lcb[c2];
#pragma unroll
        for (int k = 0; k < 4; k++)
          a2 = fmaf(ring[(s + k + 1) & 3][c2], lcw[k][c2], a2);
        a2 = a2 / (1.f + expf(-a2));
        sCf[c2 - 192] = a2;
      }
    }
    __syncthreads();

    // phase 3: scan update (h state in registers, 32 per thread)
    float dt = sdt[s & 1];
    float dA = expf(dt * Ah);
    float xv = sx[p];
    float dtx = dt * xv;
    float acc = 0.f;
#pragma unroll
    for (int i4 = 0; i4 < 8; i4++) {
      int sl = (i4 + nq * 2) & 7;  // rotated quad -> bank-conflict-free
      float4 bv = sB[nq * 8 + sl];
      float4 cv = sC[nq * 8 + sl];
      float* hp = &h[i4 * 4];      // h[i4] consistently holds quad sl's state
      hp[0] = fmaf(dA, hp[0], dtx * bv.x); acc = fmaf(hp[0], cv.x, acc);
      hp[1] = fmaf(dA, hp[1], dtx * bv.y); acc = fmaf(hp[1], cv.y, acc);
      hp[2] = fmaf(dA, hp[2], dtx * bv.z); acc = fmaf(hp[2], cv.z, acc);
      hp[3] = fmaf(dA, hp[3], dtx * bv.w); acc = fmaf(hp[3], cv.w, acc);
    }
    acc += __shfl_xor(acc, 1);
    acc += __shfl_xor(acc, 2);
    if (nq == 0) yrow[(size_t)s * D_INNER + p] = acc + Dh * xv;
  }
}

// -------------------- y * silu(z) then rmsnorm(1536) w/ gnorm_w ------------
__global__ __launch_bounds__(256) void gate_norm_kernel(
    float* __restrict__ y, const float* __restrict__ zx,
    const float* __restrict__ gw) {
  int row = blockIdx.x;
  const float* z = zx + (size_t)row * D_PROJ;
  float* yr = y + (size_t)row * D_INNER;
  int t = threadIdx.x;
  float vals[6];
  float ss = 0.f;
#pragma unroll
  for (int j = 0; j < 6; j++) {
    int c = t + j * 256;
    float zv = z[c];
    float v = yr[c] * (zv / (1.f + expf(-zv)));
    vals[j] = v;
    ss += v * v;
  }
  __shared__ float sred[4];
  ss = warp_reduce_sum(ss);
  if ((t & 63) == 0) sred[t >> 6] = ss;
  __syncthreads();
  float tot = sred[0] + sred[1] + sred[2] + sred[3];
  float inv = rsqrtf(tot / (float)D_INNER + 1e-5f);
#pragma unroll
  for (int j = 0; j < 6; j++) {
    int c = t + j * 256;
    yr[c] = gw[c] * vals[j] * inv;
  }
}

// ---------------------------------------------------------------------------
extern "C" void kernel_launch(void* const* d_in, const int* in_sizes, int n_in,
                              void* d_out, int out_size, void* d_ws, size_t ws_size,
                              hipStream_t stream) {
  const float* x          = (const float*)d_in[0];
  const float* in_proj_w  = (const float*)d_in[1];
  const float* conv_w     = (const float*)d_in[2];
  const float* conv_b     = (const float*)d_in[3];
  const float* dt_bias    = (const float*)d_in[4];
  const float* A_log      = (const float*)d_in[5];
  const float* D_skip     = (const float*)d_in[6];
  const float* gnorm_w    = (const float*)d_in[7];
  const float* out_proj_w = (const float*)d_in[8];
  const float* ln_w       = (const float*)d_in[9];
  const float* final_ln_w = (const float*)d_in[10];

  // ws usage: 25.2 + 25.2 + 109.8 + 50.3 = 210.5 MB (was 269.2 -> overflow)
  float* ws = (float*)d_ws;
  float* curx  = ws; ws += (size_t)NROWS * D_MODEL;
  float* hbuf  = ws; ws += (size_t)NROWS * D_MODEL;
  float* zxbuf = ws; ws += (size_t)NROWS * D_PROJ;
  float* ybuf  = ws; ws += (size_t)NROWS * D_INNER;

  for (int l = 0; l < NUM_LAYERS; l++) {
    const float* xin = (l == 0) ? x : curx;
    rmsnorm768_kernel<<<NROWS, 256, 0, stream>>>(
        xin, ln_w + (size_t)l * D_MODEL, hbuf, 1e-6f);

    dim3 g1(NROWS / BM, (D_PROJ + BN - 1) / BN);
    gemm_nt_kernel<<<g1, 256, 0, stream>>>(
        hbuf, in_proj_w + (size_t)l * D_PROJ * D_MODEL, nullptr, zxbuf,
        NROWS, D_PROJ, D_MODEL);

    ssd_scan_kernel<<<BATCH * NHEADS, 256, 0, stream>>>(
        zxbuf, conv_w + (size_t)l * CONV_DIM * D_CONV,
        conv_b + (size_t)l * CONV_DIM, dt_bias + l * NHEADS,
        A_log + l * NHEADS, D_skip + l * NHEADS, ybuf);

    gate_norm_kernel<<<NROWS, 256, 0, stream>>>(
        ybuf, zxbuf, gnorm_w + (size_t)l * D_INNER);

    dim3 g2(NROWS / BM, D_MODEL / BN);
    gemm_nt_kernel<<<g2, 256, 0, stream>>>(
        ybuf, out_proj_w + (size_t)l * D_MODEL * D_INNER, xin, curx,
        NROWS, D_MODEL, D_INNER);
  }
  rmsnorm768_kernel<<<NROWS, 256, 0, stream>>>(
      curx, final_ln_w, (float*)d_out, 1e-6f);
}

// Round 3
// 7108.992 us; speedup vs baseline: 2.3836x; 2.3836x over previous
//
#include <hip/hip_runtime.h>
#include <hip/hip_bf16.h>
#include <math.h>

#define NUM_LAYERS 4
#define D_MODEL 768
#define D_STATE 128
#define D_CONV 4
#define HEADDIM 64
#define D_INNER 1536
#define NHEADS 24
#define CONV_DIM 1792
#define D_PROJ 3352
#define BATCH 4
#define SEQ 2048
#define NROWS (BATCH*SEQ)   /* 8192 */
#define CHUNK 128
#define NCHUNK (SEQ/CHUNK)  /* 16 */

__device__ __forceinline__ float warp_reduce_sum(float v) {
  v += __shfl_xor(v, 32);
  v += __shfl_xor(v, 16);
  v += __shfl_xor(v, 8);
  v += __shfl_xor(v, 4);
  v += __shfl_xor(v, 2);
  v += __shfl_xor(v, 1);
  return v;
}

__device__ __forceinline__ float softplusf(float x) {
  return (x > 20.f) ? x : log1pf(expf(x));
}
__device__ __forceinline__ float siluf(float x) {
  return x / (1.f + expf(-x));
}

// -------------------- rmsnorm over 768 ------------------------------------
__global__ __launch_bounds__(256) void rmsnorm768_kernel(
    const float* __restrict__ in, const float* __restrict__ w,
    float* __restrict__ out, float eps) {
  int row = blockIdx.x;
  const float* x = in + (size_t)row * D_MODEL;
  float* o = out + (size_t)row * D_MODEL;
  int t = threadIdx.x;
  float v0 = x[t], v1 = x[t + 256], v2 = x[t + 512];
  float ss = v0 * v0 + v1 * v1 + v2 * v2;
  __shared__ float sred[4];
  ss = warp_reduce_sum(ss);
  if ((t & 63) == 0) sred[t >> 6] = ss;
  __syncthreads();
  float tot = sred[0] + sred[1] + sred[2] + sred[3];
  float inv = rsqrtf(tot / (float)D_MODEL + eps);
  o[t] = w[t] * v0 * inv;
  o[t + 256] = w[t + 256] * v1 * inv;
  o[t + 512] = w[t + 512] * v2 * inv;
}

// -------------------- fp32 GEMM: C[M][N] = A[M][K] * W[N][K]^T (+res) ------
#define BM 128
#define BN 64
#define BK 16

__global__ __launch_bounds__(256) void gemm_nt_kernel(
    const float* __restrict__ A, const float* __restrict__ W,
    const float* __restrict__ res, float* __restrict__ C,
    int M, int N, int K) {
  __shared__ float As[BK][BM];
  __shared__ float Ws[BK][BN];
  int tid = threadIdx.x;
  int tx = tid & 15;
  int ty = tid >> 4;
  int m0 = blockIdx.x * BM;
  int n0 = blockIdx.y * BN;
  int ar = tid >> 1;
  int ac = (tid & 1) * 8;
  int wr = tid >> 2;
  int wc = (tid & 3) * 4;
  const float* Aptr = A + (size_t)(m0 + ar) * K + ac;
  bool wvalid = (n0 + wr) < N;
  const float* Wptr = W + (size_t)(n0 + wr) * K + wc;

  float acc[8][4];
#pragma unroll
  for (int i = 0; i < 8; i++)
#pragma unroll
    for (int j = 0; j < 4; j++) acc[i][j] = 0.f;

  for (int k0 = 0; k0 < K; k0 += BK) {
    float4 a0 = *(const float4*)(Aptr + k0);
    float4 a1 = *(const float4*)(Aptr + k0 + 4);
    float4 wv = wvalid ? *(const float4*)(Wptr + k0) : make_float4(0.f, 0.f, 0.f, 0.f);
    As[ac + 0][ar] = a0.x; As[ac + 1][ar] = a0.y; As[ac + 2][ar] = a0.z; As[ac + 3][ar] = a0.w;
    As[ac + 4][ar] = a1.x; As[ac + 5][ar] = a1.y; As[ac + 6][ar] = a1.z; As[ac + 7][ar] = a1.w;
    Ws[wc + 0][wr] = wv.x; Ws[wc + 1][wr] = wv.y; Ws[wc + 2][wr] = wv.z; Ws[wc + 3][wr] = wv.w;
    __syncthreads();
#pragma unroll
    for (int k = 0; k < BK; k++) {
      float4 av0 = *(const float4*)&As[k][ty * 4];
      float4 av1 = *(const float4*)&As[k][64 + ty * 4];
      float4 bv  = *(const float4*)&Ws[k][tx * 4];
      float am[8] = {av0.x, av0.y, av0.z, av0.w, av1.x, av1.y, av1.z, av1.w};
      float bm[4] = {bv.x, bv.y, bv.z, bv.w};
#pragma unroll
      for (int i = 0; i < 8; i++)
#pragma unroll
        for (int j = 0; j < 4; j++)
          acc[i][j] = fmaf(am[i], bm[j], acc[i][j]);
    }
    __syncthreads();
  }

#pragma unroll
  for (int i = 0; i < 8; i++) {
    int m = m0 + ((i < 4) ? (ty * 4 + i) : (64 + ty * 4 + (i - 4)));
#pragma unroll
    for (int j = 0; j < 4; j++) {
      int n = n0 + tx * 4 + j;
      if (n < N) {
        float v = acc[i][j];
        if (res) v += res[(size_t)m * N + n];
        C[(size_t)m * N + n] = v;
      }
    }
  }
}

// ======================= chunked SSD scan ==================================
// Per (b,h): h_s = exp(dt_s*A) h_{s-1} + dt_s x_s B_s^T ;  y_s = C_s.h_s + D x_s
// Chunk L=128: H_c[p,n] = sum_tau exp(cumA_L - cumA_tau) dt_tau x[tau,p] B[tau,n]
//   h_end(c) = exp(totalA_c) h_end(c-1) + H_c
//   y_t = sum_{tau<=t} exp(cumA_t - cumA_tau) dt_tau (C_t.B_tau) x[tau,p]
//         + exp(cumA_t) (C_t . h_prev[p,:]) + D x[t,p]
// conv(k=4)+silu on x/B/C is recomputed per chunk from raw zx rows.

// ---- kernel A1: per-chunk state contribution H_c (and totalA_c) ----------
__global__ __launch_bounds__(256) void ssd_state_kernel(
    const float* __restrict__ zx, const float* __restrict__ cw,
    const float* __restrict__ cb, const float* __restrict__ dt_bias,
    const float* __restrict__ A_log, float* __restrict__ states,
    float* __restrict__ statesA) {
  __shared__ float lds[25856];          // 103.4 KB
  float* Bs   = lds;                    // [128][132]
  float* xs   = lds + 16896;            // [128][68]  (x scaled by wdt)
  float* swdt = lds + 25600;            // [128]
  float* scan = lds + 25728;            // [128]
  int t  = threadIdx.x;
  int c  = blockIdx.x & (NCHUNK - 1);
  int h  = (blockIdx.x / NCHUNK) % NHEADS;
  int b  = blockIdx.x / (NCHUNK * NHEADS);
  int s0 = c * CHUNK;
  const float* zxb = zx + (size_t)b * SEQ * D_PROJ;
  float Ah  = -expf(A_log[h]);
  float dtb = dt_bias[h];

  if (t < 128) {
    float raw = zxb[(size_t)(s0 + t) * D_PROJ + (D_INNER + CONV_DIM) + h] + dtb;
    float dt = softplusf(raw);
    swdt[t] = dt;
    scan[t] = dt * Ah;
  }
  __syncthreads();
  for (int off = 1; off < 128; off <<= 1) {
    float v = 0.f;
    if (t >= off && t < 128) v = scan[t - off];
    __syncthreads();
    if (t < 128) scan[t] += v;
    __syncthreads();
  }
  float total = scan[127];
  if (t < 128) swdt[t] *= expf(total - scan[t]);
  __syncthreads();

  // conv+silu B -> Bs[r][ch]
  for (int e = t; e < 128 * 128; e += 256) {
    int r = e >> 7, ch = e & 127;
    int gc = D_INNER + ch;        // conv channel
    int col = D_INNER + gc;       // zx column
    float a = cb[gc];
#pragma unroll
    for (int k = 0; k < 4; k++) {
      int ss = s0 + r - 3 + k;
      float rv = (ss >= 0) ? zxb[(size_t)ss * D_PROJ + col] : 0.f;
      a = fmaf(rv, cw[gc * 4 + k], a);
    }
    Bs[r * 132 + ch] = siluf(a);
  }
  // conv+silu x -> xs[r][ch] * wdt[r]
  for (int e = t; e < 128 * 64; e += 256) {
    int r = e >> 6, ch = e & 63;
    int gc = h * 64 + ch;
    int col = D_INNER + gc;
    float a = cb[gc];
#pragma unroll
    for (int k = 0; k < 4; k++) {
      int ss = s0 + r - 3 + k;
      float rv = (ss >= 0) ? zxb[(size_t)ss * D_PROJ + col] : 0.f;
      a = fmaf(rv, cw[gc * 4 + k], a);
    }
    xs[r * 68 + ch] = swdt[r] * siluf(a);
  }
  __syncthreads();

  // GEMM: H[p][n] = sum_tau xs[tau][p] * Bs[tau][n]   (p: ty*4+i, n: tx+16q)
  int tx = t & 15, ty = t >> 4;
  int p0 = ty * 4;
  float acc[4][8];
#pragma unroll
  for (int i = 0; i < 4; i++)
#pragma unroll
    for (int q = 0; q < 8; q++) acc[i][q] = 0.f;

  for (int tau = 0; tau < 128; tau++) {
    float4 xv = *(const float4*)&xs[tau * 68 + p0];
    float bv[8];
#pragma unroll
    for (int q = 0; q < 8; q++) bv[q] = Bs[tau * 132 + tx + 16 * q];
    float xa[4] = {xv.x, xv.y, xv.z, xv.w};
#pragma unroll
    for (int i = 0; i < 4; i++)
#pragma unroll
      for (int q = 0; q < 8; q++)
        acc[i][q] = fmaf(xa[i], bv[q], acc[i][q]);
  }
  float* Hc = states + ((((size_t)b * NHEADS + h) * NCHUNK + c) << 13);
#pragma unroll
  for (int i = 0; i < 4; i++)
#pragma unroll
    for (int q = 0; q < 8; q++)
      Hc[(p0 + i) * 128 + tx + 16 * q] = acc[i][q];
  if (t == 0) statesA[(b * NHEADS + h) * NCHUNK + c] = total;
}

// ---- kernel B: inter-chunk scan; states[c] <- state entering chunk c -----
__global__ __launch_bounds__(256) void ssd_chunkscan_kernel(
    float* __restrict__ states, const float* __restrict__ statesA) {
  int bh = blockIdx.x;
  int t = threadIdx.x;
  float* st = states + (size_t)bh * NCHUNK * 8192;
  const float* sA = statesA + bh * NCHUNK;
  float hacc[32];
#pragma unroll
  for (int i = 0; i < 32; i++) hacc[i] = 0.f;
  for (int c = 0; c < NCHUNK; c++) {
    float eA = expf(sA[c]);
    float* p = st + (size_t)c * 8192;
#pragma unroll
    for (int i = 0; i < 32; i++) {
      float tmp = p[i * 256 + t];
      p[i * 256 + t] = hacc[i];
      hacc[i] = fmaf(eA, hacc[i], tmp);
    }
  }
}

// ---- kernel C: per-chunk output (intra via masked CB^T, inter via h_prev) -
__global__ __launch_bounds__(256) void ssd_output_kernel(
    const float* __restrict__ zx, const float* __restrict__ cw,
    const float* __restrict__ cb, const float* __restrict__ dt_bias,
    const float* __restrict__ A_log, const float* __restrict__ D_skip,
    const float* __restrict__ states, float* __restrict__ y) {
  __shared__ float lds[38784];          // 155.1 KB
  float* Cc  = lds;                     // [128][132]
  float* Bh  = lds + 16896;             // [64][132]  (later aliased as h_prev)
  float* Sh  = lds + 25344;             // [128][68]
  float* xh  = lds + 34048;             // [64][68]
  float* sdt = lds + 38400;             // [128]
  float* scum= lds + 38528;             // [128]
  float* sdec= lds + 38656;             // [128]
  int t  = threadIdx.x;
  int c  = blockIdx.x & (NCHUNK - 1);
  int h  = (blockIdx.x / NCHUNK) % NHEADS;
  int b  = blockIdx.x / (NCHUNK * NHEADS);
  int s0 = c * CHUNK;
  const float* zxb = zx + (size_t)b * SEQ * D_PROJ;
  float Ah  = -expf(A_log[h]);
  float dtb = dt_bias[h];
  float Dh  = D_skip[h];

  if (t < 128) {
    float raw = zxb[(size_t)(s0 + t) * D_PROJ + (D_INNER + CONV_DIM) + h] + dtb;
    float dt = softplusf(raw);
    sdt[t] = dt;
    scum[t] = dt * Ah;
  }
  __syncthreads();
  for (int off = 1; off < 128; off <<= 1) {
    float v = 0.f;
    if (t >= off && t < 128) v = scum[t - off];
    __syncthreads();
    if (t < 128) scum[t] += v;
    __syncthreads();
  }
  if (t < 128) sdec[t] = expf(scum[t]);

  // conv+silu C -> Cc[r][ch]
  for (int e = t; e < 128 * 128; e += 256) {
    int r = e >> 7, ch = e & 127;
    int gc = D_INNER + D_STATE + ch;
    int col = D_INNER + gc;
    float a = cb[gc];
#pragma unroll
    for (int k = 0; k < 4; k++) {
      int ss = s0 + r - 3 + k;
      float rv = (ss >= 0) ? zxb[(size_t)ss * D_PROJ + col] : 0.f;
      a = fmaf(rv, cw[gc * 4 + k], a);
    }
    Cc[r * 132 + ch] = siluf(a);
  }
  __syncthreads();

  int tx = t & 15, ty = t >> 4;   // t_i = ty+16i (0..127), p_j/tau_j = tx+16j (0..63)
  float acc[8][4];
#pragma unroll
  for (int i = 0; i < 8; i++)
#pragma unroll
    for (int j = 0; j < 4; j++) acc[i][j] = 0.f;

  for (int hh = 0; hh < 2; hh++) {
    int r0 = hh * 64;
    // conv+silu B half -> Bh[r][ch]
    for (int e = t; e < 64 * 128; e += 256) {
      int r = e >> 7, ch = e & 127;
      int gc = D_INNER + ch;
      int col = D_INNER + gc;
      float a = cb[gc];
#pragma unroll
      for (int k = 0; k < 4; k++) {
        int ss = s0 + r0 + r - 3 + k;
        float rv = (ss >= 0) ? zxb[(size_t)ss * D_PROJ + col] : 0.f;
        a = fmaf(rv, cw[gc * 4 + k], a);
      }
      Bh[r * 132 + ch] = siluf(a);
    }
    // conv+silu x half -> xh[r][ch]
    for (int e = t; e < 64 * 64; e += 256) {
      int r = e >> 6, ch = e & 63;
      int gc = h * 64 + ch;
      int col = D_INNER + gc;
      float a = cb[gc];
#pragma unroll
      for (int k = 0; k < 4; k++) {
        int ss = s0 + r0 + r - 3 + k;
        float rv = (ss >= 0) ? zxb[(size_t)ss * D_PROJ + col] : 0.f;
        a = fmaf(rv, cw[gc * 4 + k], a);
      }
      xh[r * 68 + ch] = siluf(a);
    }
    __syncthreads();

    // GEMM1: g[i][j] = Cc[t_i][:] . Bh[tau_j][:]  (K=128)
    float g[8][4];
#pragma unroll
    for (int i = 0; i < 8; i++)
#pragma unroll
      for (int j = 0; j < 4; j++) g[i][j] = 0.f;
    for (int k = 0; k < 128; k += 4) {
      float4 cv[8];
      float4 bv[4];
#pragma unroll
      for (int i = 0; i < 8; i++) cv[i] = *(const float4*)&Cc[(ty + 16 * i) * 132 + k];
#pragma unroll
      for (int j = 0; j < 4; j++) bv[j] = *(const float4*)&Bh[(tx + 16 * j) * 132 + k];
#pragma unroll
      for (int i = 0; i < 8; i++) {
        float ca[4] = {cv[i].x, cv[i].y, cv[i].z, cv[i].w};
#pragma unroll
        for (int j = 0; j < 4; j++) {
          float ba[4] = {bv[j].x, bv[j].y, bv[j].z, bv[j].w};
#pragma unroll
          for (int kk = 0; kk < 4; kk++)
            g[i][j] = fmaf(ca[kk], ba[kk], g[i][j]);
        }
      }
    }
    // mask + decay/dt scale (+ D on diagonal) -> Sh[t][tau_local]
#pragma unroll
    for (int i = 0; i < 8; i++) {
      int tt = ty + 16 * i;
#pragma unroll
      for (int j = 0; j < 4; j++) {
        int tl = tx + 16 * j;
        int tg = r0 + tl;
        float v = 0.f;
        if (tt >= tg) {
          v = expf(scum[tt] - scum[tg]) * sdt[tg] * g[i][j];
          if (tt == tg) v += Dh;
        }
        Sh[tt * 68 + tl] = v;
      }
    }
    __syncthreads();

    // GEMM2: acc[i][j] += sum_tau Sh[t_i][tau] * xh[tau][p_j]  (K=64)
    for (int tau = 0; tau < 64; tau += 4) {
      float4 sv[8];
#pragma unroll
      for (int i = 0; i < 8; i++) sv[i] = *(const float4*)&Sh[(ty + 16 * i) * 68 + tau];
#pragma unroll
      for (int kk = 0; kk < 4; kk++) {
        float xv[4];
#pragma unroll
        for (int j = 0; j < 4; j++) xv[j] = xh[(tau + kk) * 68 + tx + 16 * j];
#pragma unroll
        for (int i = 0; i < 8; i++) {
          float sa = (kk == 0) ? sv[i].x : (kk == 1) ? sv[i].y : (kk == 2) ? sv[i].z : sv[i].w;
#pragma unroll
          for (int j = 0; j < 4; j++)
            acc[i][j] = fmaf(sa, xv[j], acc[i][j]);
        }
      }
    }
    __syncthreads();
  }

  // scale Cc rows by exp(cumA_t), load h_prev into Bh region
  for (int e = t; e < 128 * 128; e += 256) {
    int r = e >> 7, ch = e & 127;
    Cc[r * 132 + ch] *= sdec[r];
  }
  const float* st = states + ((((size_t)b * NHEADS + h) * NCHUNK + c) << 13);
  for (int e = t; e < 8192; e += 256) {
    int p = e >> 7, n = e & 127;
    Bh[p * 132 + n] = st[e];
  }
  __syncthreads();

  // GEMM3: acc[i][j] += sum_n (sdec*Cc)[t_i][n] * h_prev[p_j][n]  (K=128)
  for (int n = 0; n < 128; n += 4) {
    float4 cv[8];
#pragma unroll
    for (int i = 0; i < 8; i++) cv[i] = *(const float4*)&Cc[(ty + 16 * i) * 132 + n];
#pragma unroll
    for (int kk = 0; kk < 4; kk++) {
      float hv[4];
#pragma unroll
      for (int j = 0; j < 4; j++) hv[j] = Bh[(tx + 16 * j) * 132 + n + kk];
#pragma unroll
      for (int i = 0; i < 8; i++) {
        float ca = (kk == 0) ? cv[i].x : (kk == 1) ? cv[i].y : (kk == 2) ? cv[i].z : cv[i].w;
#pragma unroll
        for (int j = 0; j < 4; j++)
          acc[i][j] = fmaf(ca, hv[j], acc[i][j]);
      }
    }
  }

  // write y
  float* yr = y + (size_t)b * SEQ * D_INNER + h * 64;
#pragma unroll
  for (int i = 0; i < 8; i++)
#pragma unroll
    for (int j = 0; j < 4; j++)
      yr[(size_t)(s0 + ty + 16 * i) * D_INNER + tx + 16 * j] = acc[i][j];
}

// -------------------- y * silu(z) then rmsnorm(1536) w/ gnorm_w -----------
__global__ __launch_bounds__(256) void gate_norm_kernel(
    float* __restrict__ y, const float* __restrict__ zx,
    const float* __restrict__ gw) {
  int row = blockIdx.x;
  const float* z = zx + (size_t)row * D_PROJ;
  float* yr = y + (size_t)row * D_INNER;
  int t = threadIdx.x;
  float vals[6];
  float ss = 0.f;
#pragma unroll
  for (int j = 0; j < 6; j++) {
    int c = t + j * 256;
    float zv = z[c];
    float v = yr[c] * (zv / (1.f + expf(-zv)));
    vals[j] = v;
    ss += v * v;
  }
  __shared__ float sred[4];
  ss = warp_reduce_sum(ss);
  if ((t & 63) == 0) sred[t >> 6] = ss;
  __syncthreads();
  float tot = sred[0] + sred[1] + sred[2] + sred[3];
  float inv = rsqrtf(tot / (float)D_INNER + 1e-5f);
#pragma unroll
  for (int j = 0; j < 6; j++) {
    int c = t + j * 256;
    yr[c] = gw[c] * vals[j] * inv;
  }
}

// ---------------------------------------------------------------------------
extern "C" void kernel_launch(void* const* d_in, const int* in_sizes, int n_in,
                              void* d_out, int out_size, void* d_ws, size_t ws_size,
                              hipStream_t stream) {
  const float* x          = (const float*)d_in[0];
  const float* in_proj_w  = (const float*)d_in[1];
  const float* conv_w     = (const float*)d_in[2];
  const float* conv_b     = (const float*)d_in[3];
  const float* dt_bias    = (const float*)d_in[4];
  const float* A_log      = (const float*)d_in[5];
  const float* D_skip     = (const float*)d_in[6];
  const float* gnorm_w    = (const float*)d_in[7];
  const float* out_proj_w = (const float*)d_in[8];
  const float* ln_w       = (const float*)d_in[9];
  const float* final_ln_w = (const float*)d_in[10];

  // ws: 25.2 + 25.2 + 109.8 + 50.3 + 50.3 + ~0 = 260.9 MB
  float* ws = (float*)d_ws;
  float* curx    = ws; ws += (size_t)NROWS * D_MODEL;
  float* hbuf    = ws; ws += (size_t)NROWS * D_MODEL;
  float* zxbuf   = ws; ws += (size_t)NROWS * D_PROJ;
  float* ybuf    = ws; ws += (size_t)NROWS * D_INNER;
  float* states  = ws; ws += (size_t)BATCH * NHEADS * NCHUNK * HEADDIM * D_STATE;
  float* statesA = ws; ws += (size_t)BATCH * NHEADS * NCHUNK;

  for (int l = 0; l < NUM_LAYERS; l++) {
    const float* xin = (l == 0) ? x : curx;
    rmsnorm768_kernel<<<NROWS, 256, 0, stream>>>(
        xin, ln_w + (size_t)l * D_MODEL, hbuf, 1e-6f);

    dim3 g1(NROWS / BM, (D_PROJ + BN - 1) / BN);
    gemm_nt_kernel<<<g1, 256, 0, stream>>>(
        hbuf, in_proj_w + (size_t)l * D_PROJ * D_MODEL, nullptr, zxbuf,
        NROWS, D_PROJ, D_MODEL);

    ssd_state_kernel<<<BATCH * NHEADS * NCHUNK, 256, 0, stream>>>(
        zxbuf, conv_w + (size_t)l * CONV_DIM * D_CONV,
        conv_b + (size_t)l * CONV_DIM, dt_bias + l * NHEADS,
        A_log + l * NHEADS, states, statesA);

    ssd_chunkscan_kernel<<<BATCH * NHEADS, 256, 0, stream>>>(states, statesA);

    ssd_output_kernel<<<BATCH * NHEADS * NCHUNK, 256, 0, stream>>>(
        zxbuf, conv_w + (size_t)l * CONV_DIM * D_CONV,
        conv_b + (size_t)l * CONV_DIM, dt_bias + l * NHEADS,
        A_log + l * NHEADS, D_skip + l * NHEADS, states, ybuf);

    gate_norm_kernel<<<NROWS, 256, 0, stream>>>(
        ybuf, zxbuf, gnorm_w + (size_t)l * D_INNER);

    dim3 g2(NROWS / BM, D_MODEL / BN);
    gemm_nt_kernel<<<g2, 256, 0, stream>>>(
        ybuf, out_proj_w + (size_t)l * D_MODEL * D_INNER, xin, curx,
        NROWS, D_MODEL, D_INNER);
  }
  rmsnorm768_kernel<<<NROWS, 256, 0, stream>>>(
      curx, final_ln_w, (float*)d_out, 1e-6f);
}

// Round 4
// 4580.226 us; speedup vs baseline: 3.6996x; 1.5521x over previous
//
#include <hip/hip_runtime.h>
#include <hip/hip_bf16.h>
#include <math.h>

#define NUM_LAYERS 4
#define D_MODEL 768
#define D_STATE 128
#define D_CONV 4
#define HEADDIM 64
#define D_INNER 1536
#define NHEADS 24
#define CONV_DIM 1792
#define D_PROJ 3352
#define BATCH 4
#define SEQ 2048
#define NROWS (BATCH*SEQ)   /* 8192 */
#define CHUNK 128
#define NCHUNK (SEQ/CHUNK)  /* 16 */

typedef __bf16 bf16x8 __attribute__((ext_vector_type(8)));
typedef float f32x4 __attribute__((ext_vector_type(4)));

__device__ __forceinline__ float warp_reduce_sum(float v) {
  v += __shfl_xor(v, 32);
  v += __shfl_xor(v, 16);
  v += __shfl_xor(v, 8);
  v += __shfl_xor(v, 4);
  v += __shfl_xor(v, 2);
  v += __shfl_xor(v, 1);
  return v;
}

__device__ __forceinline__ float softplusf(float x) {
  return (x > 20.f) ? x : log1pf(expf(x));
}
__device__ __forceinline__ float siluf(float x) {
  return x / (1.f + expf(-x));
}

__device__ __forceinline__ void store_val(float v, float* p) { *p = v; }
__device__ __forceinline__ void store_val(float v, __hip_bfloat16* p) {
  *p = __float2bfloat16(v);
}

// -------------------- f32 -> bf16 bulk convert -----------------------------
__global__ __launch_bounds__(256) void f32_to_bf16_kernel(
    const float* __restrict__ in, __hip_bfloat16* __restrict__ out, size_t n) {
  for (size_t i = ((size_t)blockIdx.x * 256 + threadIdx.x) * 4; i < n;
       i += (size_t)gridDim.x * 256 * 4) {
    float4 v = *(const float4*)(in + i);
    __hip_bfloat16 h0 = __float2bfloat16(v.x), h1 = __float2bfloat16(v.y);
    __hip_bfloat16 h2 = __float2bfloat16(v.z), h3 = __float2bfloat16(v.w);
    ushort4 u;
    u.x = *(unsigned short*)&h0; u.y = *(unsigned short*)&h1;
    u.z = *(unsigned short*)&h2; u.w = *(unsigned short*)&h3;
    *(ushort4*)(out + i) = u;
  }
}

// -------------------- rmsnorm over 768 (templated output dtype) ------------
template <typename OUT>
__global__ __launch_bounds__(256) void rmsnorm768_kernel(
    const float* __restrict__ in, const float* __restrict__ w,
    OUT* __restrict__ out, float eps) {
  int row = blockIdx.x;
  const float* x = in + (size_t)row * D_MODEL;
  OUT* o = out + (size_t)row * D_MODEL;
  int t = threadIdx.x;
  float v0 = x[t], v1 = x[t + 256], v2 = x[t + 512];
  float ss = v0 * v0 + v1 * v1 + v2 * v2;
  __shared__ float sred[4];
  ss = warp_reduce_sum(ss);
  if ((t & 63) == 0) sred[t >> 6] = ss;
  __syncthreads();
  float tot = sred[0] + sred[1] + sred[2] + sred[3];
  float inv = rsqrtf(tot / (float)D_MODEL + eps);
  store_val(w[t] * v0 * inv, o + t);
  store_val(w[t + 256] * v1 * inv, o + t + 256);
  store_val(w[t + 512] * v2 * inv, o + t + 512);
}

// ============ bf16 MFMA GEMM: C[M][N] = A[M][K] * W[N][K]^T (+res) =========
// 128x128 tile, BK=32, 4 waves (2x2 of 64x64), double-buffered LDS fed by
// global_load_lds(16B). LDS layout per tile: [kc(4)][row(128)][8 bf16] so
// frag ds_read_b128 by 16 consecutive rows = 256B contiguous (conflict-free).
__global__ __launch_bounds__(256) void gemm_bf16_kernel(
    const __hip_bfloat16* __restrict__ A, const __hip_bfloat16* __restrict__ W,
    const float* __restrict__ res, float* __restrict__ C,
    int M, int N, int K) {
  __shared__ __bf16 At[2][4096];
  __shared__ __bf16 Bt[2][4096];
  int cpx = gridDim.x >> 3;                    // grid % 8 == 0 (1728 / 384)
  int bid = blockIdx.x;
  int bid2 = (bid & 7) * cpx + (bid >> 3);     // XCD-contiguous chunks
  int bm = bid2 & 63;                          // M/128 == 64 always here
  int bn = bid2 >> 6;
  int m0 = bm * 128, n0 = bn * 128;
  int t = threadIdx.x;
  int w = t >> 6, l = t & 63;
  int NT = K >> 5;

  // staging: thread t handles tile row (t&127), kc base (t>>7); pass p adds 2kc
  int srow = t & 127;
  int kbase = (t >> 7) * 8;                    // 0 or 8
  const __hip_bfloat16* Asrc = A + (size_t)(m0 + srow) * K + kbase;
  int nrow = n0 + srow; if (nrow >= N) nrow = N - 1;   // clamp (dup row, writes guarded)
  const __hip_bfloat16* Wsrc = W + (size_t)nrow * K + kbase;
  int ldsA0 = (w * 64) * 8;                    // pass0 wave base (bf16 elems)
  int ldsA1 = (256 + w * 64) * 8;              // pass1

#define GLL(gsrc, ldst)                                                        \
  __builtin_amdgcn_global_load_lds(                                            \
      (const __attribute__((address_space(1))) unsigned int*)(gsrc),           \
      (__attribute__((address_space(3))) unsigned int*)(ldst), 16, 0, 0)

#define STAGE(buf, kofs)                                                       \
  do {                                                                         \
    GLL(Asrc + (kofs), &At[buf][ldsA0]);                                       \
    GLL(Asrc + (kofs) + 16, &At[buf][ldsA1]);                                  \
    GLL(Wsrc + (kofs), &Bt[buf][ldsA0]);                                       \
    GLL(Wsrc + (kofs) + 16, &Bt[buf][ldsA1]);                                  \
  } while (0)

  int lr = l & 15, lk = l >> 4;
  int wr = w >> 1, wc = w & 1;
  int aoff = (lk * 128 + wr * 64 + lr) * 8;    // + mi*16*8
  int boff = (lk * 128 + wc * 64 + lr) * 8;    // + ni*16*8

  f32x4 acc[4][4];
#pragma unroll
  for (int i = 0; i < 4; i++)
#pragma unroll
    for (int j = 0; j < 4; j++) acc[i][j] = (f32x4)0.f;

  STAGE(0, 0);
  for (int kt = 0; kt < NT; ++kt) {
    int cur = kt & 1;
    if (kt + 1 < NT) {
      STAGE(cur ^ 1, (kt + 1) * 32);
      asm volatile("s_waitcnt vmcnt(4)" ::: "memory");
    } else {
      asm volatile("s_waitcnt vmcnt(0)" ::: "memory");
    }
    __builtin_amdgcn_sched_barrier(0);
    __builtin_amdgcn_s_barrier();
    __builtin_amdgcn_sched_barrier(0);
    bf16x8 av[4], bv[4];
#pragma unroll
    for (int mi = 0; mi < 4; mi++)
      av[mi] = *(const bf16x8*)&At[cur][aoff + mi * 128];
#pragma unroll
    for (int ni = 0; ni < 4; ni++)
      bv[ni] = *(const bf16x8*)&Bt[cur][boff + ni * 128];
#pragma unroll
    for (int mi = 0; mi < 4; mi++)
#pragma unroll
      for (int ni = 0; ni < 4; ni++)
        acc[mi][ni] = __builtin_amdgcn_mfma_f32_16x16x32_bf16(
            av[mi], bv[ni], acc[mi][ni], 0, 0, 0);
    __builtin_amdgcn_sched_barrier(0);
    __builtin_amdgcn_s_barrier();
  }
#undef STAGE
#undef GLL

  // C/D layout: col = lane&15, row = (lane>>4)*4 + reg
  int rbase = (l >> 4) * 4;
#pragma unroll
  for (int ni = 0; ni < 4; ni++) {
    int n = n0 + wc * 64 + ni * 16 + (l & 15);
    if (n >= N) continue;
#pragma unroll
    for (int mi = 0; mi < 4; mi++) {
#pragma unroll
      for (int r = 0; r < 4; r++) {
        int m = m0 + wr * 64 + mi * 16 + rbase + r;
        float v = acc[mi][ni][r];
        if (res) v += res[(size_t)m * N + n];
        C[(size_t)m * N + n] = v;
      }
    }
  }
}

// ======================= chunked SSD scan ==================================
// ---- kernel A1: per-chunk state contribution H_c (and totalA_c) ----------
__global__ __launch_bounds__(256) void ssd_state_kernel(
    const float* __restrict__ zx, const float* __restrict__ cw,
    const float* __restrict__ cb, const float* __restrict__ dt_bias,
    const float* __restrict__ A_log, float* __restrict__ states,
    float* __restrict__ statesA) {
  __shared__ float lds[25856];          // 103.4 KB
  float* Bs   = lds;                    // [128][132]
  float* xs   = lds + 16896;            // [128][68]  (x scaled by wdt)
  float* swdt = lds + 25600;            // [128]
  float* scan = lds + 25728;            // [128]
  int t  = threadIdx.x;
  int c  = blockIdx.x & (NCHUNK - 1);
  int h  = (blockIdx.x / NCHUNK) % NHEADS;
  int b  = blockIdx.x / (NCHUNK * NHEADS);
  int s0 = c * CHUNK;
  const float* zxb = zx + (size_t)b * SEQ * D_PROJ;
  float Ah  = -expf(A_log[h]);
  float dtb = dt_bias[h];

  if (t < 128) {
    float raw = zxb[(size_t)(s0 + t) * D_PROJ + (D_INNER + CONV_DIM) + h] + dtb;
    float dt = softplusf(raw);
    swdt[t] = dt;
    scan[t] = dt * Ah;
  }
  __syncthreads();
  for (int off = 1; off < 128; off <<= 1) {
    float v = 0.f;
    if (t >= off && t < 128) v = scan[t - off];
    __syncthreads();
    if (t < 128) scan[t] += v;
    __syncthreads();
  }
  float total = scan[127];
  if (t < 128) swdt[t] *= expf(total - scan[t]);
  __syncthreads();

  for (int e = t; e < 128 * 128; e += 256) {
    int r = e >> 7, ch = e & 127;
    int gc = D_INNER + ch;
    int col = D_INNER + gc;
    float a = cb[gc];
#pragma unroll
    for (int k = 0; k < 4; k++) {
      int ss = s0 + r - 3 + k;
      float rv = (ss >= 0) ? zxb[(size_t)ss * D_PROJ + col] : 0.f;
      a = fmaf(rv, cw[gc * 4 + k], a);
    }
    Bs[r * 132 + ch] = siluf(a);
  }
  for (int e = t; e < 128 * 64; e += 256) {
    int r = e >> 6, ch = e & 63;
    int gc = h * 64 + ch;
    int col = D_INNER + gc;
    float a = cb[gc];
#pragma unroll
    for (int k = 0; k < 4; k++) {
      int ss = s0 + r - 3 + k;
      float rv = (ss >= 0) ? zxb[(size_t)ss * D_PROJ + col] : 0.f;
      a = fmaf(rv, cw[gc * 4 + k], a);
    }
    xs[r * 68 + ch] = swdt[r] * siluf(a);
  }
  __syncthreads();

  int tx = t & 15, ty = t >> 4;
  int p0 = ty * 4;
  float acc[4][8];
#pragma unroll
  for (int i = 0; i < 4; i++)
#pragma unroll
    for (int q = 0; q < 8; q++) acc[i][q] = 0.f;

  for (int tau = 0; tau < 128; tau++) {
    float4 xv = *(const float4*)&xs[tau * 68 + p0];
    float bv[8];
#pragma unroll
    for (int q = 0; q < 8; q++) bv[q] = Bs[tau * 132 + tx + 16 * q];
    float xa[4] = {xv.x, xv.y, xv.z, xv.w};
#pragma unroll
    for (int i = 0; i < 4; i++)
#pragma unroll
      for (int q = 0; q < 8; q++)
        acc[i][q] = fmaf(xa[i], bv[q], acc[i][q]);
  }
  float* Hc = states + ((((size_t)b * NHEADS + h) * NCHUNK + c) << 13);
#pragma unroll
  for (int i = 0; i < 4; i++)
#pragma unroll
    for (int q = 0; q < 8; q++)
      Hc[(p0 + i) * 128 + tx + 16 * q] = acc[i][q];
  if (t == 0) statesA[(b * NHEADS + h) * NCHUNK + c] = total;
}

// ---- kernel B: inter-chunk scan; states[c] <- state entering chunk c -----
__global__ __launch_bounds__(256) void ssd_chunkscan_kernel(
    float* __restrict__ states, const float* __restrict__ statesA) {
  int bh = blockIdx.x;
  int t = threadIdx.x;
  float* st = states + (size_t)bh * NCHUNK * 8192;
  const float* sA = statesA + bh * NCHUNK;
  float hacc[32];
#pragma unroll
  for (int i = 0; i < 32; i++) hacc[i] = 0.f;
  for (int c = 0; c < NCHUNK; c++) {
    float eA = expf(sA[c]);
    float* p = st + (size_t)c * 8192;
#pragma unroll
    for (int i = 0; i < 32; i++) {
      float tmp = p[i * 256 + t];
      p[i * 256 + t] = hacc[i];
      hacc[i] = fmaf(eA, hacc[i], tmp);
    }
  }
}

// ---- kernel C: per-chunk output (y written as bf16) ----------------------
__global__ __launch_bounds__(256) void ssd_output_kernel(
    const float* __restrict__ zx, const float* __restrict__ cw,
    const float* __restrict__ cb, const float* __restrict__ dt_bias,
    const float* __restrict__ A_log, const float* __restrict__ D_skip,
    const float* __restrict__ states, __hip_bfloat16* __restrict__ y) {
  __shared__ float lds[38784];          // 155.1 KB
  float* Cc  = lds;                     // [128][132]
  float* Bh  = lds + 16896;             // [64][132]  (later aliased as h_prev)
  float* Sh  = lds + 25344;             // [128][68]
  float* xh  = lds + 34048;             // [64][68]
  float* sdt = lds + 38400;             // [128]
  float* scum= lds + 38528;             // [128]
  float* sdec= lds + 38656;             // [128]
  int t  = threadIdx.x;
  int c  = blockIdx.x & (NCHUNK - 1);
  int h  = (blockIdx.x / NCHUNK) % NHEADS;
  int b  = blockIdx.x / (NCHUNK * NHEADS);
  int s0 = c * CHUNK;
  const float* zxb = zx + (size_t)b * SEQ * D_PROJ;
  float Ah  = -expf(A_log[h]);
  float dtb = dt_bias[h];
  float Dh  = D_skip[h];

  if (t < 128) {
    float raw = zxb[(size_t)(s0 + t) * D_PROJ + (D_INNER + CONV_DIM) + h] + dtb;
    float dt = softplusf(raw);
    sdt[t] = dt;
    scum[t] = dt * Ah;
  }
  __syncthreads();
  for (int off = 1; off < 128; off <<= 1) {
    float v = 0.f;
    if (t >= off && t < 128) v = scum[t - off];
    __syncthreads();
    if (t < 128) scum[t] += v;
    __syncthreads();
  }
  if (t < 128) sdec[t] = expf(scum[t]);

  for (int e = t; e < 128 * 128; e += 256) {
    int r = e >> 7, ch = e & 127;
    int gc = D_INNER + D_STATE + ch;
    int col = D_INNER + gc;
    float a = cb[gc];
#pragma unroll
    for (int k = 0; k < 4; k++) {
      int ss = s0 + r - 3 + k;
      float rv = (ss >= 0) ? zxb[(size_t)ss * D_PROJ + col] : 0.f;
      a = fmaf(rv, cw[gc * 4 + k], a);
    }
    Cc[r * 132 + ch] = siluf(a);
  }
  __syncthreads();

  int tx = t & 15, ty = t >> 4;
  float acc[8][4];
#pragma unroll
  for (int i = 0; i < 8; i++)
#pragma unroll
    for (int j = 0; j < 4; j++) acc[i][j] = 0.f;

  for (int hh = 0; hh < 2; hh++) {
    int r0 = hh * 64;
    for (int e = t; e < 64 * 128; e += 256) {
      int r = e >> 7, ch = e & 127;
      int gc = D_INNER + ch;
      int col = D_INNER + gc;
      float a = cb[gc];
#pragma unroll
      for (int k = 0; k < 4; k++) {
        int ss = s0 + r0 + r - 3 + k;
        float rv = (ss >= 0) ? zxb[(size_t)ss * D_PROJ + col] : 0.f;
        a = fmaf(rv, cw[gc * 4 + k], a);
      }
      Bh[r * 132 + ch] = siluf(a);
    }
    for (int e = t; e < 64 * 64; e += 256) {
      int r = e >> 6, ch = e & 63;
      int gc = h * 64 + ch;
      int col = D_INNER + gc;
      float a = cb[gc];
#pragma unroll
      for (int k = 0; k < 4; k++) {
        int ss = s0 + r0 + r - 3 + k;
        float rv = (ss >= 0) ? zxb[(size_t)ss * D_PROJ + col] : 0.f;
        a = fmaf(rv, cw[gc * 4 + k], a);
      }
      xh[r * 68 + ch] = siluf(a);
    }
    __syncthreads();

    float g[8][4];
#pragma unroll
    for (int i = 0; i < 8; i++)
#pragma unroll
      for (int j = 0; j < 4; j++) g[i][j] = 0.f;
    for (int k = 0; k < 128; k += 4) {
      float4 cv[8];
      float4 bv[4];
#pragma unroll
      for (int i = 0; i < 8; i++) cv[i] = *(const float4*)&Cc[(ty + 16 * i) * 132 + k];
#pragma unroll
      for (int j = 0; j < 4; j++) bv[j] = *(const float4*)&Bh[(tx + 16 * j) * 132 + k];
#pragma unroll
      for (int i = 0; i < 8; i++) {
        float ca[4] = {cv[i].x, cv[i].y, cv[i].z, cv[i].w};
#pragma unroll
        for (int j = 0; j < 4; j++) {
          float ba[4] = {bv[j].x, bv[j].y, bv[j].z, bv[j].w};
#pragma unroll
          for (int kk = 0; kk < 4; kk++)
            g[i][j] = fmaf(ca[kk], ba[kk], g[i][j]);
        }
      }
    }
#pragma unroll
    for (int i = 0; i < 8; i++) {
      int tt = ty + 16 * i;
#pragma unroll
      for (int j = 0; j < 4; j++) {
        int tl = tx + 16 * j;
        int tg = r0 + tl;
        float v = 0.f;
        if (tt >= tg) {
          v = expf(scum[tt] - scum[tg]) * sdt[tg] * g[i][j];
          if (tt == tg) v += Dh;
        }
        Sh[tt * 68 + tl] = v;
      }
    }
    __syncthreads();

    for (int tau = 0; tau < 64; tau += 4) {
      float4 sv[8];
#pragma unroll
      for (int i = 0; i < 8; i++) sv[i] = *(const float4*)&Sh[(ty + 16 * i) * 68 + tau];
#pragma unroll
      for (int kk = 0; kk < 4; kk++) {
        float xv[4];
#pragma unroll
        for (int j = 0; j < 4; j++) xv[j] = xh[(tau + kk) * 68 + tx + 16 * j];
#pragma unroll
        for (int i = 0; i < 8; i++) {
          float sa = (kk == 0) ? sv[i].x : (kk == 1) ? sv[i].y : (kk == 2) ? sv[i].z : sv[i].w;
#pragma unroll
          for (int j = 0; j < 4; j++)
            acc[i][j] = fmaf(sa, xv[j], acc[i][j]);
        }
      }
    }
    __syncthreads();
  }

  for (int e = t; e < 128 * 128; e += 256) {
    int r = e >> 7, ch = e & 127;
    Cc[r * 132 + ch] *= sdec[r];
  }
  const float* st = states + ((((size_t)b * NHEADS + h) * NCHUNK + c) << 13);
  for (int e = t; e < 8192; e += 256) {
    int p = e >> 7, n = e & 127;
    Bh[p * 132 + n] = st[e];
  }
  __syncthreads();

  for (int n = 0; n < 128; n += 4) {
    float4 cv[8];
#pragma unroll
    for (int i = 0; i < 8; i++) cv[i] = *(const float4*)&Cc[(ty + 16 * i) * 132 + n];
#pragma unroll
    for (int kk = 0; kk < 4; kk++) {
      float hv[4];
#pragma unroll
      for (int j = 0; j < 4; j++) hv[j] = Bh[(tx + 16 * j) * 132 + n + kk];
#pragma unroll
      for (int i = 0; i < 8; i++) {
        float ca = (kk == 0) ? cv[i].x : (kk == 1) ? cv[i].y : (kk == 2) ? cv[i].z : cv[i].w;
#pragma unroll
        for (int j = 0; j < 4; j++)
          acc[i][j] = fmaf(ca, hv[j], acc[i][j]);
      }
    }
  }

  __hip_bfloat16* yr = y + (size_t)b * SEQ * D_INNER + h * 64;
#pragma unroll
  for (int i = 0; i < 8; i++)
#pragma unroll
    for (int j = 0; j < 4; j++)
      yr[(size_t)(s0 + ty + 16 * i) * D_INNER + tx + 16 * j] =
          __float2bfloat16(acc[i][j]);
}

// ---------- y(bf16) * silu(z) then rmsnorm(1536), in-place bf16 -----------
__global__ __launch_bounds__(256) void gate_norm_kernel(
    __hip_bfloat16* __restrict__ y, const float* __restrict__ zx,
    const float* __restrict__ gw) {
  int row = blockIdx.x;
  const float* z = zx + (size_t)row * D_PROJ;
  __hip_bfloat16* yr = y + (size_t)row * D_INNER;
  int t = threadIdx.x;
  float vals[6];
  float ss = 0.f;
#pragma unroll
  for (int j = 0; j < 6; j++) {
    int c = t + j * 256;
    float zv = z[c];
    float v = __bfloat162float(yr[c]) * (zv / (1.f + expf(-zv)));
    vals[j] = v;
    ss += v * v;
  }
  __shared__ float sred[4];
  ss = warp_reduce_sum(ss);
  if ((t & 63) == 0) sred[t >> 6] = ss;
  __syncthreads();
  float tot = sred[0] + sred[1] + sred[2] + sred[3];
  float inv = rsqrtf(tot / (float)D_INNER + 1e-5f);
#pragma unroll
  for (int j = 0; j < 6; j++) {
    int c = t + j * 256;
    yr[c] = __float2bfloat16(gw[c] * vals[j] * inv);
  }
}

// ---------------------------------------------------------------------------
extern "C" void kernel_launch(void* const* d_in, const int* in_sizes, int n_in,
                              void* d_out, int out_size, void* d_ws, size_t ws_size,
                              hipStream_t stream) {
  const float* x          = (const float*)d_in[0];
  const float* in_proj_w  = (const float*)d_in[1];
  const float* conv_w     = (const float*)d_in[2];
  const float* conv_b     = (const float*)d_in[3];
  const float* dt_bias    = (const float*)d_in[4];
  const float* A_log      = (const float*)d_in[5];
  const float* D_skip     = (const float*)d_in[6];
  const float* gnorm_w    = (const float*)d_in[7];
  const float* out_proj_w = (const float*)d_in[8];
  const float* ln_w       = (const float*)d_in[9];
  const float* final_ln_w = (const float*)d_in[10];

  // ws (253.1 MB): curx 25.2 | zx 109.8 | states 50.3 | hbuf_b 12.6 |
  //                ybuf_b 25.2 | wi_b 20.6 | wo_b 9.4
  float* ws = (float*)d_ws;
  float* curx    = ws; ws += (size_t)NROWS * D_MODEL;
  float* zxbuf   = ws; ws += (size_t)NROWS * D_PROJ;
  float* states  = ws; ws += (size_t)BATCH * NHEADS * NCHUNK * HEADDIM * D_STATE;
  float* statesA = ws; ws += 2048;
  __hip_bfloat16* hbuf_b = (__hip_bfloat16*)ws; ws += (size_t)NROWS * D_MODEL / 2;
  __hip_bfloat16* ybuf_b = (__hip_bfloat16*)ws; ws += (size_t)NROWS * D_INNER / 2;
  __hip_bfloat16* wi_b   = (__hip_bfloat16*)ws; ws += (size_t)NUM_LAYERS * D_PROJ * D_MODEL / 2;
  __hip_bfloat16* wo_b   = (__hip_bfloat16*)ws; ws += (size_t)NUM_LAYERS * D_MODEL * D_INNER / 2;

  f32_to_bf16_kernel<<<1024, 256, 0, stream>>>(
      in_proj_w, wi_b, (size_t)NUM_LAYERS * D_PROJ * D_MODEL);
  f32_to_bf16_kernel<<<1024, 256, 0, stream>>>(
      out_proj_w, wo_b, (size_t)NUM_LAYERS * D_MODEL * D_INNER);

  for (int l = 0; l < NUM_LAYERS; l++) {
    const float* xin = (l == 0) ? x : curx;
    rmsnorm768_kernel<__hip_bfloat16><<<NROWS, 256, 0, stream>>>(
        xin, ln_w + (size_t)l * D_MODEL, hbuf_b, 1e-6f);

    gemm_bf16_kernel<<<64 * 27, 256, 0, stream>>>(
        hbuf_b, wi_b + (size_t)l * D_PROJ * D_MODEL, nullptr, zxbuf,
        NROWS, D_PROJ, D_MODEL);

    ssd_state_kernel<<<BATCH * NHEADS * NCHUNK, 256, 0, stream>>>(
        zxbuf, conv_w + (size_t)l * CONV_DIM * D_CONV,
        conv_b + (size_t)l * CONV_DIM, dt_bias + l * NHEADS,
        A_log + l * NHEADS, states, statesA);

    ssd_chunkscan_kernel<<<BATCH * NHEADS, 256, 0, stream>>>(states, statesA);

    ssd_output_kernel<<<BATCH * NHEADS * NCHUNK, 256, 0, stream>>>(
        zxbuf, conv_w + (size_t)l * CONV_DIM * D_CONV,
        conv_b + (size_t)l * CONV_DIM, dt_bias + l * NHEADS,
        A_log + l * NHEADS, D_skip + l * NHEADS, states, ybuf_b);

    gate_norm_kernel<<<NROWS, 256, 0, stream>>>(
        ybuf_b, zxbuf, gnorm_w + (size_t)l * D_INNER);

    gemm_bf16_kernel<<<64 * 6, 256, 0, stream>>>(
        ybuf_b, wo_b + (size_t)l * D_MODEL * D_INNER, xin, curx,
        NROWS, D_MODEL, D_INNER);
  }
  rmsnorm768_kernel<float><<<NROWS, 256, 0, stream>>>(
      curx, final_ln_w, (float*)d_out, 1e-6f);
}

// Round 5
// 1374.209 us; speedup vs baseline: 12.3307x; 3.3330x over previous
//
#include <hip/hip_runtime.h>
#include <hip/hip_bf16.h>
#include <math.h>

#define NUM_LAYERS 4
#define D_MODEL 768
#define D_STATE 128
#define D_CONV 4
#define HEADDIM 64
#define D_INNER 1536
#define NHEADS 24
#define CONV_DIM 1792
#define D_PROJ 3352
#define BATCH 4
#define SEQ 2048
#define NROWS (BATCH*SEQ)   /* 8192 */
#define CHUNK 128
#define NCHUNK (SEQ/CHUNK)  /* 16 */
#define LOG2E 1.4426950408889634f

typedef __bf16 bf16x8 __attribute__((ext_vector_type(8)));
typedef float f32x4 __attribute__((ext_vector_type(4)));

#define GLL(gsrc, ldst)                                                        \
  __builtin_amdgcn_global_load_lds(                                            \
      (const __attribute__((address_space(1))) unsigned int*)(gsrc),           \
      (__attribute__((address_space(3))) unsigned int*)(ldst), 16, 0, 0)

__device__ __forceinline__ float warp_reduce_sum(float v) {
  v += __shfl_xor(v, 32);
  v += __shfl_xor(v, 16);
  v += __shfl_xor(v, 8);
  v += __shfl_xor(v, 4);
  v += __shfl_xor(v, 2);
  v += __shfl_xor(v, 1);
  return v;
}

__device__ __forceinline__ float softplusf(float x) {
  return (x > 20.f) ? x : log1pf(expf(x));
}
__device__ __forceinline__ float siluf(float x) {
  return x / (1.f + expf(-x));
}

__device__ __forceinline__ void store_val(float v, float* p) { *p = v; }
__device__ __forceinline__ void store_val(float v, __hip_bfloat16* p) {
  *p = __float2bfloat16(v);
}

// -------------------- f32 -> bf16 bulk convert -----------------------------
__global__ __launch_bounds__(256) void f32_to_bf16_kernel(
    const float* __restrict__ in, __hip_bfloat16* __restrict__ out, size_t n) {
  for (size_t i = ((size_t)blockIdx.x * 256 + threadIdx.x) * 4; i < n;
       i += (size_t)gridDim.x * 256 * 4) {
    float4 v = *(const float4*)(in + i);
    __hip_bfloat16 h0 = __float2bfloat16(v.x), h1 = __float2bfloat16(v.y);
    __hip_bfloat16 h2 = __float2bfloat16(v.z), h3 = __float2bfloat16(v.w);
    ushort4 u;
    u.x = *(unsigned short*)&h0; u.y = *(unsigned short*)&h1;
    u.z = *(unsigned short*)&h2; u.w = *(unsigned short*)&h3;
    *(ushort4*)(out + i) = u;
  }
}

// -------------------- rmsnorm over 768 (templated output dtype) ------------
template <typename OUT>
__global__ __launch_bounds__(256) void rmsnorm768_kernel(
    const float* __restrict__ in, const float* __restrict__ w,
    OUT* __restrict__ out, float eps) {
  int row = blockIdx.x;
  const float* x = in + (size_t)row * D_MODEL;
  OUT* o = out + (size_t)row * D_MODEL;
  int t = threadIdx.x;
  float v0 = x[t], v1 = x[t + 256], v2 = x[t + 512];
  float ss = v0 * v0 + v1 * v1 + v2 * v2;
  __shared__ float sred[4];
  ss = warp_reduce_sum(ss);
  if ((t & 63) == 0) sred[t >> 6] = ss;
  __syncthreads();
  float tot = sred[0] + sred[1] + sred[2] + sred[3];
  float inv = rsqrtf(tot / (float)D_MODEL + eps);
  store_val(w[t] * v0 * inv, o + t);
  store_val(w[t + 256] * v1 * inv, o + t + 256);
  store_val(w[t + 512] * v2 * inv, o + t + 512);
}

// ============ bf16 MFMA GEMM: C[M][N] = A[M][K] * W[N][K]^T (+res) =========
__global__ __launch_bounds__(256) void gemm_bf16_kernel(
    const __hip_bfloat16* __restrict__ A, const __hip_bfloat16* __restrict__ W,
    const float* __restrict__ res, float* __restrict__ C,
    int M, int N, int K) {
  __shared__ __bf16 At[2][4096];
  __shared__ __bf16 Bt[2][4096];
  int cpx = gridDim.x >> 3;
  int bid = blockIdx.x;
  int bid2 = (bid & 7) * cpx + (bid >> 3);
  int bm = bid2 & 63;
  int bn = bid2 >> 6;
  int m0 = bm * 128, n0 = bn * 128;
  int t = threadIdx.x;
  int w = t >> 6, l = t & 63;
  int NT = K >> 5;

  int srow = t & 127;
  int kbase = (t >> 7) * 8;
  const __hip_bfloat16* Asrc = A + (size_t)(m0 + srow) * K + kbase;
  int nrow = n0 + srow; if (nrow >= N) nrow = N - 1;
  const __hip_bfloat16* Wsrc = W + (size_t)nrow * K + kbase;
  int ldsA0 = (w * 64) * 8;
  int ldsA1 = (256 + w * 64) * 8;

#define STAGE(buf, kofs)                                                       \
  do {                                                                         \
    GLL(Asrc + (kofs), &At[buf][ldsA0]);                                       \
    GLL(Asrc + (kofs) + 16, &At[buf][ldsA1]);                                  \
    GLL(Wsrc + (kofs), &Bt[buf][ldsA0]);                                       \
    GLL(Wsrc + (kofs) + 16, &Bt[buf][ldsA1]);                                  \
  } while (0)

  int lr = l & 15, lk = l >> 4;
  int wr = w >> 1, wc = w & 1;
  int aoff = (lk * 128 + wr * 64 + lr) * 8;
  int boff = (lk * 128 + wc * 64 + lr) * 8;

  f32x4 acc[4][4];
#pragma unroll
  for (int i = 0; i < 4; i++)
#pragma unroll
    for (int j = 0; j < 4; j++) acc[i][j] = (f32x4)0.f;

  STAGE(0, 0);
  for (int kt = 0; kt < NT; ++kt) {
    int cur = kt & 1;
    if (kt + 1 < NT) {
      STAGE(cur ^ 1, (kt + 1) * 32);
      asm volatile("s_waitcnt vmcnt(4)" ::: "memory");
    } else {
      asm volatile("s_waitcnt vmcnt(0)" ::: "memory");
    }
    __builtin_amdgcn_sched_barrier(0);
    __builtin_amdgcn_s_barrier();
    __builtin_amdgcn_sched_barrier(0);
    bf16x8 av[4], bv[4];
#pragma unroll
    for (int mi = 0; mi < 4; mi++)
      av[mi] = *(const bf16x8*)&At[cur][aoff + mi * 128];
#pragma unroll
    for (int ni = 0; ni < 4; ni++)
      bv[ni] = *(const bf16x8*)&Bt[cur][boff + ni * 128];
#pragma unroll
    for (int mi = 0; mi < 4; mi++)
#pragma unroll
      for (int ni = 0; ni < 4; ni++)
        acc[mi][ni] = __builtin_amdgcn_mfma_f32_16x16x32_bf16(
            av[mi], bv[ni], acc[mi][ni], 0, 0, 0);
    __builtin_amdgcn_sched_barrier(0);
    __builtin_amdgcn_s_barrier();
  }
#undef STAGE

  int rbase = (l >> 4) * 4;
#pragma unroll
  for (int ni = 0; ni < 4; ni++) {
    int n = n0 + wc * 64 + ni * 16 + (l & 15);
    if (n >= N) continue;
#pragma unroll
    for (int mi = 0; mi < 4; mi++) {
#pragma unroll
      for (int r = 0; r < 4; r++) {
        int m = m0 + wr * 64 + mi * 16 + rbase + r;
        float v = acc[mi][ni][r];
        if (res) v += res[(size_t)m * N + n];
        C[(size_t)m * N + n] = v;
      }
    }
  }
}

// ======================= chunked SSD (MFMA) ================================
// dt_kernel: softplus + within-chunk inclusive prefix of dt*A (log2-scaled)
__global__ __launch_bounds__(128) void dt_kernel(
    const float* __restrict__ zx, const float* __restrict__ dt_bias,
    const float* __restrict__ A_log, float* __restrict__ dtbuf,
    float* __restrict__ cum2buf) {
  int c = blockIdx.x & 15;
  int h = (blockIdx.x >> 4) % NHEADS;
  int b = blockIdx.x / (16 * NHEADS);
  int t = threadIdx.x;
  int s = c * CHUNK + t;
  float Ah = -expf(A_log[h]);
  float raw = zx[((size_t)b * SEQ + s) * D_PROJ + (D_INNER + CONV_DIM) + h] +
              dt_bias[h];
  float dt = softplusf(raw);
  __shared__ float sc[128];
  sc[t] = dt * Ah;
  __syncthreads();
  for (int off = 1; off < 128; off <<= 1) {
    float v = (t >= off) ? sc[t - off] : 0.f;
    __syncthreads();
    sc[t] += v;
    __syncthreads();
  }
  size_t o = ((size_t)b * NHEADS + h) * SEQ + s;
  dtbuf[o] = dt;
  cum2buf[o] = sc[t] * LOG2E;
}

// conv_tiles: conv(k=4)+bias+silu once; emit bf16 MFMA k-major tiles.
//  xA : [b][c][h][to(16)][p(64)][8]   (k = tau)
//  Bkt: [b][c][to(16)][n(128)][8]     (k = tau)
//  Bkn: [b][c][no(16)][tau(128)][8]   (k = n)
//  Ckn: [b][c][no(16)][t(128)][8]     (k = n)
__global__ __launch_bounds__(256) void conv_tiles_kernel(
    const float* __restrict__ zx, const float* __restrict__ cw,
    const float* __restrict__ cb, __hip_bfloat16* __restrict__ xA,
    __hip_bfloat16* __restrict__ Bkt, __hip_bfloat16* __restrict__ Bkn,
    __hip_bfloat16* __restrict__ Ckn) {
  __shared__ float srows[11 * CONV_DIM];
  int to = blockIdx.x & 15;
  int c  = (blockIdx.x >> 4) & 15;
  int b  = blockIdx.x >> 8;
  int t  = threadIdx.x;
  int sb = c * CHUNK + to * 8;
  const float* zxb = zx + (size_t)b * SEQ * D_PROJ + D_INNER;
  for (int r = 0; r < 11; r++) {
    int s = sb - 3 + r;
    const float* src = zxb + (size_t)s * D_PROJ;
    for (int ch = t; ch < CONV_DIM; ch += 256)
      srows[r * CONV_DIM + ch] = (s >= 0) ? src[ch] : 0.f;
  }
  __syncthreads();
  int bc = b * 16 + c;
#pragma unroll
  for (int k7 = 0; k7 < 7; k7++) {
    int ch = t + k7 * 256;
    float w0 = cw[ch * 4], w1 = cw[ch * 4 + 1];
    float w2 = cw[ch * 4 + 2], w3 = cw[ch * 4 + 3];
    float bias = cb[ch];
    float out[8];
#pragma unroll
    for (int j = 0; j < 8; j++) {
      float a = bias;
      a = fmaf(srows[(j + 0) * CONV_DIM + ch], w0, a);
      a = fmaf(srows[(j + 1) * CONV_DIM + ch], w1, a);
      a = fmaf(srows[(j + 2) * CONV_DIM + ch], w2, a);
      a = fmaf(srows[(j + 3) * CONV_DIM + ch], w3, a);
      out[j] = siluf(a);
    }
    if (ch < D_INNER) {
      int h = ch >> 6, p = ch & 63;
      bf16x8 v;
#pragma unroll
      for (int j = 0; j < 8; j++) v[j] = (__bf16)out[j];
      *(bf16x8*)&xA[((((size_t)bc * 24 + h) * 16 + to) * 64 + p) * 8] = v;
    } else if (ch < D_INNER + D_STATE) {
      int n = ch - D_INNER;
      bf16x8 v;
#pragma unroll
      for (int j = 0; j < 8; j++) v[j] = (__bf16)out[j];
      *(bf16x8*)&Bkt[(((size_t)bc * 16 + to) * 128 + n) * 8] = v;
      __hip_bfloat16* dst = Bkn + (size_t)bc * 16384 + ((n >> 3) * 128) * 8 + (n & 7);
#pragma unroll
      for (int j = 0; j < 8; j++)
        dst[(to * 8 + j) * 8] = __float2bfloat16(out[j]);
    } else {
      int n = ch - D_INNER - D_STATE;
      __hip_bfloat16* dst = Ckn + (size_t)bc * 16384 + ((n >> 3) * 128) * 8 + (n & 7);
#pragma unroll
      for (int j = 0; j < 8; j++)
        dst[(to * 8 + j) * 8] = __float2bfloat16(out[j]);
    }
  }
}

// ssd_state: H[p][n] = sum_tau (wdt[tau]*x[tau][p]) * B[tau][n] via MFMA.
// Writes bf16 contribution directly in h-tile layout [no(16)][p(64)][8].
__global__ __launch_bounds__(256) void ssd_state_kernel(
    const __hip_bfloat16* __restrict__ xA, const __hip_bfloat16* __restrict__ Bkt,
    const float* __restrict__ dtbuf, const float* __restrict__ cum2buf,
    __hip_bfloat16* __restrict__ states) {
  __shared__ __bf16 sX[8192];
  __shared__ __bf16 sB[16384];
  __shared__ float swdt[128];
  int c = blockIdx.x & 15;
  int h = (blockIdx.x >> 4) % NHEADS;
  int b = blockIdx.x / (16 * NHEADS);
  int t = threadIdx.x;
  int l = t & 63, w = t >> 6;
  const __hip_bfloat16* xsrc = xA + ((size_t)(b * 16 + c) * 24 + h) * 8192;
  const __hip_bfloat16* bsrc = Bkt + (size_t)(b * 16 + c) * 16384;
#pragma unroll
  for (int i = 0; i < 4; i++) GLL(xsrc + (i * 256 + t) * 8, &sX[(i * 256 + t) * 8]);
#pragma unroll
  for (int i = 0; i < 8; i++) GLL(bsrc + (i * 256 + t) * 8, &sB[(i * 256 + t) * 8]);
  {
    size_t dto = ((size_t)b * NHEADS + h) * SEQ + c * CHUNK;
    if (t < 128) {
      float total2 = cum2buf[dto + 127];
      swdt[t] = dtbuf[dto + t] * exp2f(total2 - cum2buf[dto + t]);
    }
  }
  __syncthreads();
#pragma unroll
  for (int i = 0; i < 4; i++) {
    int o = i * 256 + t;
    int to = o >> 6;
    bf16x8 v = *(bf16x8*)&sX[o * 8];
#pragma unroll
    for (int j = 0; j < 8; j++)
      v[j] = (__bf16)((float)v[j] * swdt[to * 8 + j]);
    *(bf16x8*)&sX[o * 8] = v;
  }
  __syncthreads();
  int n0w = w * 32;
  f32x4 acc[4][2];
#pragma unroll
  for (int i = 0; i < 4; i++)
#pragma unroll
    for (int j = 0; j < 2; j++) acc[i][j] = (f32x4)0.f;
#pragma unroll
  for (int kk = 0; kk < 4; kk++) {
    int ko = kk * 4 + (l >> 4);
    bf16x8 av[4], bv[2];
#pragma unroll
    for (int mi = 0; mi < 4; mi++)
      av[mi] = *(const bf16x8*)&sX[(ko * 64 + mi * 16 + (l & 15)) * 8];
#pragma unroll
    for (int ni = 0; ni < 2; ni++)
      bv[ni] = *(const bf16x8*)&sB[(ko * 128 + n0w + ni * 16 + (l & 15)) * 8];
#pragma unroll
    for (int mi = 0; mi < 4; mi++)
#pragma unroll
      for (int ni = 0; ni < 2; ni++)
        acc[mi][ni] = __builtin_amdgcn_mfma_f32_16x16x32_bf16(
            av[mi], bv[ni], acc[mi][ni], 0, 0, 0);
  }
  __hip_bfloat16* dst = states + (((size_t)b * NHEADS + h) * 16 + c) * 8192;
#pragma unroll
  for (int mi = 0; mi < 4; mi++)
#pragma unroll
    for (int ni = 0; ni < 2; ni++) {
      int n = n0w + ni * 16 + (l & 15);
#pragma unroll
      for (int r = 0; r < 4; r++) {
        int p = mi * 16 + (l >> 4) * 4 + r;
        dst[((n >> 3) * 64 + p) * 8 + (n & 7)] = __float2bfloat16(acc[mi][ni][r]);
      }
    }
}

// chunkscan: in-place exclusive prefix over c (16 steps), bf16 tiles.
__global__ __launch_bounds__(256) void ssd_chunkscan_kernel(
    __hip_bfloat16* __restrict__ states, const float* __restrict__ cum2buf) {
  int q = blockIdx.x & 3;
  int bh = blockIdx.x >> 2;
  int t = threadIdx.x;
  int o = q * 256 + t;
  __hip_bfloat16* base = states + (size_t)bh * NCHUNK * 8192 + (size_t)o * 8;
  const float* c2 = cum2buf + (size_t)bh * SEQ;
  float hacc[8];
#pragma unroll
  for (int j = 0; j < 8; j++) hacc[j] = 0.f;
  for (int c = 0; c < NCHUNK; c++) {
    float eA = exp2f(c2[c * 128 + 127]);
    __hip_bfloat16* p = base + (size_t)c * 8192;
    bf16x8 v = *(bf16x8*)p;
    bf16x8 wv;
#pragma unroll
    for (int j = 0; j < 8; j++) {
      float tmp = (float)v[j];
      wv[j] = (__bf16)hacc[j];
      hacc[j] = fmaf(eA, hacc[j], tmp);
    }
    *(bf16x8*)p = wv;
  }
}

// ssd_output: G = C.B^T -> mask/decay in-register -> Y1 = S.x ; Y2 = C.h^T
// LDS 80KB (2 WG/CU): sC 32K | sBS 32K (B then S) | sXH 16K (x then h_prev)
__global__ __launch_bounds__(256) void ssd_output_kernel(
    const __hip_bfloat16* __restrict__ Ckn, const __hip_bfloat16* __restrict__ Bkn,
    const __hip_bfloat16* __restrict__ xA, const __hip_bfloat16* __restrict__ states,
    const float* __restrict__ dtbuf, const float* __restrict__ cum2buf,
    const float* __restrict__ D_skip, __hip_bfloat16* __restrict__ y) {
  __shared__ __bf16 sC[16384];
  __shared__ __bf16 sBS[16384];
  __shared__ __bf16 sXH[8192];
  int c = blockIdx.x & 15;
  int h = (blockIdx.x >> 4) % NHEADS;
  int b = blockIdx.x / (16 * NHEADS);
  int t = threadIdx.x;
  int l = t & 63, w = t >> 6;
  int bc = b * 16 + c;
  const __hip_bfloat16* csrc = Ckn + (size_t)bc * 16384;
  const __hip_bfloat16* bsrc = Bkn + (size_t)bc * 16384;
  const __hip_bfloat16* xsrc = xA + ((size_t)bc * 24 + h) * 8192;
#pragma unroll
  for (int i = 0; i < 8; i++) GLL(csrc + (i * 256 + t) * 8, &sC[(i * 256 + t) * 8]);
#pragma unroll
  for (int i = 0; i < 8; i++) GLL(bsrc + (i * 256 + t) * 8, &sBS[(i * 256 + t) * 8]);
#pragma unroll
  for (int i = 0; i < 4; i++) GLL(xsrc + (i * 256 + t) * 8, &sXH[(i * 256 + t) * 8]);

  size_t dto = ((size_t)b * NHEADS + h) * SEQ + c * CHUNK;
  float cum2_t[8], cum2_tau[8], dt_tau[8];
#pragma unroll
  for (int fm = 0; fm < 2; fm++)
#pragma unroll
    for (int r = 0; r < 4; r++)
      cum2_t[fm * 4 + r] = cum2buf[dto + w * 32 + fm * 16 + (l >> 4) * 4 + r];
#pragma unroll
  for (int fc = 0; fc < 8; fc++) {
    cum2_tau[fc] = cum2buf[dto + fc * 16 + (l & 15)];
    dt_tau[fc] = dtbuf[dto + fc * 16 + (l & 15)];
  }
  float Dh = D_skip[h];
  __syncthreads();

  // GEMM1: G[t][tau], this wave's t-rows = [w*32, w*32+32)
  f32x4 g[2][8];
#pragma unroll
  for (int i = 0; i < 2; i++)
#pragma unroll
    for (int j = 0; j < 8; j++) g[i][j] = (f32x4)0.f;
#pragma unroll
  for (int kk = 0; kk < 4; kk++) {
    int ko = kk * 4 + (l >> 4);
    bf16x8 a0 = *(const bf16x8*)&sC[(ko * 128 + w * 32 + (l & 15)) * 8];
    bf16x8 a1 = *(const bf16x8*)&sC[(ko * 128 + w * 32 + 16 + (l & 15)) * 8];
#pragma unroll
    for (int fc = 0; fc < 8; fc++) {
      bf16x8 bv = *(const bf16x8*)&sBS[(ko * 128 + fc * 16 + (l & 15)) * 8];
      g[0][fc] = __builtin_amdgcn_mfma_f32_16x16x32_bf16(a0, bv, g[0][fc], 0, 0, 0);
      g[1][fc] = __builtin_amdgcn_mfma_f32_16x16x32_bf16(a1, bv, g[1][fc], 0, 0, 0);
    }
  }
  __syncthreads();  // all waves done reading B before S overwrites it

  // mask + decay + dt (+D on diag) -> S bf16 into sBS [to][t][8]
#pragma unroll
  for (int fm = 0; fm < 2; fm++)
#pragma unroll
    for (int fc = 0; fc < 8; fc++) {
      int tau = fc * 16 + (l & 15);
#pragma unroll
      for (int r = 0; r < 4; r++) {
        int tt = w * 32 + fm * 16 + (l >> 4) * 4 + r;
        float v = 0.f;
        if (tt >= tau) {
          v = exp2f(cum2_t[fm * 4 + r] - cum2_tau[fc]) * dt_tau[fc] * g[fm][fc][r];
          if (tt == tau) v += Dh;
        }
        sBS[((tau >> 3) * 128 + tt) * 8 + (tau & 7)] = (__bf16)v;
      }
    }
  // GEMM2 reads only rows this wave wrote -> wave-local dep, no barrier.
  f32x4 y1[2][4];
#pragma unroll
  for (int i = 0; i < 2; i++)
#pragma unroll
    for (int j = 0; j < 4; j++) y1[i][j] = (f32x4)0.f;
#pragma unroll
  for (int kk = 0; kk < 4; kk++) {
    int ko = kk * 4 + (l >> 4);
    bf16x8 a0 = *(const bf16x8*)&sBS[(ko * 128 + w * 32 + (l & 15)) * 8];
    bf16x8 a1 = *(const bf16x8*)&sBS[(ko * 128 + w * 32 + 16 + (l & 15)) * 8];
#pragma unroll
    for (int fc = 0; fc < 4; fc++) {
      bf16x8 bv = *(const bf16x8*)&sXH[(ko * 64 + fc * 16 + (l & 15)) * 8];
      y1[0][fc] = __builtin_amdgcn_mfma_f32_16x16x32_bf16(a0, bv, y1[0][fc], 0, 0, 0);
      y1[1][fc] = __builtin_amdgcn_mfma_f32_16x16x32_bf16(a1, bv, y1[1][fc], 0, 0, 0);
    }
  }
  __syncthreads();  // all waves done with x before h_prev overwrites it
  const __hip_bfloat16* hsrc = states + (((size_t)b * NHEADS + h) * 16 + c) * 8192;
#pragma unroll
  for (int i = 0; i < 4; i++) GLL(hsrc + (i * 256 + t) * 8, &sXH[(i * 256 + t) * 8]);
  __syncthreads();

  // GEMM3: Y2[t][p] = sum_n C[t][n] * h_prev[p][n]
  f32x4 y2[2][4];
#pragma unroll
  for (int i = 0; i < 2; i++)
#pragma unroll
    for (int j = 0; j < 4; j++) y2[i][j] = (f32x4)0.f;
#pragma unroll
  for (int kk = 0; kk < 4; kk++) {
    int ko = kk * 4 + (l >> 4);
    bf16x8 a0 = *(const bf16x8*)&sC[(ko * 128 + w * 32 + (l & 15)) * 8];
    bf16x8 a1 = *(const bf16x8*)&sC[(ko * 128 + w * 32 + 16 + (l & 15)) * 8];
#pragma unroll
    for (int fc = 0; fc < 4; fc++) {
      bf16x8 bv = *(const bf16x8*)&sXH[(ko * 64 + fc * 16 + (l & 15)) * 8];
      y2[0][fc] = __builtin_amdgcn_mfma_f32_16x16x32_bf16(a0, bv, y2[0][fc], 0, 0, 0);
      y2[1][fc] = __builtin_amdgcn_mfma_f32_16x16x32_bf16(a1, bv, y2[1][fc], 0, 0, 0);
    }
  }

  __hip_bfloat16* yr = y + ((size_t)b * SEQ + c * CHUNK) * D_INNER + h * 64;
#pragma unroll
  for (int fm = 0; fm < 2; fm++)
#pragma unroll
    for (int r = 0; r < 4; r++) {
      int tt = w * 32 + fm * 16 + (l >> 4) * 4 + r;
      float sdec = exp2f(cum2_t[fm * 4 + r]);
#pragma unroll
      for (int fc = 0; fc < 4; fc++) {
        int p = fc * 16 + (l & 15);
        yr[(size_t)tt * D_INNER + p] =
            __float2bfloat16(y1[fm][fc][r] + sdec * y2[fm][fc][r]);
      }
    }
}

// ---------- y(bf16) * silu(z) then rmsnorm(1536), in-place bf16 -----------
__global__ __launch_bounds__(256) void gate_norm_kernel(
    __hip_bfloat16* __restrict__ y, const float* __restrict__ zx,
    const float* __restrict__ gw) {
  int row = blockIdx.x;
  const float* z = zx + (size_t)row * D_PROJ;
  __hip_bfloat16* yr = y + (size_t)row * D_INNER;
  int t = threadIdx.x;
  float vals[6];
  float ss = 0.f;
#pragma unroll
  for (int j = 0; j < 6; j++) {
    int c = t + j * 256;
    float zv = z[c];
    float v = __bfloat162float(yr[c]) * (zv / (1.f + expf(-zv)));
    vals[j] = v;
    ss += v * v;
  }
  __shared__ float sred[4];
  ss = warp_reduce_sum(ss);
  if ((t & 63) == 0) sred[t >> 6] = ss;
  __syncthreads();
  float tot = sred[0] + sred[1] + sred[2] + sred[3];
  float inv = rsqrtf(tot / (float)D_INNER + 1e-5f);
#pragma unroll
  for (int j = 0; j < 6; j++) {
    int c = t + j * 256;
    yr[c] = __float2bfloat16(gw[c] * vals[j] * inv);
  }
}

// ---------------------------------------------------------------------------
extern "C" void kernel_launch(void* const* d_in, const int* in_sizes, int n_in,
                              void* d_out, int out_size, void* d_ws, size_t ws_size,
                              hipStream_t stream) {
  const float* x          = (const float*)d_in[0];
  const float* in_proj_w  = (const float*)d_in[1];
  const float* conv_w     = (const float*)d_in[2];
  const float* conv_b     = (const float*)d_in[3];
  const float* dt_bias    = (const float*)d_in[4];
  const float* A_log      = (const float*)d_in[5];
  const float* D_skip     = (const float*)d_in[6];
  const float* gnorm_w    = (const float*)d_in[7];
  const float* out_proj_w = (const float*)d_in[8];
  const float* ln_w       = (const float*)d_in[9];
  const float* final_ln_w = (const float*)d_in[10];

  // ws total ~238.5 MB
  float* ws = (float*)d_ws;
  float* curx   = ws; ws += (size_t)NROWS * D_MODEL;           // 25.2 MB
  float* zxbuf  = ws; ws += (size_t)NROWS * D_PROJ;            // 109.8 MB
  float* dtbuf  = ws; ws += (size_t)BATCH * NHEADS * SEQ;      // 0.8 MB
  float* cum2   = ws; ws += (size_t)BATCH * NHEADS * SEQ;      // 0.8 MB
  __hip_bfloat16* hbuf_b = (__hip_bfloat16*)ws; ws += (size_t)NROWS * D_MODEL / 2;   // 12.6
  __hip_bfloat16* ybuf_b = (__hip_bfloat16*)ws; ws += (size_t)NROWS * D_INNER / 2;   // 25.2
  __hip_bfloat16* wi_b   = (__hip_bfloat16*)ws; ws += (size_t)D_PROJ * D_MODEL / 2;  // 5.2
  __hip_bfloat16* wo_b   = (__hip_bfloat16*)ws; ws += (size_t)D_MODEL * D_INNER / 2; // 2.4
  __hip_bfloat16* xAb    = (__hip_bfloat16*)ws; ws += (size_t)BATCH * NCHUNK * 24 * 8192 / 2; // 25.2
  __hip_bfloat16* Bkt    = (__hip_bfloat16*)ws; ws += (size_t)BATCH * NCHUNK * 16384 / 2;     // 2.1
  __hip_bfloat16* Bkn    = (__hip_bfloat16*)ws; ws += (size_t)BATCH * NCHUNK * 16384 / 2;     // 2.1
  __hip_bfloat16* Ckn    = (__hip_bfloat16*)ws; ws += (size_t)BATCH * NCHUNK * 16384 / 2;     // 2.1
  __hip_bfloat16* states = (__hip_bfloat16*)ws;                                               // 25.2

  for (int l = 0; l < NUM_LAYERS; l++) {
    const float* xin = (l == 0) ? x : curx;
    f32_to_bf16_kernel<<<512, 256, 0, stream>>>(
        in_proj_w + (size_t)l * D_PROJ * D_MODEL, wi_b, (size_t)D_PROJ * D_MODEL);
    f32_to_bf16_kernel<<<512, 256, 0, stream>>>(
        out_proj_w + (size_t)l * D_MODEL * D_INNER, wo_b, (size_t)D_MODEL * D_INNER);

    rmsnorm768_kernel<__hip_bfloat16><<<NROWS, 256, 0, stream>>>(
        xin, ln_w + (size_t)l * D_MODEL, hbuf_b, 1e-6f);

    gemm_bf16_kernel<<<64 * 27, 256, 0, stream>>>(
        hbuf_b, wi_b, nullptr, zxbuf, NROWS, D_PROJ, D_MODEL);

    dt_kernel<<<BATCH * NHEADS * NCHUNK, 128, 0, stream>>>(
        zxbuf, dt_bias + l * NHEADS, A_log + l * NHEADS, dtbuf, cum2);

    conv_tiles_kernel<<<BATCH * NCHUNK * 16, 256, 0, stream>>>(
        zxbuf, conv_w + (size_t)l * CONV_DIM * D_CONV,
        conv_b + (size_t)l * CONV_DIM, xAb, Bkt, Bkn, Ckn);

    ssd_state_kernel<<<BATCH * NHEADS * NCHUNK, 256, 0, stream>>>(
        xAb, Bkt, dtbuf, cum2, states);

    ssd_chunkscan_kernel<<<BATCH * NHEADS * 4, 256, 0, stream>>>(states, cum2);

    ssd_output_kernel<<<BATCH * NHEADS * NCHUNK, 256, 0, stream>>>(
        Ckn, Bkn, xAb, states, dtbuf, cum2, D_skip + l * NHEADS, ybuf_b);

    gate_norm_kernel<<<NROWS, 256, 0, stream>>>(
        ybuf_b, zxbuf, gnorm_w + (size_t)l * D_INNER);

    gemm_bf16_kernel<<<64 * 6, 256, 0, stream>>>(
        ybuf_b, wo_b, xin, curx, NROWS, D_MODEL, D_INNER);
  }
  rmsnorm768_kernel<float><<<NROWS, 256, 0, stream>>>(
      curx, final_ln_w, (float*)d_out, 1e-6f);
}

// Round 6
// 1129.740 us; speedup vs baseline: 14.9990x; 1.2164x over previous
//
#include <hip/hip_runtime.h>
#include <hip/hip_bf16.h>
#include <math.h>

#define NUM_LAYERS 4
#define D_MODEL 768
#define D_STATE 128
#define D_CONV 4
#define HEADDIM 64
#define D_INNER 1536
#define NHEADS 24
#define CONV_DIM 1792
#define D_PROJ 3352
#define BATCH 4
#define SEQ 2048
#define NROWS (BATCH*SEQ)   /* 8192 */
#define CHUNK 128
#define NCHUNK (SEQ/CHUNK)  /* 16 */
#define LOG2E 1.4426950408889634f

typedef __bf16 bf16x8 __attribute__((ext_vector_type(8)));
typedef float f32x4 __attribute__((ext_vector_type(4)));

#define GLL(gsrc, ldst)                                                        \
  __builtin_amdgcn_global_load_lds(                                            \
      (const __attribute__((address_space(1))) unsigned int*)(gsrc),           \
      (__attribute__((address_space(3))) unsigned int*)(ldst), 16, 0, 0)

__device__ __forceinline__ float warp_reduce_sum(float v) {
  v += __shfl_xor(v, 32);
  v += __shfl_xor(v, 16);
  v += __shfl_xor(v, 8);
  v += __shfl_xor(v, 4);
  v += __shfl_xor(v, 2);
  v += __shfl_xor(v, 1);
  return v;
}

__device__ __forceinline__ float softplusf(float x) {
  return (x > 20.f) ? x : log1pf(expf(x));
}
__device__ __forceinline__ float siluf(float x) {
  return x / (1.f + expf(-x));
}

__device__ __forceinline__ void store_val(float v, float* p) { *p = v; }
__device__ __forceinline__ void store_val(float v, __hip_bfloat16* p) {
  *p = __float2bfloat16(v);
}

// -------------------- f32 -> bf16 bulk convert -----------------------------
__global__ __launch_bounds__(256) void f32_to_bf16_kernel(
    const float* __restrict__ in, __hip_bfloat16* __restrict__ out, size_t n) {
  for (size_t i = ((size_t)blockIdx.x * 256 + threadIdx.x) * 4; i < n;
       i += (size_t)gridDim.x * 256 * 4) {
    float4 v = *(const float4*)(in + i);
    __hip_bfloat16 h0 = __float2bfloat16(v.x), h1 = __float2bfloat16(v.y);
    __hip_bfloat16 h2 = __float2bfloat16(v.z), h3 = __float2bfloat16(v.w);
    ushort4 u;
    u.x = *(unsigned short*)&h0; u.y = *(unsigned short*)&h1;
    u.z = *(unsigned short*)&h2; u.w = *(unsigned short*)&h3;
    *(ushort4*)(out + i) = u;
  }
}

// -------------------- rmsnorm over 768 (templated output dtype) ------------
template <typename OUT>
__global__ __launch_bounds__(256) void rmsnorm768_kernel(
    const float* __restrict__ in, const float* __restrict__ w,
    OUT* __restrict__ out, float eps) {
  int row = blockIdx.x;
  const float* x = in + (size_t)row * D_MODEL;
  OUT* o = out + (size_t)row * D_MODEL;
  int t = threadIdx.x;
  float v0 = x[t], v1 = x[t + 256], v2 = x[t + 512];
  float ss = v0 * v0 + v1 * v1 + v2 * v2;
  __shared__ float sred[4];
  ss = warp_reduce_sum(ss);
  if ((t & 63) == 0) sred[t >> 6] = ss;
  __syncthreads();
  float tot = sred[0] + sred[1] + sred[2] + sred[3];
  float inv = rsqrtf(tot / (float)D_MODEL + eps);
  store_val(w[t] * v0 * inv, o + t);
  store_val(w[t + 256] * v1 * inv, o + t + 256);
  store_val(w[t + 512] * v2 * inv, o + t + 512);
}

// =========== shared MFMA main-loop macro (128x128 tile, BK=32) =============
#define GEMM_PROLOGUE_AND_MAINLOOP(Asrc, Wsrc, Kdim)                           \
  int t = threadIdx.x;                                                         \
  int w = t >> 6, l = t & 63;                                                  \
  int NT = (Kdim) >> 5;                                                        \
  int ldsA0 = (w * 64) * 8;                                                    \
  int ldsA1 = (256 + w * 64) * 8;                                              \
  int lr = l & 15, lk = l >> 4;                                                \
  int wr = w >> 1, wc = w & 1;                                                 \
  int aoff = (lk * 128 + wr * 64 + lr) * 8;                                    \
  int boff = (lk * 128 + wc * 64 + lr) * 8;                                    \
  f32x4 acc[4][4];                                                             \
  _Pragma("unroll") for (int i = 0; i < 4; i++)                                \
      _Pragma("unroll") for (int j = 0; j < 4; j++) acc[i][j] = (f32x4)0.f;    \
  STAGE(0, 0);                                                                 \
  for (int kt = 0; kt < NT; ++kt) {                                            \
    int cur = kt & 1;                                                          \
    if (kt + 1 < NT) {                                                         \
      STAGE(cur ^ 1, (kt + 1) * 32);                                           \
      asm volatile("s_waitcnt vmcnt(4)" ::: "memory");                         \
    } else {                                                                   \
      asm volatile("s_waitcnt vmcnt(0)" ::: "memory");                         \
    }                                                                          \
    __builtin_amdgcn_sched_barrier(0);                                         \
    __builtin_amdgcn_s_barrier();                                              \
    __builtin_amdgcn_sched_barrier(0);                                         \
    bf16x8 av[4], bv[4];                                                       \
    _Pragma("unroll") for (int mi = 0; mi < 4; mi++)                           \
        av[mi] = *(const bf16x8*)&At[cur][aoff + mi * 128];                    \
    _Pragma("unroll") for (int ni = 0; ni < 4; ni++)                           \
        bv[ni] = *(const bf16x8*)&Bt[cur][boff + ni * 128];                    \
    _Pragma("unroll") for (int mi = 0; mi < 4; mi++)                           \
        _Pragma("unroll") for (int ni = 0; ni < 4; ni++)                       \
            acc[mi][ni] = __builtin_amdgcn_mfma_f32_16x16x32_bf16(             \
                av[mi], bv[ni], acc[mi][ni], 0, 0, 0);                         \
    __builtin_amdgcn_sched_barrier(0);                                         \
    __builtin_amdgcn_s_barrier();                                              \
  }

#define STAGE(buf, kofs)                                                       \
  do {                                                                         \
    GLL(Aptr + (kofs), &At[buf][ldsA0]);                                       \
    GLL(Aptr + (kofs) + 16, &At[buf][ldsA1]);                                  \
    GLL(Wptr + (kofs), &Bt[buf][ldsA0]);                                       \
    GLL(Wptr + (kofs) + 16, &Bt[buf][ldsA1]);                                  \
  } while (0)

// ===== generic GEMM: C[M][N](f32) = A[M][K](bf16) * W[N][K]^T (+res) =======
// bn-fastest within each XCD chunk -> A-panel L2 reuse.
__global__ __launch_bounds__(256) void gemm_bf16_kernel(
    const __hip_bfloat16* __restrict__ A, const __hip_bfloat16* __restrict__ W,
    const float* __restrict__ res, float* __restrict__ C,
    int M, int N, int K) {
  __shared__ __bf16 At[2][4096];
  __shared__ __bf16 Bt[2][4096];
  int cpx = gridDim.x >> 3;
  int bid = blockIdx.x;
  int bid2 = (bid & 7) * cpx + (bid >> 3);
  int nbn = (N + 127) >> 7;
  int bn = bid2 % nbn;
  int bm = bid2 / nbn;
  int m0 = bm * 128, n0 = bn * 128;
  int srow = threadIdx.x & 127;
  int kbase = (threadIdx.x >> 7) * 8;
  const __hip_bfloat16* Aptr = A + (size_t)(m0 + srow) * K + kbase;
  int nrow = n0 + srow; if (nrow >= N) nrow = N - 1;
  const __hip_bfloat16* Wptr = W + (size_t)nrow * K + kbase;

  GEMM_PROLOGUE_AND_MAINLOOP(A, W, K)

  int rbase = (l >> 4) * 4;
#pragma unroll
  for (int ni = 0; ni < 4; ni++) {
    int n = n0 + wc * 64 + ni * 16 + (l & 15);
    if (n >= N) continue;
#pragma unroll
    for (int mi = 0; mi < 4; mi++) {
#pragma unroll
      for (int r = 0; r < 4; r++) {
        int m = m0 + wr * 64 + mi * 16 + rbase + r;
        float v = acc[mi][ni][r];
        if (res) v += res[(size_t)m * N + n];
        C[(size_t)m * N + n] = v;
      }
    }
  }
}

// ===== in_proj GEMM with split epilogue: z(bf16) | xBC(bf16) | dt(f32) =====
__global__ __launch_bounds__(256) void gemm_inproj_kernel(
    const __hip_bfloat16* __restrict__ A, const __hip_bfloat16* __restrict__ W,
    __hip_bfloat16* __restrict__ zout, __hip_bfloat16* __restrict__ xout,
    float* __restrict__ dtout) {
  const int K = D_MODEL, N = D_PROJ;
  __shared__ __bf16 At[2][4096];
  __shared__ __bf16 Bt[2][4096];
  int cpx = gridDim.x >> 3;                  // 216
  int bid = blockIdx.x;
  int bid2 = (bid & 7) * cpx + (bid >> 3);
  int bn = bid2 % 27;
  int bm = bid2 / 27;
  int m0 = bm * 128, n0 = bn * 128;
  int srow = threadIdx.x & 127;
  int kbase = (threadIdx.x >> 7) * 8;
  const __hip_bfloat16* Aptr = A + (size_t)(m0 + srow) * K + kbase;
  int nrow = n0 + srow; if (nrow >= N) nrow = N - 1;
  const __hip_bfloat16* Wptr = W + (size_t)nrow * K + kbase;

  GEMM_PROLOGUE_AND_MAINLOOP(A, W, K)

  int rbase = (l >> 4) * 4;
  if (bn < 12) {                       // z region, cols n0..n0+127 < 1536
#pragma unroll
    for (int ni = 0; ni < 4; ni++) {
      int n = n0 + wc * 64 + ni * 16 + (l & 15);
#pragma unroll
      for (int mi = 0; mi < 4; mi++)
#pragma unroll
        for (int r = 0; r < 4; r++) {
          int m = m0 + wr * 64 + mi * 16 + rbase + r;
          zout[(size_t)m * D_INNER + n] = __float2bfloat16(acc[mi][ni][r]);
        }
    }
  } else if (bn < 26) {                // xBC region
    int nb = n0 - D_INNER;
#pragma unroll
    for (int ni = 0; ni < 4; ni++) {
      int n = nb + wc * 64 + ni * 16 + (l & 15);
#pragma unroll
      for (int mi = 0; mi < 4; mi++)
#pragma unroll
        for (int r = 0; r < 4; r++) {
          int m = m0 + wr * 64 + mi * 16 + rbase + r;
          xout[(size_t)m * CONV_DIM + n] = __float2bfloat16(acc[mi][ni][r]);
        }
    }
  } else {                             // dt region: cols 3328..3351 (24)
#pragma unroll
    for (int ni = 0; ni < 4; ni++) {
      int col = wc * 64 + ni * 16 + (l & 15);
      if (col >= 24) continue;
#pragma unroll
      for (int mi = 0; mi < 4; mi++)
#pragma unroll
        for (int r = 0; r < 4; r++) {
          int m = m0 + wr * 64 + mi * 16 + rbase + r;
          dtout[(size_t)m * 24 + col] = acc[mi][ni][r];
        }
    }
  }
}

// ======================= chunked SSD (MFMA) ================================
// dt_kernel: softplus + within-chunk inclusive prefix of dt*A (log2-scaled)
__global__ __launch_bounds__(128) void dt_kernel(
    const float* __restrict__ dtraw, const float* __restrict__ dt_bias,
    const float* __restrict__ A_log, float* __restrict__ dtbuf,
    float* __restrict__ cum2buf) {
  int c = blockIdx.x & 15;
  int h = (blockIdx.x >> 4) % NHEADS;
  int b = blockIdx.x / (16 * NHEADS);
  int t = threadIdx.x;
  int s = c * CHUNK + t;
  float Ah = -expf(A_log[h]);
  float raw = dtraw[((size_t)b * SEQ + s) * 24 + h] + dt_bias[h];
  float dt = softplusf(raw);
  __shared__ float sc[128];
  sc[t] = dt * Ah;
  __syncthreads();
  for (int off = 1; off < 128; off <<= 1) {
    float v = (t >= off) ? sc[t - off] : 0.f;
    __syncthreads();
    sc[t] += v;
    __syncthreads();
  }
  size_t o = ((size_t)b * NHEADS + h) * SEQ + s;
  dtbuf[o] = dt;
  cum2buf[o] = sc[t] * LOG2E;
}

// conv_tiles: conv(k=4)+bias+silu once (bf16 input); emit bf16 MFMA tiles.
//  xA : [b][c][h][to(16)][p(64)][8]   (k = tau)
//  Bkt: [b][c][to(16)][n(128)][8]     (k = tau)
//  Bkn: [b][c][no(16)][tau(128)][8]   (k = n)
//  Ckn: [b][c][no(16)][t(128)][8]     (k = n)
__global__ __launch_bounds__(256) void conv_tiles_kernel(
    const __hip_bfloat16* __restrict__ xbc, const float* __restrict__ cw,
    const float* __restrict__ cb, __hip_bfloat16* __restrict__ xA,
    __hip_bfloat16* __restrict__ Bkt, __hip_bfloat16* __restrict__ Bkn,
    __hip_bfloat16* __restrict__ Ckn) {
  __shared__ float srows[11 * CONV_DIM];
  int to = blockIdx.x & 15;
  int c  = (blockIdx.x >> 4) & 15;
  int b  = blockIdx.x >> 8;
  int t  = threadIdx.x;
  int sb = c * CHUNK + to * 8;
  const __hip_bfloat16* base = xbc + (size_t)b * SEQ * CONV_DIM;
  for (int e = t; e < 11 * 224; e += 256) {
    int r = e / 224, c8 = (e - r * 224) * 8;
    int s = sb - 3 + r;
    float* dst = &srows[r * CONV_DIM + c8];
    if (s >= 0) {
      bf16x8 v = *(const bf16x8*)&base[(size_t)s * CONV_DIM + c8];
#pragma unroll
      for (int j = 0; j < 8; j++) dst[j] = (float)v[j];
    } else {
#pragma unroll
      for (int j = 0; j < 8; j++) dst[j] = 0.f;
    }
  }
  __syncthreads();
  int bc = b * 16 + c;
#pragma unroll
  for (int k7 = 0; k7 < 7; k7++) {
    int ch = t + k7 * 256;
    float w0 = cw[ch * 4], w1 = cw[ch * 4 + 1];
    float w2 = cw[ch * 4 + 2], w3 = cw[ch * 4 + 3];
    float bias = cb[ch];
    float out[8];
#pragma unroll
    for (int j = 0; j < 8; j++) {
      float a = bias;
      a = fmaf(srows[(j + 0) * CONV_DIM + ch], w0, a);
      a = fmaf(srows[(j + 1) * CONV_DIM + ch], w1, a);
      a = fmaf(srows[(j + 2) * CONV_DIM + ch], w2, a);
      a = fmaf(srows[(j + 3) * CONV_DIM + ch], w3, a);
      out[j] = siluf(a);
    }
    if (ch < D_INNER) {
      int h = ch >> 6, p = ch & 63;
      bf16x8 v;
#pragma unroll
      for (int j = 0; j < 8; j++) v[j] = (__bf16)out[j];
      *(bf16x8*)&xA[((((size_t)bc * 24 + h) * 16 + to) * 64 + p) * 8] = v;
    } else if (ch < D_INNER + D_STATE) {
      int n = ch - D_INNER;
      bf16x8 v;
#pragma unroll
      for (int j = 0; j < 8; j++) v[j] = (__bf16)out[j];
      *(bf16x8*)&Bkt[(((size_t)bc * 16 + to) * 128 + n) * 8] = v;
      __hip_bfloat16* dst = Bkn + (size_t)bc * 16384 + ((n >> 3) * 128) * 8 + (n & 7);
#pragma unroll
      for (int j = 0; j < 8; j++)
        dst[(to * 8 + j) * 8] = __float2bfloat16(out[j]);
    } else {
      int n = ch - D_INNER - D_STATE;
      __hip_bfloat16* dst = Ckn + (size_t)bc * 16384 + ((n >> 3) * 128) * 8 + (n & 7);
#pragma unroll
      for (int j = 0; j < 8; j++)
        dst[(to * 8 + j) * 8] = __float2bfloat16(out[j]);
    }
  }
}

// ssd_state: H[p][n] = sum_tau (wdt[tau]*x[tau][p]) * B[tau][n] via MFMA.
__global__ __launch_bounds__(256) void ssd_state_kernel(
    const __hip_bfloat16* __restrict__ xA, const __hip_bfloat16* __restrict__ Bkt,
    const float* __restrict__ dtbuf, const float* __restrict__ cum2buf,
    __hip_bfloat16* __restrict__ states) {
  __shared__ __bf16 sX[8192];
  __shared__ __bf16 sB[16384];
  __shared__ float swdt[128];
  int c = blockIdx.x & 15;
  int h = (blockIdx.x >> 4) % NHEADS;
  int b = blockIdx.x / (16 * NHEADS);
  int t = threadIdx.x;
  int l = t & 63, w = t >> 6;
  const __hip_bfloat16* xsrc = xA + ((size_t)(b * 16 + c) * 24 + h) * 8192;
  const __hip_bfloat16* bsrc = Bkt + (size_t)(b * 16 + c) * 16384;
#pragma unroll
  for (int i = 0; i < 4; i++) GLL(xsrc + (i * 256 + t) * 8, &sX[(i * 256 + t) * 8]);
#pragma unroll
  for (int i = 0; i < 8; i++) GLL(bsrc + (i * 256 + t) * 8, &sB[(i * 256 + t) * 8]);
  {
    size_t dto = ((size_t)b * NHEADS + h) * SEQ + c * CHUNK;
    if (t < 128) {
      float total2 = cum2buf[dto + 127];
      swdt[t] = dtbuf[dto + t] * exp2f(total2 - cum2buf[dto + t]);
    }
  }
  __syncthreads();
#pragma unroll
  for (int i = 0; i < 4; i++) {
    int o = i * 256 + t;
    int to = o >> 6;
    bf16x8 v = *(bf16x8*)&sX[o * 8];
#pragma unroll
    for (int j = 0; j < 8; j++)
      v[j] = (__bf16)((float)v[j] * swdt[to * 8 + j]);
    *(bf16x8*)&sX[o * 8] = v;
  }
  __syncthreads();
  int n0w = w * 32;
  f32x4 acc[4][2];
#pragma unroll
  for (int i = 0; i < 4; i++)
#pragma unroll
    for (int j = 0; j < 2; j++) acc[i][j] = (f32x4)0.f;
#pragma unroll
  for (int kk = 0; kk < 4; kk++) {
    int ko = kk * 4 + (l >> 4);
    bf16x8 av[4], bv[2];
#pragma unroll
    for (int mi = 0; mi < 4; mi++)
      av[mi] = *(const bf16x8*)&sX[(ko * 64 + mi * 16 + (l & 15)) * 8];
#pragma unroll
    for (int ni = 0; ni < 2; ni++)
      bv[ni] = *(const bf16x8*)&sB[(ko * 128 + n0w + ni * 16 + (l & 15)) * 8];
#pragma unroll
    for (int mi = 0; mi < 4; mi++)
#pragma unroll
      for (int ni = 0; ni < 2; ni++)
        acc[mi][ni] = __builtin_amdgcn_mfma_f32_16x16x32_bf16(
            av[mi], bv[ni], acc[mi][ni], 0, 0, 0);
  }
  __hip_bfloat16* dst = states + (((size_t)b * NHEADS + h) * 16 + c) * 8192;
#pragma unroll
  for (int mi = 0; mi < 4; mi++)
#pragma unroll
    for (int ni = 0; ni < 2; ni++) {
      int n = n0w + ni * 16 + (l & 15);
#pragma unroll
      for (int r = 0; r < 4; r++) {
        int p = mi * 16 + (l >> 4) * 4 + r;
        dst[((n >> 3) * 64 + p) * 8 + (n & 7)] = __float2bfloat16(acc[mi][ni][r]);
      }
    }
}

// chunkscan: in-place exclusive prefix over c (16 steps), bf16 tiles.
__global__ __launch_bounds__(256) void ssd_chunkscan_kernel(
    __hip_bfloat16* __restrict__ states, const float* __restrict__ cum2buf) {
  int q = blockIdx.x & 3;
  int bh = blockIdx.x >> 2;
  int t = threadIdx.x;
  int o = q * 256 + t;
  __hip_bfloat16* base = states + (size_t)bh * NCHUNK * 8192 + (size_t)o * 8;
  const float* c2 = cum2buf + (size_t)bh * SEQ;
  float hacc[8];
#pragma unroll
  for (int j = 0; j < 8; j++) hacc[j] = 0.f;
  for (int c = 0; c < NCHUNK; c++) {
    float eA = exp2f(c2[c * 128 + 127]);
    __hip_bfloat16* p = base + (size_t)c * 8192;
    bf16x8 v = *(bf16x8*)p;
    bf16x8 wv;
#pragma unroll
    for (int j = 0; j < 8; j++) {
      float tmp = (float)v[j];
      wv[j] = (__bf16)hacc[j];
      hacc[j] = fmaf(eA, hacc[j], tmp);
    }
    *(bf16x8*)p = wv;
  }
}

// ssd_output: G = C.B^T -> mask/decay in-register -> Y1 = S.x ; Y2 = C.h^T
__global__ __launch_bounds__(256) void ssd_output_kernel(
    const __hip_bfloat16* __restrict__ Ckn, const __hip_bfloat16* __restrict__ Bkn,
    const __hip_bfloat16* __restrict__ xA, const __hip_bfloat16* __restrict__ states,
    const float* __restrict__ dtbuf, const float* __restrict__ cum2buf,
    const float* __restrict__ D_skip, __hip_bfloat16* __restrict__ y) {
  __shared__ __bf16 sC[16384];
  __shared__ __bf16 sBS[16384];
  __shared__ __bf16 sXH[8192];
  int c = blockIdx.x & 15;
  int h = (blockIdx.x >> 4) % NHEADS;
  int b = blockIdx.x / (16 * NHEADS);
  int t = threadIdx.x;
  int l = t & 63, w = t >> 6;
  int bc = b * 16 + c;
  const __hip_bfloat16* csrc = Ckn + (size_t)bc * 16384;
  const __hip_bfloat16* bsrc = Bkn + (size_t)bc * 16384;
  const __hip_bfloat16* xsrc = xA + ((size_t)bc * 24 + h) * 8192;
#pragma unroll
  for (int i = 0; i < 8; i++) GLL(csrc + (i * 256 + t) * 8, &sC[(i * 256 + t) * 8]);
#pragma unroll
  for (int i = 0; i < 8; i++) GLL(bsrc + (i * 256 + t) * 8, &sBS[(i * 256 + t) * 8]);
#pragma unroll
  for (int i = 0; i < 4; i++) GLL(xsrc + (i * 256 + t) * 8, &sXH[(i * 256 + t) * 8]);

  size_t dto = ((size_t)b * NHEADS + h) * SEQ + c * CHUNK;
  float cum2_t[8], cum2_tau[8], dt_tau[8];
#pragma unroll
  for (int fm = 0; fm < 2; fm++)
#pragma unroll
    for (int r = 0; r < 4; r++)
      cum2_t[fm * 4 + r] = cum2buf[dto + w * 32 + fm * 16 + (l >> 4) * 4 + r];
#pragma unroll
  for (int fc = 0; fc < 8; fc++) {
    cum2_tau[fc] = cum2buf[dto + fc * 16 + (l & 15)];
    dt_tau[fc] = dtbuf[dto + fc * 16 + (l & 15)];
  }
  float Dh = D_skip[h];
  __syncthreads();

  f32x4 g[2][8];
#pragma unroll
  for (int i = 0; i < 2; i++)
#pragma unroll
    for (int j = 0; j < 8; j++) g[i][j] = (f32x4)0.f;
#pragma unroll
  for (int kk = 0; kk < 4; kk++) {
    int ko = kk * 4 + (l >> 4);
    bf16x8 a0 = *(const bf16x8*)&sC[(ko * 128 + w * 32 + (l & 15)) * 8];
    bf16x8 a1 = *(const bf16x8*)&sC[(ko * 128 + w * 32 + 16 + (l & 15)) * 8];
#pragma unroll
    for (int fc = 0; fc < 8; fc++) {
      bf16x8 bv = *(const bf16x8*)&sBS[(ko * 128 + fc * 16 + (l & 15)) * 8];
      g[0][fc] = __builtin_amdgcn_mfma_f32_16x16x32_bf16(a0, bv, g[0][fc], 0, 0, 0);
      g[1][fc] = __builtin_amdgcn_mfma_f32_16x16x32_bf16(a1, bv, g[1][fc], 0, 0, 0);
    }
  }
  __syncthreads();  // all waves done reading B before S overwrites it

#pragma unroll
  for (int fm = 0; fm < 2; fm++)
#pragma unroll
    for (int fc = 0; fc < 8; fc++) {
      int tau = fc * 16 + (l & 15);
#pragma unroll
      for (int r = 0; r < 4; r++) {
        int tt = w * 32 + fm * 16 + (l >> 4) * 4 + r;
        float v = 0.f;
        if (tt >= tau) {
          v = exp2f(cum2_t[fm * 4 + r] - cum2_tau[fc]) * dt_tau[fc] * g[fm][fc][r];
          if (tt == tau) v += Dh;
        }
        sBS[((tau >> 3) * 128 + tt) * 8 + (tau & 7)] = (__bf16)v;
      }
    }
  f32x4 y1[2][4];
#pragma unroll
  for (int i = 0; i < 2; i++)
#pragma unroll
    for (int j = 0; j < 4; j++) y1[i][j] = (f32x4)0.f;
#pragma unroll
  for (int kk = 0; kk < 4; kk++) {
    int ko = kk * 4 + (l >> 4);
    bf16x8 a0 = *(const bf16x8*)&sBS[(ko * 128 + w * 32 + (l & 15)) * 8];
    bf16x8 a1 = *(const bf16x8*)&sBS[(ko * 128 + w * 32 + 16 + (l & 15)) * 8];
#pragma unroll
    for (int fc = 0; fc < 4; fc++) {
      bf16x8 bv = *(const bf16x8*)&sXH[(ko * 64 + fc * 16 + (l & 15)) * 8];
      y1[0][fc] = __builtin_amdgcn_mfma_f32_16x16x32_bf16(a0, bv, y1[0][fc], 0, 0, 0);
      y1[1][fc] = __builtin_amdgcn_mfma_f32_16x16x32_bf16(a1, bv, y1[1][fc], 0, 0, 0);
    }
  }
  __syncthreads();  // all waves done with x before h_prev overwrites it
  const __hip_bfloat16* hsrc = states + (((size_t)b * NHEADS + h) * 16 + c) * 8192;
#pragma unroll
  for (int i = 0; i < 4; i++) GLL(hsrc + (i * 256 + t) * 8, &sXH[(i * 256 + t) * 8]);
  __syncthreads();

  f32x4 y2[2][4];
#pragma unroll
  for (int i = 0; i < 2; i++)
#pragma unroll
    for (int j = 0; j < 4; j++) y2[i][j] = (f32x4)0.f;
#pragma unroll
  for (int kk = 0; kk < 4; kk++) {
    int ko = kk * 4 + (l >> 4);
    bf16x8 a0 = *(const bf16x8*)&sC[(ko * 128 + w * 32 + (l & 15)) * 8];
    bf16x8 a1 = *(const bf16x8*)&sC[(ko * 128 + w * 32 + 16 + (l & 15)) * 8];
#pragma unroll
    for (int fc = 0; fc < 4; fc++) {
      bf16x8 bv = *(const bf16x8*)&sXH[(ko * 64 + fc * 16 + (l & 15)) * 8];
      y2[0][fc] = __builtin_amdgcn_mfma_f32_16x16x32_bf16(a0, bv, y2[0][fc], 0, 0, 0);
      y2[1][fc] = __builtin_amdgcn_mfma_f32_16x16x32_bf16(a1, bv, y2[1][fc], 0, 0, 0);
    }
  }

  __hip_bfloat16* yr = y + ((size_t)b * SEQ + c * CHUNK) * D_INNER + h * 64;
#pragma unroll
  for (int fm = 0; fm < 2; fm++)
#pragma unroll
    for (int r = 0; r < 4; r++) {
      int tt = w * 32 + fm * 16 + (l >> 4) * 4 + r;
      float sdec = exp2f(cum2_t[fm * 4 + r]);
#pragma unroll
      for (int fc = 0; fc < 4; fc++) {
        int p = fc * 16 + (l & 15);
        yr[(size_t)tt * D_INNER + p] =
            __float2bfloat16(y1[fm][fc][r] + sdec * y2[fm][fc][r]);
      }
    }
}

// ---- y(bf16) * silu(z bf16) then rmsnorm(1536); 192 thr, bf16x8 ----------
__global__ __launch_bounds__(192) void gate_norm_kernel(
    __hip_bfloat16* __restrict__ y, const __hip_bfloat16* __restrict__ z,
    const float* __restrict__ gw) {
  int row = blockIdx.x;
  const __hip_bfloat16* zr = z + (size_t)row * D_INNER;
  __hip_bfloat16* yr = y + (size_t)row * D_INNER;
  int t = threadIdx.x;
  bf16x8 yv = *(const bf16x8*)&yr[t * 8];
  bf16x8 zv = *(const bf16x8*)&zr[t * 8];
  float vals[8];
  float ss = 0.f;
#pragma unroll
  for (int j = 0; j < 8; j++) {
    float zf = (float)zv[j];
    float v = (float)yv[j] * siluf(zf);
    vals[j] = v;
    ss += v * v;
  }
  __shared__ float sred[3];
  ss = warp_reduce_sum(ss);
  if ((t & 63) == 0) sred[t >> 6] = ss;
  __syncthreads();
  float tot = sred[0] + sred[1] + sred[2];
  float inv = rsqrtf(tot / (float)D_INNER + 1e-5f);
  bf16x8 o;
#pragma unroll
  for (int j = 0; j < 8; j++)
    o[j] = (__bf16)(gw[t * 8 + j] * vals[j] * inv);
  *(bf16x8*)&yr[t * 8] = o;
}

// ---------------------------------------------------------------------------
extern "C" void kernel_launch(void* const* d_in, const int* in_sizes, int n_in,
                              void* d_out, int out_size, void* d_ws, size_t ws_size,
                              hipStream_t stream) {
  const float* x          = (const float*)d_in[0];
  const float* in_proj_w  = (const float*)d_in[1];
  const float* conv_w     = (const float*)d_in[2];
  const float* conv_b     = (const float*)d_in[3];
  const float* dt_bias    = (const float*)d_in[4];
  const float* A_log      = (const float*)d_in[5];
  const float* D_skip     = (const float*)d_in[6];
  const float* gnorm_w    = (const float*)d_in[7];
  const float* out_proj_w = (const float*)d_in[8];
  const float* ln_w       = (const float*)d_in[9];
  const float* final_ln_w = (const float*)d_in[10];

  // ws total ~206 MB
  float* ws = (float*)d_ws;
  float* curx   = ws; ws += (size_t)NROWS * D_MODEL;           // 25.2 MB
  float* dtraw  = ws; ws += (size_t)NROWS * 24;                // 0.8
  float* dtbuf  = ws; ws += (size_t)BATCH * NHEADS * SEQ;      // 0.8
  float* cum2   = ws; ws += (size_t)BATCH * NHEADS * SEQ;      // 0.8
  __hip_bfloat16* zbuf   = (__hip_bfloat16*)ws; ws += (size_t)NROWS * D_INNER / 2;   // 25.2
  __hip_bfloat16* xbcbuf = (__hip_bfloat16*)ws; ws += (size_t)NROWS * CONV_DIM / 2;  // 29.4
  __hip_bfloat16* hbuf_b = (__hip_bfloat16*)ws; ws += (size_t)NROWS * D_MODEL / 2;   // 12.6
  __hip_bfloat16* ybuf_b = (__hip_bfloat16*)ws; ws += (size_t)NROWS * D_INNER / 2;   // 25.2
  __hip_bfloat16* wi_b   = (__hip_bfloat16*)ws; ws += (size_t)NUM_LAYERS * D_PROJ * D_MODEL / 2;   // 20.6
  __hip_bfloat16* wo_b   = (__hip_bfloat16*)ws; ws += (size_t)NUM_LAYERS * D_MODEL * D_INNER / 2;  // 9.4
  __hip_bfloat16* xAb    = (__hip_bfloat16*)ws; ws += (size_t)BATCH * NCHUNK * 24 * 8192 / 2; // 25.2
  __hip_bfloat16* Bkt    = (__hip_bfloat16*)ws; ws += (size_t)BATCH * NCHUNK * 16384 / 2;     // 2.1
  __hip_bfloat16* Bkn    = (__hip_bfloat16*)ws; ws += (size_t)BATCH * NCHUNK * 16384 / 2;     // 2.1
  __hip_bfloat16* Ckn    = (__hip_bfloat16*)ws; ws += (size_t)BATCH * NCHUNK * 16384 / 2;     // 2.1
  __hip_bfloat16* states = (__hip_bfloat16*)ws;                                               // 25.2

  f32_to_bf16_kernel<<<1024, 256, 0, stream>>>(
      in_proj_w, wi_b, (size_t)NUM_LAYERS * D_PROJ * D_MODEL);
  f32_to_bf16_kernel<<<1024, 256, 0, stream>>>(
      out_proj_w, wo_b, (size_t)NUM_LAYERS * D_MODEL * D_INNER);

  for (int l = 0; l < NUM_LAYERS; l++) {
    const float* xin = (l == 0) ? x : curx;
    rmsnorm768_kernel<__hip_bfloat16><<<NROWS, 256, 0, stream>>>(
        xin, ln_w + (size_t)l * D_MODEL, hbuf_b, 1e-6f);

    gemm_inproj_kernel<<<64 * 27, 256, 0, stream>>>(
        hbuf_b, wi_b + (size_t)l * D_PROJ * D_MODEL, zbuf, xbcbuf, dtraw);

    dt_kernel<<<BATCH * NHEADS * NCHUNK, 128, 0, stream>>>(
        dtraw, dt_bias + l * NHEADS, A_log + l * NHEADS, dtbuf, cum2);

    conv_tiles_kernel<<<BATCH * NCHUNK * 16, 256, 0, stream>>>(
        xbcbuf, conv_w + (size_t)l * CONV_DIM * D_CONV,
        conv_b + (size_t)l * CONV_DIM, xAb, Bkt, Bkn, Ckn);

    ssd_state_kernel<<<BATCH * NHEADS * NCHUNK, 256, 0, stream>>>(
        xAb, Bkt, dtbuf, cum2, states);

    ssd_chunkscan_kernel<<<BATCH * NHEADS * 4, 256, 0, stream>>>(states, cum2);

    ssd_output_kernel<<<BATCH * NHEADS * NCHUNK, 256, 0, stream>>>(
        Ckn, Bkn, xAb, states, dtbuf, cum2, D_skip + l * NHEADS, ybuf_b);

    gate_norm_kernel<<<NROWS, 192, 0, stream>>>(
        ybuf_b, zbuf, gnorm_w + (size_t)l * D_INNER);

    gemm_bf16_kernel<<<64 * 6, 256, 0, stream>>>(
        ybuf_b, wo_b + (size_t)l * D_MODEL * D_INNER, xin, curx,
        NROWS, D_MODEL, D_INNER);
  }
  rmsnorm768_kernel<float><<<NROWS, 256, 0, stream>>>(
      curx, final_ln_w, (float*)d_out, 1e-6f);
}

// Round 7
// 1078.830 us; speedup vs baseline: 15.7068x; 1.0472x over previous
//
#include <hip/hip_runtime.h>
#include <hip/hip_bf16.h>
#include <math.h>

#define NUM_LAYERS 4
#define D_MODEL 768
#define D_STATE 128
#define D_CONV 4
#define HEADDIM 64
#define D_INNER 1536
#define NHEADS 24
#define CONV_DIM 1792
#define D_PROJ 3352
#define BATCH 4
#define SEQ 2048
#define NROWS (BATCH*SEQ)   /* 8192 */
#define CHUNK 128
#define NCHUNK (SEQ/CHUNK)  /* 16 */
#define LOG2E 1.4426950408889634f

typedef __bf16 bf16x8 __attribute__((ext_vector_type(8)));
typedef float f32x4 __attribute__((ext_vector_type(4)));

#define GLL(gsrc, ldst)                                                        \
  __builtin_amdgcn_global_load_lds(                                            \
      (const __attribute__((address_space(1))) unsigned int*)(gsrc),           \
      (__attribute__((address_space(3))) unsigned int*)(ldst), 16, 0, 0)

__device__ __forceinline__ float warp_reduce_sum(float v) {
  v += __shfl_xor(v, 32);
  v += __shfl_xor(v, 16);
  v += __shfl_xor(v, 8);
  v += __shfl_xor(v, 4);
  v += __shfl_xor(v, 2);
  v += __shfl_xor(v, 1);
  return v;
}

__device__ __forceinline__ float softplusf(float x) {
  return (x > 20.f) ? x : log1pf(expf(x));
}
__device__ __forceinline__ float siluf(float x) {
  return x / (1.f + expf(-x));
}

__device__ __forceinline__ void store_val(float v, float* p) { *p = v; }
__device__ __forceinline__ void store_val(float v, __hip_bfloat16* p) {
  *p = __float2bfloat16(v);
}

// -------------------- f32 -> bf16 bulk convert -----------------------------
__global__ __launch_bounds__(256) void f32_to_bf16_kernel(
    const float* __restrict__ in, __hip_bfloat16* __restrict__ out, size_t n) {
  for (size_t i = ((size_t)blockIdx.x * 256 + threadIdx.x) * 4; i < n;
       i += (size_t)gridDim.x * 256 * 4) {
    float4 v = *(const float4*)(in + i);
    __hip_bfloat16 h0 = __float2bfloat16(v.x), h1 = __float2bfloat16(v.y);
    __hip_bfloat16 h2 = __float2bfloat16(v.z), h3 = __float2bfloat16(v.w);
    ushort4 u;
    u.x = *(unsigned short*)&h0; u.y = *(unsigned short*)&h1;
    u.z = *(unsigned short*)&h2; u.w = *(unsigned short*)&h3;
    *(ushort4*)(out + i) = u;
  }
}

// -------------------- rmsnorm over 768 (templated output dtype) ------------
template <typename OUT>
__global__ __launch_bounds__(256) void rmsnorm768_kernel(
    const float* __restrict__ in, const float* __restrict__ w,
    OUT* __restrict__ out, float eps) {
  int row = blockIdx.x;
  const float* x = in + (size_t)row * D_MODEL;
  OUT* o = out + (size_t)row * D_MODEL;
  int t = threadIdx.x;
  float v0 = x[t], v1 = x[t + 256], v2 = x[t + 512];
  float ss = v0 * v0 + v1 * v1 + v2 * v2;
  __shared__ float sred[4];
  ss = warp_reduce_sum(ss);
  if ((t & 63) == 0) sred[t >> 6] = ss;
  __syncthreads();
  float tot = sred[0] + sred[1] + sred[2] + sred[3];
  float inv = rsqrtf(tot / (float)D_MODEL + eps);
  store_val(w[t] * v0 * inv, o + t);
  store_val(w[t + 256] * v1 * inv, o + t + 256);
  store_val(w[t + 512] * v2 * inv, o + t + 512);
}

// =========== 128x128 MFMA main-loop macro (BK=32, 4 waves) =================
#define GEMM_PROLOGUE_AND_MAINLOOP(Asrc, Wsrc, Kdim)                           \
  int t = threadIdx.x;                                                         \
  int w = t >> 6, l = t & 63;                                                  \
  int NT = (Kdim) >> 5;                                                        \
  int ldsA0 = (w * 64) * 8;                                                    \
  int ldsA1 = (256 + w * 64) * 8;                                              \
  int lr = l & 15, lk = l >> 4;                                                \
  int wr = w >> 1, wc = w & 1;                                                 \
  int aoff = (lk * 128 + wr * 64 + lr) * 8;                                    \
  int boff = (lk * 128 + wc * 64 + lr) * 8;                                    \
  f32x4 acc[4][4];                                                             \
  _Pragma("unroll") for (int i = 0; i < 4; i++)                                \
      _Pragma("unroll") for (int j = 0; j < 4; j++) acc[i][j] = (f32x4)0.f;    \
  STAGE(0, 0);                                                                 \
  for (int kt = 0; kt < NT; ++kt) {                                            \
    int cur = kt & 1;                                                          \
    if (kt + 1 < NT) {                                                         \
      STAGE(cur ^ 1, (kt + 1) * 32);                                           \
      asm volatile("s_waitcnt vmcnt(4)" ::: "memory");                         \
    } else {                                                                   \
      asm volatile("s_waitcnt vmcnt(0)" ::: "memory");                         \
    }                                                                          \
    __builtin_amdgcn_sched_barrier(0);                                         \
    __builtin_amdgcn_s_barrier();                                              \
    __builtin_amdgcn_sched_barrier(0);                                         \
    bf16x8 av[4], bv[4];                                                       \
    _Pragma("unroll") for (int mi = 0; mi < 4; mi++)                           \
        av[mi] = *(const bf16x8*)&At[cur][aoff + mi * 128];                    \
    _Pragma("unroll") for (int ni = 0; ni < 4; ni++)                           \
        bv[ni] = *(const bf16x8*)&Bt[cur][boff + ni * 128];                    \
    __builtin_amdgcn_s_setprio(1);                                             \
    _Pragma("unroll") for (int mi = 0; mi < 4; mi++)                           \
        _Pragma("unroll") for (int ni = 0; ni < 4; ni++)                       \
            acc[mi][ni] = __builtin_amdgcn_mfma_f32_16x16x32_bf16(             \
                av[mi], bv[ni], acc[mi][ni], 0, 0, 0);                         \
    __builtin_amdgcn_s_setprio(0);                                             \
    __builtin_amdgcn_sched_barrier(0);                                         \
    __builtin_amdgcn_s_barrier();                                              \
  }

#define STAGE(buf, kofs)                                                       \
  do {                                                                         \
    GLL(Aptr + (kofs), &At[buf][ldsA0]);                                       \
    GLL(Aptr + (kofs) + 16, &At[buf][ldsA1]);                                  \
    GLL(Wptr + (kofs), &Bt[buf][ldsA0]);                                       \
    GLL(Wptr + (kofs) + 16, &Bt[buf][ldsA1]);                                  \
  } while (0)

// ===== generic GEMM (128x128): C[M][N](f32) = A * W^T (+res) ===============
__global__ __launch_bounds__(256) void gemm_bf16_kernel(
    const __hip_bfloat16* __restrict__ A, const __hip_bfloat16* __restrict__ W,
    const float* __restrict__ res, float* __restrict__ C,
    int M, int N, int K) {
  __shared__ __bf16 At[2][4096];
  __shared__ __bf16 Bt[2][4096];
  int cpx = gridDim.x >> 3;
  int bid = blockIdx.x;
  int bid2 = (bid & 7) * cpx + (bid >> 3);
  int nbn = (N + 127) >> 7;
  int bn = bid2 % nbn;
  int bm = bid2 / nbn;
  int m0 = bm * 128, n0 = bn * 128;
  int srow = threadIdx.x & 127;
  int kbase = (threadIdx.x >> 7) * 8;
  const __hip_bfloat16* Aptr = A + (size_t)(m0 + srow) * K + kbase;
  int nrow = n0 + srow; if (nrow >= N) nrow = N - 1;
  const __hip_bfloat16* Wptr = W + (size_t)nrow * K + kbase;

  GEMM_PROLOGUE_AND_MAINLOOP(A, W, K)

  int rbase = (l >> 4) * 4;
#pragma unroll
  for (int ni = 0; ni < 4; ni++) {
    int n = n0 + wc * 64 + ni * 16 + (l & 15);
    if (n >= N) continue;
#pragma unroll
    for (int mi = 0; mi < 4; mi++) {
#pragma unroll
      for (int r = 0; r < 4; r++) {
        int m = m0 + wr * 64 + mi * 16 + rbase + r;
        float v = acc[mi][ni][r];
        if (res) v += res[(size_t)m * N + n];
        C[(size_t)m * N + n] = v;
      }
    }
  }
}

// ===== in_proj GEMM: 256x256 tile, 8 waves, BK=32, split epilogue ==========
// N-tile boundaries align with regions: bn 0-5 = z (1536), 6-12 = xBC (1792),
// 13 = dt (24 of 256). 2-phase skeleton identical to 128x128 kernel.
__global__ __launch_bounds__(512, 2) void gemm_inproj_kernel(
    const __hip_bfloat16* __restrict__ A, const __hip_bfloat16* __restrict__ W,
    __hip_bfloat16* __restrict__ zout, __hip_bfloat16* __restrict__ xout,
    float* __restrict__ dtout) {
  const int K = D_MODEL, N = D_PROJ;
  __shared__ __bf16 At[2][8192];        // [oct(4)][row(256)][8]
  __shared__ __bf16 Bt[2][8192];
  int cpx = gridDim.x >> 3;             // 448/8 = 56
  int bid = blockIdx.x;
  int bid2 = (bid & 7) * cpx + (bid >> 3);
  int bn = bid2 % 14;
  int bm = bid2 / 14;
  int m0 = bm * 256, n0 = bn * 256;
  int t = threadIdx.x;
  int w = t >> 6, l = t & 63;

  // staging: idx = i*8+w -> oct = idx>>2, rowblock = idx&3; row = rb*64+l
  const __hip_bfloat16* Aptr[2];
  const __hip_bfloat16* Wptr[2];
  int dOff[2];
#pragma unroll
  for (int i = 0; i < 2; i++) {
    int idx = i * 8 + w;
    int oct = idx >> 2, rb = idx & 3;
    dOff[i] = oct * 2048 + rb * 512;
    Aptr[i] = A + (size_t)(m0 + rb * 64 + l) * K + oct * 8;
    int wrow = n0 + rb * 64 + l; if (wrow >= N) wrow = N - 1;
    Wptr[i] = W + (size_t)wrow * K + oct * 8;
  }

#define STAGE2(buf, kt)                                                        \
  do {                                                                         \
    _Pragma("unroll") for (int i = 0; i < 2; i++)                              \
        GLL(Aptr[i] + (kt) * 32, &At[buf][dOff[i]]);                           \
    _Pragma("unroll") for (int i = 0; i < 2; i++)                              \
        GLL(Wptr[i] + (kt) * 32, &Bt[buf][dOff[i]]);                           \
  } while (0)

  int lr = l & 15, lk = l >> 4;
  int wr = w >> 2, wc = w & 3;          // wave grid 2M x 4N; wave = 128M x 64N
  f32x4 acc[8][4];
#pragma unroll
  for (int i = 0; i < 8; i++)
#pragma unroll
    for (int j = 0; j < 4; j++) acc[i][j] = (f32x4)0.f;

  const int NT = 24;                    // K=768 / 32
  STAGE2(0, 0);
  for (int kt = 0; kt < NT; ++kt) {
    int cur = kt & 1;
    if (kt + 1 < NT) {
      STAGE2(cur ^ 1, kt + 1);
      asm volatile("s_waitcnt vmcnt(4)" ::: "memory");
    } else {
      asm volatile("s_waitcnt vmcnt(0)" ::: "memory");
    }
    __builtin_amdgcn_sched_barrier(0);
    __builtin_amdgcn_s_barrier();
    __builtin_amdgcn_sched_barrier(0);
    bf16x8 av[8], bv[4];
#pragma unroll
    for (int mi = 0; mi < 8; mi++)
      av[mi] = *(const bf16x8*)&At[cur][lk * 2048 + (wr * 128 + mi * 16 + lr) * 8];
#pragma unroll
    for (int ni = 0; ni < 4; ni++)
      bv[ni] = *(const bf16x8*)&Bt[cur][lk * 2048 + (wc * 64 + ni * 16 + lr) * 8];
    __builtin_amdgcn_s_setprio(1);
#pragma unroll
    for (int mi = 0; mi < 8; mi++)
#pragma unroll
      for (int ni = 0; ni < 4; ni++)
        acc[mi][ni] = __builtin_amdgcn_mfma_f32_16x16x32_bf16(
            av[mi], bv[ni], acc[mi][ni], 0, 0, 0);
    __builtin_amdgcn_s_setprio(0);
    __builtin_amdgcn_sched_barrier(0);
    __builtin_amdgcn_s_barrier();
  }
#undef STAGE2

  int rbase = (l >> 4) * 4;
  if (bn < 6) {                         // z region
#pragma unroll
    for (int ni = 0; ni < 4; ni++) {
      int n = n0 + wc * 64 + ni * 16 + lr;
#pragma unroll
      for (int mi = 0; mi < 8; mi++)
#pragma unroll
        for (int r = 0; r < 4; r++) {
          int m = m0 + wr * 128 + mi * 16 + rbase + r;
          zout[(size_t)m * D_INNER + n] = __float2bfloat16(acc[mi][ni][r]);
        }
    }
  } else if (bn < 13) {                 // xBC region
    int nb = n0 - D_INNER;
#pragma unroll
    for (int ni = 0; ni < 4; ni++) {
      int n = nb + wc * 64 + ni * 16 + lr;
#pragma unroll
      for (int mi = 0; mi < 8; mi++)
#pragma unroll
        for (int r = 0; r < 4; r++) {
          int m = m0 + wr * 128 + mi * 16 + rbase + r;
          xout[(size_t)m * CONV_DIM + n] = __float2bfloat16(acc[mi][ni][r]);
        }
    }
  } else {                              // dt region: 24 cols
#pragma unroll
    for (int ni = 0; ni < 4; ni++) {
      int loc = wc * 64 + ni * 16 + lr;
      if (loc >= 24) continue;
#pragma unroll
      for (int mi = 0; mi < 8; mi++)
#pragma unroll
        for (int r = 0; r < 4; r++) {
          int m = m0 + wr * 128 + mi * 16 + rbase + r;
          dtout[(size_t)m * 24 + loc] = acc[mi][ni][r];
        }
    }
  }
}

// ======================= chunked SSD (MFMA) ================================
// dt_kernel: softplus + within-chunk inclusive prefix of dt*A (log2-scaled)
__global__ __launch_bounds__(128) void dt_kernel(
    const float* __restrict__ dtraw, const float* __restrict__ dt_bias,
    const float* __restrict__ A_log, float* __restrict__ dtbuf,
    float* __restrict__ cum2buf) {
  int c = blockIdx.x & 15;
  int h = (blockIdx.x >> 4) % NHEADS;
  int b = blockIdx.x / (16 * NHEADS);
  int t = threadIdx.x;
  int s = c * CHUNK + t;
  float Ah = -expf(A_log[h]);
  float raw = dtraw[((size_t)b * SEQ + s) * 24 + h] + dt_bias[h];
  float dt = softplusf(raw);
  __shared__ float sc[128];
  sc[t] = dt * Ah;
  __syncthreads();
  for (int off = 1; off < 128; off <<= 1) {
    float v = (t >= off) ? sc[t - off] : 0.f;
    __syncthreads();
    sc[t] += v;
    __syncthreads();
  }
  size_t o = ((size_t)b * NHEADS + h) * SEQ + s;
  dtbuf[o] = dt;
  cum2buf[o] = sc[t] * LOG2E;
}

// conv_tiles: conv(k=4)+bias+silu once (bf16 input); emit bf16 MFMA tiles.
__global__ __launch_bounds__(256) void conv_tiles_kernel(
    const __hip_bfloat16* __restrict__ xbc, const float* __restrict__ cw,
    const float* __restrict__ cb, __hip_bfloat16* __restrict__ xA,
    __hip_bfloat16* __restrict__ Bkt, __hip_bfloat16* __restrict__ Bkn,
    __hip_bfloat16* __restrict__ Ckn) {
  __shared__ float srows[11 * CONV_DIM];
  int to = blockIdx.x & 15;
  int c  = (blockIdx.x >> 4) & 15;
  int b  = blockIdx.x >> 8;
  int t  = threadIdx.x;
  int sb = c * CHUNK + to * 8;
  const __hip_bfloat16* base = xbc + (size_t)b * SEQ * CONV_DIM;
  for (int e = t; e < 11 * 224; e += 256) {
    int r = e / 224, c8 = (e - r * 224) * 8;
    int s = sb - 3 + r;
    float* dst = &srows[r * CONV_DIM + c8];
    if (s >= 0) {
      bf16x8 v = *(const bf16x8*)&base[(size_t)s * CONV_DIM + c8];
#pragma unroll
      for (int j = 0; j < 8; j++) dst[j] = (float)v[j];
    } else {
#pragma unroll
      for (int j = 0; j < 8; j++) dst[j] = 0.f;
    }
  }
  __syncthreads();
  int bc = b * 16 + c;
#pragma unroll
  for (int k7 = 0; k7 < 7; k7++) {
    int ch = t + k7 * 256;
    float w0 = cw[ch * 4], w1 = cw[ch * 4 + 1];
    float w2 = cw[ch * 4 + 2], w3 = cw[ch * 4 + 3];
    float bias = cb[ch];
    float out[8];
#pragma unroll
    for (int j = 0; j < 8; j++) {
      float a = bias;
      a = fmaf(srows[(j + 0) * CONV_DIM + ch], w0, a);
      a = fmaf(srows[(j + 1) * CONV_DIM + ch], w1, a);
      a = fmaf(srows[(j + 2) * CONV_DIM + ch], w2, a);
      a = fmaf(srows[(j + 3) * CONV_DIM + ch], w3, a);
      out[j] = siluf(a);
    }
    if (ch < D_INNER) {
      int h = ch >> 6, p = ch & 63;
      bf16x8 v;
#pragma unroll
      for (int j = 0; j < 8; j++) v[j] = (__bf16)out[j];
      *(bf16x8*)&xA[((((size_t)bc * 24 + h) * 16 + to) * 64 + p) * 8] = v;
    } else if (ch < D_INNER + D_STATE) {
      int n = ch - D_INNER;
      bf16x8 v;
#pragma unroll
      for (int j = 0; j < 8; j++) v[j] = (__bf16)out[j];
      *(bf16x8*)&Bkt[(((size_t)bc * 16 + to) * 128 + n) * 8] = v;
      __hip_bfloat16* dst = Bkn + (size_t)bc * 16384 + ((n >> 3) * 128) * 8 + (n & 7);
#pragma unroll
      for (int j = 0; j < 8; j++)
        dst[(to * 8 + j) * 8] = __float2bfloat16(out[j]);
    } else {
      int n = ch - D_INNER - D_STATE;
      __hip_bfloat16* dst = Ckn + (size_t)bc * 16384 + ((n >> 3) * 128) * 8 + (n & 7);
#pragma unroll
      for (int j = 0; j < 8; j++)
        dst[(to * 8 + j) * 8] = __float2bfloat16(out[j]);
    }
  }
}

// ssd_state: H[p][n] = sum_tau (wdt[tau]*x[tau][p]) * B[tau][n] via MFMA.
__global__ __launch_bounds__(256) void ssd_state_kernel(
    const __hip_bfloat16* __restrict__ xA, const __hip_bfloat16* __restrict__ Bkt,
    const float* __restrict__ dtbuf, const float* __restrict__ cum2buf,
    __hip_bfloat16* __restrict__ states) {
  __shared__ __bf16 sX[8192];
  __shared__ __bf16 sB[16384];
  __shared__ float swdt[128];
  int c = blockIdx.x & 15;
  int h = (blockIdx.x >> 4) % NHEADS;
  int b = blockIdx.x / (16 * NHEADS);
  int t = threadIdx.x;
  int l = t & 63, w = t >> 6;
  const __hip_bfloat16* xsrc = xA + ((size_t)(b * 16 + c) * 24 + h) * 8192;
  const __hip_bfloat16* bsrc = Bkt + (size_t)(b * 16 + c) * 16384;
#pragma unroll
  for (int i = 0; i < 4; i++) GLL(xsrc + (i * 256 + t) * 8, &sX[(i * 256 + t) * 8]);
#pragma unroll
  for (int i = 0; i < 8; i++) GLL(bsrc + (i * 256 + t) * 8, &sB[(i * 256 + t) * 8]);
  {
    size_t dto = ((size_t)b * NHEADS + h) * SEQ + c * CHUNK;
    if (t < 128) {
      float total2 = cum2buf[dto + 127];
      swdt[t] = dtbuf[dto + t] * exp2f(total2 - cum2buf[dto + t]);
    }
  }
  __syncthreads();
#pragma unroll
  for (int i = 0; i < 4; i++) {
    int o = i * 256 + t;
    int to = o >> 6;
    bf16x8 v = *(bf16x8*)&sX[o * 8];
#pragma unroll
    for (int j = 0; j < 8; j++)
      v[j] = (__bf16)((float)v[j] * swdt[to * 8 + j]);
    *(bf16x8*)&sX[o * 8] = v;
  }
  __syncthreads();
  int n0w = w * 32;
  f32x4 acc[4][2];
#pragma unroll
  for (int i = 0; i < 4; i++)
#pragma unroll
    for (int j = 0; j < 2; j++) acc[i][j] = (f32x4)0.f;
#pragma unroll
  for (int kk = 0; kk < 4; kk++) {
    int ko = kk * 4 + (l >> 4);
    bf16x8 av[4], bv[2];
#pragma unroll
    for (int mi = 0; mi < 4; mi++)
      av[mi] = *(const bf16x8*)&sX[(ko * 64 + mi * 16 + (l & 15)) * 8];
#pragma unroll
    for (int ni = 0; ni < 2; ni++)
      bv[ni] = *(const bf16x8*)&sB[(ko * 128 + n0w + ni * 16 + (l & 15)) * 8];
#pragma unroll
    for (int mi = 0; mi < 4; mi++)
#pragma unroll
      for (int ni = 0; ni < 2; ni++)
        acc[mi][ni] = __builtin_amdgcn_mfma_f32_16x16x32_bf16(
            av[mi], bv[ni], acc[mi][ni], 0, 0, 0);
  }
  __hip_bfloat16* dst = states + (((size_t)b * NHEADS + h) * 16 + c) * 8192;
#pragma unroll
  for (int mi = 0; mi < 4; mi++)
#pragma unroll
    for (int ni = 0; ni < 2; ni++) {
      int n = n0w + ni * 16 + (l & 15);
#pragma unroll
      for (int r = 0; r < 4; r++) {
        int p = mi * 16 + (l >> 4) * 4 + r;
        dst[((n >> 3) * 64 + p) * 8 + (n & 7)] = __float2bfloat16(acc[mi][ni][r]);
      }
    }
}

// chunkscan: in-place exclusive prefix over c (16 steps), bf16 tiles.
__global__ __launch_bounds__(256) void ssd_chunkscan_kernel(
    __hip_bfloat16* __restrict__ states, const float* __restrict__ cum2buf) {
  int q = blockIdx.x & 3;
  int bh = blockIdx.x >> 2;
  int t = threadIdx.x;
  int o = q * 256 + t;
  __hip_bfloat16* base = states + (size_t)bh * NCHUNK * 8192 + (size_t)o * 8;
  const float* c2 = cum2buf + (size_t)bh * SEQ;
  float hacc[8];
#pragma unroll
  for (int j = 0; j < 8; j++) hacc[j] = 0.f;
  for (int c = 0; c < NCHUNK; c++) {
    float eA = exp2f(c2[c * 128 + 127]);
    __hip_bfloat16* p = base + (size_t)c * 8192;
    bf16x8 v = *(bf16x8*)p;
    bf16x8 wv;
#pragma unroll
    for (int j = 0; j < 8; j++) {
      float tmp = (float)v[j];
      wv[j] = (__bf16)hacc[j];
      hacc[j] = fmaf(eA, hacc[j], tmp);
    }
    *(bf16x8*)p = wv;
  }
}

// ssd_output: G = C.B^T -> mask/decay in-register -> Y1 = S.x ; Y2 = C.h^T
__global__ __launch_bounds__(256) void ssd_output_kernel(
    const __hip_bfloat16* __restrict__ Ckn, const __hip_bfloat16* __restrict__ Bkn,
    const __hip_bfloat16* __restrict__ xA, const __hip_bfloat16* __restrict__ states,
    const float* __restrict__ dtbuf, const float* __restrict__ cum2buf,
    const float* __restrict__ D_skip, __hip_bfloat16* __restrict__ y) {
  __shared__ __bf16 sC[16384];
  __shared__ __bf16 sBS[16384];
  __shared__ __bf16 sXH[8192];
  int c = blockIdx.x & 15;
  int h = (blockIdx.x >> 4) % NHEADS;
  int b = blockIdx.x / (16 * NHEADS);
  int t = threadIdx.x;
  int l = t & 63, w = t >> 6;
  int bc = b * 16 + c;
  const __hip_bfloat16* csrc = Ckn + (size_t)bc * 16384;
  const __hip_bfloat16* bsrc = Bkn + (size_t)bc * 16384;
  const __hip_bfloat16* xsrc = xA + ((size_t)bc * 24 + h) * 8192;
#pragma unroll
  for (int i = 0; i < 8; i++) GLL(csrc + (i * 256 + t) * 8, &sC[(i * 256 + t) * 8]);
#pragma unroll
  for (int i = 0; i < 8; i++) GLL(bsrc + (i * 256 + t) * 8, &sBS[(i * 256 + t) * 8]);
#pragma unroll
  for (int i = 0; i < 4; i++) GLL(xsrc + (i * 256 + t) * 8, &sXH[(i * 256 + t) * 8]);

  size_t dto = ((size_t)b * NHEADS + h) * SEQ + c * CHUNK;
  float cum2_t[8], cum2_tau[8], dt_tau[8];
#pragma unroll
  for (int fm = 0; fm < 2; fm++)
#pragma unroll
    for (int r = 0; r < 4; r++)
      cum2_t[fm * 4 + r] = cum2buf[dto + w * 32 + fm * 16 + (l >> 4) * 4 + r];
#pragma unroll
  for (int fc = 0; fc < 8; fc++) {
    cum2_tau[fc] = cum2buf[dto + fc * 16 + (l & 15)];
    dt_tau[fc] = dtbuf[dto + fc * 16 + (l & 15)];
  }
  float Dh = D_skip[h];
  __syncthreads();

  f32x4 g[2][8];
#pragma unroll
  for (int i = 0; i < 2; i++)
#pragma unroll
    for (int j = 0; j < 8; j++) g[i][j] = (f32x4)0.f;
#pragma unroll
  for (int kk = 0; kk < 4; kk++) {
    int ko = kk * 4 + (l >> 4);
    bf16x8 a0 = *(const bf16x8*)&sC[(ko * 128 + w * 32 + (l & 15)) * 8];
    bf16x8 a1 = *(const bf16x8*)&sC[(ko * 128 + w * 32 + 16 + (l & 15)) * 8];
#pragma unroll
    for (int fc = 0; fc < 8; fc++) {
      bf16x8 bv = *(const bf16x8*)&sBS[(ko * 128 + fc * 16 + (l & 15)) * 8];
      g[0][fc] = __builtin_amdgcn_mfma_f32_16x16x32_bf16(a0, bv, g[0][fc], 0, 0, 0);
      g[1][fc] = __builtin_amdgcn_mfma_f32_16x16x32_bf16(a1, bv, g[1][fc], 0, 0, 0);
    }
  }
  __syncthreads();  // all waves done reading B before S overwrites it

#pragma unroll
  for (int fm = 0; fm < 2; fm++)
#pragma unroll
    for (int fc = 0; fc < 8; fc++) {
      int tau = fc * 16 + (l & 15);
#pragma unroll
      for (int r = 0; r < 4; r++) {
        int tt = w * 32 + fm * 16 + (l >> 4) * 4 + r;
        float v = 0.f;
        if (tt >= tau) {
          v = exp2f(cum2_t[fm * 4 + r] - cum2_tau[fc]) * dt_tau[fc] * g[fm][fc][r];
          if (tt == tau) v += Dh;
        }
        sBS[((tau >> 3) * 128 + tt) * 8 + (tau & 7)] = (__bf16)v;
      }
    }
  f32x4 y1[2][4];
#pragma unroll
  for (int i = 0; i < 2; i++)
#pragma unroll
    for (int j = 0; j < 4; j++) y1[i][j] = (f32x4)0.f;
#pragma unroll
  for (int kk = 0; kk < 4; kk++) {
    int ko = kk * 4 + (l >> 4);
    bf16x8 a0 = *(const bf16x8*)&sBS[(ko * 128 + w * 32 + (l & 15)) * 8];
    bf16x8 a1 = *(const bf16x8*)&sBS[(ko * 128 + w * 32 + 16 + (l & 15)) * 8];
#pragma unroll
    for (int fc = 0; fc < 4; fc++) {
      bf16x8 bv = *(const bf16x8*)&sXH[(ko * 64 + fc * 16 + (l & 15)) * 8];
      y1[0][fc] = __builtin_amdgcn_mfma_f32_16x16x32_bf16(a0, bv, y1[0][fc], 0, 0, 0);
      y1[1][fc] = __builtin_amdgcn_mfma_f32_16x16x32_bf16(a1, bv, y1[1][fc], 0, 0, 0);
    }
  }
  __syncthreads();  // all waves done with x before h_prev overwrites it
  const __hip_bfloat16* hsrc = states + (((size_t)b * NHEADS + h) * 16 + c) * 8192;
#pragma unroll
  for (int i = 0; i < 4; i++) GLL(hsrc + (i * 256 + t) * 8, &sXH[(i * 256 + t) * 8]);
  __syncthreads();

  f32x4 y2[2][4];
#pragma unroll
  for (int i = 0; i < 2; i++)
#pragma unroll
    for (int j = 0; j < 4; j++) y2[i][j] = (f32x4)0.f;
#pragma unroll
  for (int kk = 0; kk < 4; kk++) {
    int ko = kk * 4 + (l >> 4);
    bf16x8 a0 = *(const bf16x8*)&sC[(ko * 128 + w * 32 + (l & 15)) * 8];
    bf16x8 a1 = *(const bf16x8*)&sC[(ko * 128 + w * 32 + 16 + (l & 15)) * 8];
#pragma unroll
    for (int fc = 0; fc < 4; fc++) {
      bf16x8 bv = *(const bf16x8*)&sXH[(ko * 64 + fc * 16 + (l & 15)) * 8];
      y2[0][fc] = __builtin_amdgcn_mfma_f32_16x16x32_bf16(a0, bv, y2[0][fc], 0, 0, 0);
      y2[1][fc] = __builtin_amdgcn_mfma_f32_16x16x32_bf16(a1, bv, y2[1][fc], 0, 0, 0);
    }
  }

  __hip_bfloat16* yr = y + ((size_t)b * SEQ + c * CHUNK) * D_INNER + h * 64;
#pragma unroll
  for (int fm = 0; fm < 2; fm++)
#pragma unroll
    for (int r = 0; r < 4; r++) {
      int tt = w * 32 + fm * 16 + (l >> 4) * 4 + r;
      float sdec = exp2f(cum2_t[fm * 4 + r]);
#pragma unroll
      for (int fc = 0; fc < 4; fc++) {
        int p = fc * 16 + (l & 15);
        yr[(size_t)tt * D_INNER + p] =
            __float2bfloat16(y1[fm][fc][r] + sdec * y2[fm][fc][r]);
      }
    }
}

// ---- y(bf16) * silu(z bf16) then rmsnorm(1536); 192 thr, bf16x8 ----------
__global__ __launch_bounds__(192) void gate_norm_kernel(
    __hip_bfloat16* __restrict__ y, const __hip_bfloat16* __restrict__ z,
    const float* __restrict__ gw) {
  int row = blockIdx.x;
  const __hip_bfloat16* zr = z + (size_t)row * D_INNER;
  __hip_bfloat16* yr = y + (size_t)row * D_INNER;
  int t = threadIdx.x;
  bf16x8 yv = *(const bf16x8*)&yr[t * 8];
  bf16x8 zv = *(const bf16x8*)&zr[t * 8];
  float vals[8];
  float ss = 0.f;
#pragma unroll
  for (int j = 0; j < 8; j++) {
    float zf = (float)zv[j];
    float v = (float)yv[j] * siluf(zf);
    vals[j] = v;
    ss += v * v;
  }
  __shared__ float sred[3];
  ss = warp_reduce_sum(ss);
  if ((t & 63) == 0) sred[t >> 6] = ss;
  __syncthreads();
  float tot = sred[0] + sred[1] + sred[2];
  float inv = rsqrtf(tot / (float)D_INNER + 1e-5f);
  bf16x8 o;
#pragma unroll
  for (int j = 0; j < 8; j++)
    o[j] = (__bf16)(gw[t * 8 + j] * vals[j] * inv);
  *(bf16x8*)&yr[t * 8] = o;
}

// ---------------------------------------------------------------------------
extern "C" void kernel_launch(void* const* d_in, const int* in_sizes, int n_in,
                              void* d_out, int out_size, void* d_ws, size_t ws_size,
                              hipStream_t stream) {
  const float* x          = (const float*)d_in[0];
  const float* in_proj_w  = (const float*)d_in[1];
  const float* conv_w     = (const float*)d_in[2];
  const float* conv_b     = (const float*)d_in[3];
  const float* dt_bias    = (const float*)d_in[4];
  const float* A_log      = (const float*)d_in[5];
  const float* D_skip     = (const float*)d_in[6];
  const float* gnorm_w    = (const float*)d_in[7];
  const float* out_proj_w = (const float*)d_in[8];
  const float* ln_w       = (const float*)d_in[9];
  const float* final_ln_w = (const float*)d_in[10];

  // ws total ~206 MB
  float* ws = (float*)d_ws;
  float* curx   = ws; ws += (size_t)NROWS * D_MODEL;           // 25.2 MB
  float* dtraw  = ws; ws += (size_t)NROWS * 24;                // 0.8
  float* dtbuf  = ws; ws += (size_t)BATCH * NHEADS * SEQ;      // 0.8
  float* cum2   = ws; ws += (size_t)BATCH * NHEADS * SEQ;      // 0.8
  __hip_bfloat16* zbuf   = (__hip_bfloat16*)ws; ws += (size_t)NROWS * D_INNER / 2;   // 25.2
  __hip_bfloat16* xbcbuf = (__hip_bfloat16*)ws; ws += (size_t)NROWS * CONV_DIM / 2;  // 29.4
  __hip_bfloat16* hbuf_b = (__hip_bfloat16*)ws; ws += (size_t)NROWS * D_MODEL / 2;   // 12.6
  __hip_bfloat16* ybuf_b = (__hip_bfloat16*)ws; ws += (size_t)NROWS * D_INNER / 2;   // 25.2
  __hip_bfloat16* wi_b   = (__hip_bfloat16*)ws; ws += (size_t)NUM_LAYERS * D_PROJ * D_MODEL / 2;   // 20.6
  __hip_bfloat16* wo_b   = (__hip_bfloat16*)ws; ws += (size_t)NUM_LAYERS * D_MODEL * D_INNER / 2;  // 9.4
  __hip_bfloat16* xAb    = (__hip_bfloat16*)ws; ws += (size_t)BATCH * NCHUNK * 24 * 8192 / 2; // 25.2
  __hip_bfloat16* Bkt    = (__hip_bfloat16*)ws; ws += (size_t)BATCH * NCHUNK * 16384 / 2;     // 2.1
  __hip_bfloat16* Bkn    = (__hip_bfloat16*)ws; ws += (size_t)BATCH * NCHUNK * 16384 / 2;     // 2.1
  __hip_bfloat16* Ckn    = (__hip_bfloat16*)ws; ws += (size_t)BATCH * NCHUNK * 16384 / 2;     // 2.1
  __hip_bfloat16* states = (__hip_bfloat16*)ws;                                               // 25.2

  f32_to_bf16_kernel<<<1024, 256, 0, stream>>>(
      in_proj_w, wi_b, (size_t)NUM_LAYERS * D_PROJ * D_MODEL);
  f32_to_bf16_kernel<<<1024, 256, 0, stream>>>(
      out_proj_w, wo_b, (size_t)NUM_LAYERS * D_MODEL * D_INNER);

  for (int l = 0; l < NUM_LAYERS; l++) {
    const float* xin = (l == 0) ? x : curx;
    rmsnorm768_kernel<__hip_bfloat16><<<NROWS, 256, 0, stream>>>(
        xin, ln_w + (size_t)l * D_MODEL, hbuf_b, 1e-6f);

    gemm_inproj_kernel<<<448, 512, 0, stream>>>(
        hbuf_b, wi_b + (size_t)l * D_PROJ * D_MODEL, zbuf, xbcbuf, dtraw);

    dt_kernel<<<BATCH * NHEADS * NCHUNK, 128, 0, stream>>>(
        dtraw, dt_bias + l * NHEADS, A_log + l * NHEADS, dtbuf, cum2);

    conv_tiles_kernel<<<BATCH * NCHUNK * 16, 256, 0, stream>>>(
        xbcbuf, conv_w + (size_t)l * CONV_DIM * D_CONV,
        conv_b + (size_t)l * CONV_DIM, xAb, Bkt, Bkn, Ckn);

    ssd_state_kernel<<<BATCH * NHEADS * NCHUNK, 256, 0, stream>>>(
        xAb, Bkt, dtbuf, cum2, states);

    ssd_chunkscan_kernel<<<BATCH * NHEADS * 4, 256, 0, stream>>>(states, cum2);

    ssd_output_kernel<<<BATCH * NHEADS * NCHUNK, 256, 0, stream>>>(
        Ckn, Bkn, xAb, states, dtbuf, cum2, D_skip + l * NHEADS, ybuf_b);

    gate_norm_kernel<<<NROWS, 192, 0, stream>>>(
        ybuf_b, zbuf, gnorm_w + (size_t)l * D_INNER);

    gemm_bf16_kernel<<<64 * 6, 256, 0, stream>>>(
        ybuf_b, wo_b + (size_t)l * D_MODEL * D_INNER, xin, curx,
        NROWS, D_MODEL, D_INNER);
  }
  rmsnorm768_kernel<float><<<NROWS, 256, 0, stream>>>(
      curx, final_ln_w, (float*)d_out, 1e-6f);
}

// Round 9
// 1068.551 us; speedup vs baseline: 15.8579x; 1.0096x over previous
//
#include <hip/hip_runtime.h>
#include <hip/hip_bf16.h>
#include <math.h>

#define NUM_LAYERS 4
#define D_MODEL 768
#define D_STATE 128
#define D_CONV 4
#define HEADDIM 64
#define D_INNER 1536
#define NHEADS 24
#define CONV_DIM 1792
#define D_PROJ 3352
#define BATCH 4
#define SEQ 2048
#define NROWS (BATCH*SEQ)   /* 8192 */
#define CHUNK 128
#define NCHUNK (SEQ/CHUNK)  /* 16 */
#define LOG2E 1.4426950408889634f

typedef __bf16 bf16x8 __attribute__((ext_vector_type(8)));
typedef float f32x4 __attribute__((ext_vector_type(4)));

#define GLL(gsrc, ldst)                                                        \
  __builtin_amdgcn_global_load_lds(                                            \
      (const __attribute__((address_space(1))) unsigned int*)(gsrc),           \
      (__attribute__((address_space(3))) unsigned int*)(ldst), 16, 0, 0)

__device__ __forceinline__ float warp_reduce_sum(float v) {
  v += __shfl_xor(v, 32);
  v += __shfl_xor(v, 16);
  v += __shfl_xor(v, 8);
  v += __shfl_xor(v, 4);
  v += __shfl_xor(v, 2);
  v += __shfl_xor(v, 1);
  return v;
}

__device__ __forceinline__ float softplusf(float x) {
  return (x > 20.f) ? x : log1pf(expf(x));
}
__device__ __forceinline__ float siluf(float x) {
  return x / (1.f + expf(-x));
}

__device__ __forceinline__ void store_val(float v, float* p) { *p = v; }
__device__ __forceinline__ void store_val(float v, __hip_bfloat16* p) {
  *p = __float2bfloat16(v);
}

// -------------------- f32 -> bf16 bulk convert -----------------------------
__global__ __launch_bounds__(256) void f32_to_bf16_kernel(
    const float* __restrict__ in, __hip_bfloat16* __restrict__ out, size_t n) {
  for (size_t i = ((size_t)blockIdx.x * 256 + threadIdx.x) * 4; i < n;
       i += (size_t)gridDim.x * 256 * 4) {
    float4 v = *(const float4*)(in + i);
    __hip_bfloat16 h0 = __float2bfloat16(v.x), h1 = __float2bfloat16(v.y);
    __hip_bfloat16 h2 = __float2bfloat16(v.z), h3 = __float2bfloat16(v.w);
    ushort4 u;
    u.x = *(unsigned short*)&h0; u.y = *(unsigned short*)&h1;
    u.z = *(unsigned short*)&h2; u.w = *(unsigned short*)&h3;
    *(ushort4*)(out + i) = u;
  }
}

// -------------------- rmsnorm over 768 (templated output dtype) ------------
template <typename OUT>
__global__ __launch_bounds__(256) void rmsnorm768_kernel(
    const float* __restrict__ in, const float* __restrict__ w,
    OUT* __restrict__ out, float eps) {
  int row = blockIdx.x;
  const float* x = in + (size_t)row * D_MODEL;
  OUT* o = out + (size_t)row * D_MODEL;
  int t = threadIdx.x;
  float v0 = x[t], v1 = x[t + 256], v2 = x[t + 512];
  float ss = v0 * v0 + v1 * v1 + v2 * v2;
  __shared__ float sred[4];
  ss = warp_reduce_sum(ss);
  if ((t & 63) == 0) sred[t >> 6] = ss;
  __syncthreads();
  float tot = sred[0] + sred[1] + sred[2] + sred[3];
  float inv = rsqrtf(tot / (float)D_MODEL + eps);
  store_val(w[t] * v0 * inv, o + t);
  store_val(w[t + 256] * v1 * inv, o + t + 256);
  store_val(w[t + 512] * v2 * inv, o + t + 512);
}

// =========== 128x128 MFMA main-loop macro (BK=32, 4 waves) =================
#define GEMM_PROLOGUE_AND_MAINLOOP(Asrc, Wsrc, Kdim)                           \
  int t = threadIdx.x;                                                         \
  int w = t >> 6, l = t & 63;                                                  \
  int NT = (Kdim) >> 5;                                                        \
  int ldsA0 = (w * 64) * 8;                                                    \
  int ldsA1 = (256 + w * 64) * 8;                                              \
  int lr = l & 15, lk = l >> 4;                                                \
  int wr = w >> 1, wc = w & 1;                                                 \
  int aoff = (lk * 128 + wr * 64 + lr) * 8;                                    \
  int boff = (lk * 128 + wc * 64 + lr) * 8;                                    \
  f32x4 acc[4][4];                                                             \
  _Pragma("unroll") for (int i = 0; i < 4; i++)                                \
      _Pragma("unroll") for (int j = 0; j < 4; j++) acc[i][j] = (f32x4)0.f;    \
  STAGE(0, 0);                                                                 \
  for (int kt = 0; kt < NT; ++kt) {                                            \
    int cur = kt & 1;                                                          \
    if (kt + 1 < NT) {                                                         \
      STAGE(cur ^ 1, (kt + 1) * 32);                                           \
      asm volatile("s_waitcnt vmcnt(4)" ::: "memory");                         \
    } else {                                                                   \
      asm volatile("s_waitcnt vmcnt(0)" ::: "memory");                         \
    }                                                                          \
    __builtin_amdgcn_sched_barrier(0);                                         \
    __builtin_amdgcn_s_barrier();                                              \
    __builtin_amdgcn_sched_barrier(0);                                         \
    bf16x8 av[4], bv[4];                                                       \
    _Pragma("unroll") for (int mi = 0; mi < 4; mi++)                           \
        av[mi] = *(const bf16x8*)&At[cur][aoff + mi * 128];                    \
    _Pragma("unroll") for (int ni = 0; ni < 4; ni++)                           \
        bv[ni] = *(const bf16x8*)&Bt[cur][boff + ni * 128];                    \
    __builtin_amdgcn_s_setprio(1);                                             \
    _Pragma("unroll") for (int mi = 0; mi < 4; mi++)                           \
        _Pragma("unroll") for (int ni = 0; ni < 4; ni++)                       \
            acc[mi][ni] = __builtin_amdgcn_mfma_f32_16x16x32_bf16(             \
                av[mi], bv[ni], acc[mi][ni], 0, 0, 0);                         \
    __builtin_amdgcn_s_setprio(0);                                             \
    __builtin_amdgcn_sched_barrier(0);                                         \
    __builtin_amdgcn_s_barrier();                                              \
  }

#define STAGE(buf, kofs)                                                       \
  do {                                                                         \
    GLL(Aptr + (kofs), &At[buf][ldsA0]);                                       \
    GLL(Aptr + (kofs) + 16, &At[buf][ldsA1]);                                  \
    GLL(Wptr + (kofs), &Bt[buf][ldsA0]);                                       \
    GLL(Wptr + (kofs) + 16, &Bt[buf][ldsA1]);                                  \
  } while (0)

// ===== generic GEMM (128x128): C[M][N](f32) = A * W^T (+res) ===============
__global__ __launch_bounds__(256) void gemm_bf16_kernel(
    const __hip_bfloat16* __restrict__ A, const __hip_bfloat16* __restrict__ W,
    const float* __restrict__ res, float* __restrict__ C,
    int M, int N, int K) {
  __shared__ __bf16 At[2][4096];
  __shared__ __bf16 Bt[2][4096];
  int cpx = gridDim.x >> 3;
  int bid = blockIdx.x;
  int bid2 = (bid & 7) * cpx + (bid >> 3);
  int nbn = (N + 127) >> 7;
  int bn = bid2 % nbn;
  int bm = bid2 / nbn;
  int m0 = bm * 128, n0 = bn * 128;
  int srow = threadIdx.x & 127;
  int kbase = (threadIdx.x >> 7) * 8;
  const __hip_bfloat16* Aptr = A + (size_t)(m0 + srow) * K + kbase;
  int nrow = n0 + srow; if (nrow >= N) nrow = N - 1;
  const __hip_bfloat16* Wptr = W + (size_t)nrow * K + kbase;

  GEMM_PROLOGUE_AND_MAINLOOP(A, W, K)

  int rbase = (l >> 4) * 4;
#pragma unroll
  for (int ni = 0; ni < 4; ni++) {
    int n = n0 + wc * 64 + ni * 16 + (l & 15);
    if (n >= N) continue;
#pragma unroll
    for (int mi = 0; mi < 4; mi++) {
#pragma unroll
      for (int r = 0; r < 4; r++) {
        int m = m0 + wr * 64 + mi * 16 + rbase + r;
        float v = acc[mi][ni][r];
        if (res) v += res[(size_t)m * N + n];
        C[(size_t)m * N + n] = v;
      }
    }
  }
}

// ===== in_proj GEMM: 256x256 tile, 8 waves, BK=64, 2-phase double buffer ===
// Same proven sync skeleton as rounds 5-7 (STAGE next -> counted vmcnt ->
// barrier -> ds_read+MFMA -> barrier); BK=64 halves the barrier count.
__global__ __launch_bounds__(512, 2) void gemm_inproj_kernel(
    const __hip_bfloat16* __restrict__ A, const __hip_bfloat16* __restrict__ W,
    __hip_bfloat16* __restrict__ zout, __hip_bfloat16* __restrict__ xout,
    float* __restrict__ dtout) {
  const int K = D_MODEL, N = D_PROJ;      // 768, 3352; NT = 12 K-tiles of 64
  __shared__ __bf16 At[2][16384];         // [oct(8)][row(256)][8]
  __shared__ __bf16 Bt[2][16384];
  int cpx = gridDim.x >> 3;               // 448/8 = 56
  int bid = blockIdx.x;
  int bid2 = (bid & 7) * cpx + (bid >> 3);
  int bn = bid2 % 14;
  int bm = bid2 / 14;
  int m0 = bm * 256, n0 = bn * 256;
  int t = threadIdx.x;
  int w = t >> 6, l = t & 63;
  int lr = l & 15, lk = l >> 4;
  int wr = w >> 2, wc = w & 3;            // wave grid 2M x 4N; wave = 128x64

  // staging: thread t -> row (t&255), oct-half (t>>8); 4 A + 4 B chunks
  int srow = t & 255;
  int shi = t >> 8;                        // wave-uniform (waves 64-aligned)
  const __hip_bfloat16* Arow = A + (size_t)(m0 + srow) * K;
  int nrow = n0 + srow; if (nrow >= N) nrow = N - 1;
  const __hip_bfloat16* Wrow = W + (size_t)nrow * K;

#define STAGE3(buf, kt)                                                       \
  do {                                                                        \
    _Pragma("unroll") for (int i = 0; i < 4; i++) {                           \
      int oct = 2 * i + shi;                                                  \
      GLL(Arow + (kt) * 64 + oct * 8, &At[buf][(oct * 256 + srow) * 8]);      \
    }                                                                         \
    _Pragma("unroll") for (int i = 0; i < 4; i++) {                           \
      int oct = 2 * i + shi;                                                  \
      GLL(Wrow + (kt) * 64 + oct * 8, &Bt[buf][(oct * 256 + srow) * 8]);      \
    }                                                                         \
  } while (0)

  f32x4 acc[8][4];
#pragma unroll
  for (int i = 0; i < 8; i++)
#pragma unroll
    for (int j = 0; j < 4; j++) acc[i][j] = (f32x4)0.f;

  const int NT = 12;
  STAGE3(0, 0);
  for (int kt = 0; kt < NT; ++kt) {
    int cur = kt & 1;
    if (kt + 1 < NT) {
      STAGE3(cur ^ 1, kt + 1);
      asm volatile("s_waitcnt vmcnt(8)" ::: "memory");
    } else {
      asm volatile("s_waitcnt vmcnt(0)" ::: "memory");
    }
    __builtin_amdgcn_sched_barrier(0);
    __builtin_amdgcn_s_barrier();
    __builtin_amdgcn_sched_barrier(0);
#pragma unroll
    for (int ks = 0; ks < 2; ks++) {
      int ko = ks * 4 + lk;
      bf16x8 av[8], bv[4];
#pragma unroll
      for (int mi = 0; mi < 8; mi++)
        av[mi] = *(const bf16x8*)&At[cur][(ko * 256 + wr * 128 + mi * 16 + lr) * 8];
#pragma unroll
      for (int ni = 0; ni < 4; ni++)
        bv[ni] = *(const bf16x8*)&Bt[cur][(ko * 256 + wc * 64 + ni * 16 + lr) * 8];
      __builtin_amdgcn_s_setprio(1);
#pragma unroll
      for (int mi = 0; mi < 8; mi++)
#pragma unroll
        for (int ni = 0; ni < 4; ni++)
          acc[mi][ni] = __builtin_amdgcn_mfma_f32_16x16x32_bf16(
              av[mi], bv[ni], acc[mi][ni], 0, 0, 0);
      __builtin_amdgcn_s_setprio(0);
    }
    __builtin_amdgcn_sched_barrier(0);
    __builtin_amdgcn_s_barrier();
  }
#undef STAGE3

  int rbase = lk * 4;
  if (bn < 6) {                           // z region
#pragma unroll
    for (int ni = 0; ni < 4; ni++) {
      int n = n0 + wc * 64 + ni * 16 + lr;
#pragma unroll
      for (int mi = 0; mi < 8; mi++)
#pragma unroll
        for (int r = 0; r < 4; r++) {
          int m = m0 + wr * 128 + mi * 16 + rbase + r;
          zout[(size_t)m * D_INNER + n] = __float2bfloat16(acc[mi][ni][r]);
        }
    }
  } else if (bn < 13) {                   // xBC region
    int nb = n0 - D_INNER;
#pragma unroll
    for (int ni = 0; ni < 4; ni++) {
      int n = nb + wc * 64 + ni * 16 + lr;
#pragma unroll
      for (int mi = 0; mi < 8; mi++)
#pragma unroll
        for (int r = 0; r < 4; r++) {
          int m = m0 + wr * 128 + mi * 16 + rbase + r;
          xout[(size_t)m * CONV_DIM + n] = __float2bfloat16(acc[mi][ni][r]);
        }
    }
  } else {                                // dt region: 24 cols
#pragma unroll
    for (int ni = 0; ni < 4; ni++) {
      int loc = wc * 64 + ni * 16 + lr;
      if (loc >= 24) continue;
#pragma unroll
      for (int mi = 0; mi < 8; mi++)
#pragma unroll
        for (int r = 0; r < 4; r++) {
          int m = m0 + wr * 128 + mi * 16 + rbase + r;
          dtout[(size_t)m * 24 + loc] = acc[mi][ni][r];
        }
    }
  }
}

// ======================= chunked SSD (MFMA) ================================
// dt_kernel: softplus + within-chunk inclusive prefix of dt*A (log2-scaled)
__global__ __launch_bounds__(128) void dt_kernel(
    const float* __restrict__ dtraw, const float* __restrict__ dt_bias,
    const float* __restrict__ A_log, float* __restrict__ dtbuf,
    float* __restrict__ cum2buf) {
  int c = blockIdx.x & 15;
  int h = (blockIdx.x >> 4) % NHEADS;
  int b = blockIdx.x / (16 * NHEADS);
  int t = threadIdx.x;
  int s = c * CHUNK + t;
  float Ah = -expf(A_log[h]);
  float raw = dtraw[((size_t)b * SEQ + s) * 24 + h] + dt_bias[h];
  float dt = softplusf(raw);
  __shared__ float sc[128];
  sc[t] = dt * Ah;
  __syncthreads();
  for (int off = 1; off < 128; off <<= 1) {
    float v = (t >= off) ? sc[t - off] : 0.f;
    __syncthreads();
    sc[t] += v;
    __syncthreads();
  }
  size_t o = ((size_t)b * NHEADS + h) * SEQ + s;
  dtbuf[o] = dt;
  cum2buf[o] = sc[t] * LOG2E;
}

// conv_tiles: conv(k=4)+bias+silu once (bf16 input); emit bf16 MFMA tiles.
__global__ __launch_bounds__(256) void conv_tiles_kernel(
    const __hip_bfloat16* __restrict__ xbc, const float* __restrict__ cw,
    const float* __restrict__ cb, __hip_bfloat16* __restrict__ xA,
    __hip_bfloat16* __restrict__ Bkt, __hip_bfloat16* __restrict__ Bkn,
    __hip_bfloat16* __restrict__ Ckn) {
  __shared__ float srows[11 * CONV_DIM];
  int to = blockIdx.x & 15;
  int c  = (blockIdx.x >> 4) & 15;
  int b  = blockIdx.x >> 8;
  int t  = threadIdx.x;
  int sb = c * CHUNK + to * 8;
  const __hip_bfloat16* base = xbc + (size_t)b * SEQ * CONV_DIM;
  for (int e = t; e < 11 * 224; e += 256) {
    int r = e / 224, c8 = (e - r * 224) * 8;
    int s = sb - 3 + r;
    float* dst = &srows[r * CONV_DIM + c8];
    if (s >= 0) {
      bf16x8 v = *(const bf16x8*)&base[(size_t)s * CONV_DIM + c8];
#pragma unroll
      for (int j = 0; j < 8; j++) dst[j] = (float)v[j];
    } else {
#pragma unroll
      for (int j = 0; j < 8; j++) dst[j] = 0.f;
    }
  }
  __syncthreads();
  int bc = b * 16 + c;
#pragma unroll
  for (int k7 = 0; k7 < 7; k7++) {
    int ch = t + k7 * 256;
    float w0 = cw[ch * 4], w1 = cw[ch * 4 + 1];
    float w2 = cw[ch * 4 + 2], w3 = cw[ch * 4 + 3];
    float bias = cb[ch];
    float out[8];
#pragma unroll
    for (int j = 0; j < 8; j++) {
      float a = bias;
      a = fmaf(srows[(j + 0) * CONV_DIM + ch], w0, a);
      a = fmaf(srows[(j + 1) * CONV_DIM + ch], w1, a);
      a = fmaf(srows[(j + 2) * CONV_DIM + ch], w2, a);
      a = fmaf(srows[(j + 3) * CONV_DIM + ch], w3, a);
      out[j] = siluf(a);
    }
    if (ch < D_INNER) {
      int h = ch >> 6, p = ch & 63;
      bf16x8 v;
#pragma unroll
      for (int j = 0; j < 8; j++) v[j] = (__bf16)out[j];
      *(bf16x8*)&xA[((((size_t)bc * 24 + h) * 16 + to) * 64 + p) * 8] = v;
    } else if (ch < D_INNER + D_STATE) {
      int n = ch - D_INNER;
      bf16x8 v;
#pragma unroll
      for (int j = 0; j < 8; j++) v[j] = (__bf16)out[j];
      *(bf16x8*)&Bkt[(((size_t)bc * 16 + to) * 128 + n) * 8] = v;
      __hip_bfloat16* dst = Bkn + (size_t)bc * 16384 + ((n >> 3) * 128) * 8 + (n & 7);
#pragma unroll
      for (int j = 0; j < 8; j++)
        dst[(to * 8 + j) * 8] = __float2bfloat16(out[j]);
    } else {
      int n = ch - D_INNER - D_STATE;
      __hip_bfloat16* dst = Ckn + (size_t)bc * 16384 + ((n >> 3) * 128) * 8 + (n & 7);
#pragma unroll
      for (int j = 0; j < 8; j++)
        dst[(to * 8 + j) * 8] = __float2bfloat16(out[j]);
    }
  }
}

// ssd_state: H[p][n] = sum_tau (wdt[tau]*x[tau][p]) * B[tau][n] via MFMA.
__global__ __launch_bounds__(256) void ssd_state_kernel(
    const __hip_bfloat16* __restrict__ xA, const __hip_bfloat16* __restrict__ Bkt,
    const float* __restrict__ dtbuf, const float* __restrict__ cum2buf,
    __hip_bfloat16* __restrict__ states) {
  __shared__ __bf16 sX[8192];
  __shared__ __bf16 sB[16384];
  __shared__ float swdt[128];
  int c = blockIdx.x & 15;
  int h = (blockIdx.x >> 4) % NHEADS;
  int b = blockIdx.x / (16 * NHEADS);
  int t = threadIdx.x;
  int l = t & 63, w = t >> 6;
  const __hip_bfloat16* xsrc = xA + ((size_t)(b * 16 + c) * 24 + h) * 8192;
  const __hip_bfloat16* bsrc = Bkt + (size_t)(b * 16 + c) * 16384;
#pragma unroll
  for (int i = 0; i < 4; i++) GLL(xsrc + (i * 256 + t) * 8, &sX[(i * 256 + t) * 8]);
#pragma unroll
  for (int i = 0; i < 8; i++) GLL(bsrc + (i * 256 + t) * 8, &sB[(i * 256 + t) * 8]);
  {
    size_t dto = ((size_t)b * NHEADS + h) * SEQ + c * CHUNK;
    if (t < 128) {
      float total2 = cum2buf[dto + 127];
      swdt[t] = dtbuf[dto + t] * exp2f(total2 - cum2buf[dto + t]);
    }
  }
  __syncthreads();
#pragma unroll
  for (int i = 0; i < 4; i++) {
    int o = i * 256 + t;
    int to = o >> 6;
    bf16x8 v = *(bf16x8*)&sX[o * 8];
#pragma unroll
    for (int j = 0; j < 8; j++)
      v[j] = (__bf16)((float)v[j] * swdt[to * 8 + j]);
    *(bf16x8*)&sX[o * 8] = v;
  }
  __syncthreads();
  int n0w = w * 32;
  f32x4 acc[4][2];
#pragma unroll
  for (int i = 0; i < 4; i++)
#pragma unroll
    for (int j = 0; j < 2; j++) acc[i][j] = (f32x4)0.f;
#pragma unroll
  for (int kk = 0; kk < 4; kk++) {
    int ko = kk * 4 + (l >> 4);
    bf16x8 av[4], bv[2];
#pragma unroll
    for (int mi = 0; mi < 4; mi++)
      av[mi] = *(const bf16x8*)&sX[(ko * 64 + mi * 16 + (l & 15)) * 8];
#pragma unroll
    for (int ni = 0; ni < 2; ni++)
      bv[ni] = *(const bf16x8*)&sB[(ko * 128 + n0w + ni * 16 + (l & 15)) * 8];
#pragma unroll
    for (int mi = 0; mi < 4; mi++)
#pragma unroll
      for (int ni = 0; ni < 2; ni++)
        acc[mi][ni] = __builtin_amdgcn_mfma_f32_16x16x32_bf16(
            av[mi], bv[ni], acc[mi][ni], 0, 0, 0);
  }
  __hip_bfloat16* dst = states + (((size_t)b * NHEADS + h) * 16 + c) * 8192;
#pragma unroll
  for (int mi = 0; mi < 4; mi++)
#pragma unroll
    for (int ni = 0; ni < 2; ni++) {
      int n = n0w + ni * 16 + (l & 15);
#pragma unroll
      for (int r = 0; r < 4; r++) {
        int p = mi * 16 + (l >> 4) * 4 + r;
        dst[((n >> 3) * 64 + p) * 8 + (n & 7)] = __float2bfloat16(acc[mi][ni][r]);
      }
    }
}

// chunkscan: in-place exclusive prefix over c (16 steps), bf16 tiles.
__global__ __launch_bounds__(256) void ssd_chunkscan_kernel(
    __hip_bfloat16* __restrict__ states, const float* __restrict__ cum2buf) {
  int q = blockIdx.x & 3;
  int bh = blockIdx.x >> 2;
  int t = threadIdx.x;
  int o = q * 256 + t;
  __hip_bfloat16* base = states + (size_t)bh * NCHUNK * 8192 + (size_t)o * 8;
  const float* c2 = cum2buf + (size_t)bh * SEQ;
  float hacc[8];
#pragma unroll
  for (int j = 0; j < 8; j++) hacc[j] = 0.f;
  for (int c = 0; c < NCHUNK; c++) {
    float eA = exp2f(c2[c * 128 + 127]);
    __hip_bfloat16* p = base + (size_t)c * 8192;
    bf16x8 v = *(bf16x8*)p;
    bf16x8 wv;
#pragma unroll
    for (int j = 0; j < 8; j++) {
      float tmp = (float)v[j];
      wv[j] = (__bf16)hacc[j];
      hacc[j] = fmaf(eA, hacc[j], tmp);
    }
    *(bf16x8*)p = wv;
  }
}

// ssd_output: G = C.B^T -> mask/decay in-register -> Y1 = S.x ; Y2 = C.h^T
__global__ __launch_bounds__(256) void ssd_output_kernel(
    const __hip_bfloat16* __restrict__ Ckn, const __hip_bfloat16* __restrict__ Bkn,
    const __hip_bfloat16* __restrict__ xA, const __hip_bfloat16* __restrict__ states,
    const float* __restrict__ dtbuf, const float* __restrict__ cum2buf,
    const float* __restrict__ D_skip, __hip_bfloat16* __restrict__ y) {
  __shared__ __bf16 sC[16384];
  __shared__ __bf16 sBS[16384];
  __shared__ __bf16 sXH[8192];
  int c = blockIdx.x & 15;
  int h = (blockIdx.x >> 4) % NHEADS;
  int b = blockIdx.x / (16 * NHEADS);
  int t = threadIdx.x;
  int l = t & 63, w = t >> 6;
  int bc = b * 16 + c;
  const __hip_bfloat16* csrc = Ckn + (size_t)bc * 16384;
  const __hip_bfloat16* bsrc = Bkn + (size_t)bc * 16384;
  const __hip_bfloat16* xsrc = xA + ((size_t)bc * 24 + h) * 8192;
#pragma unroll
  for (int i = 0; i < 8; i++) GLL(csrc + (i * 256 + t) * 8, &sC[(i * 256 + t) * 8]);
#pragma unroll
  for (int i = 0; i < 8; i++) GLL(bsrc + (i * 256 + t) * 8, &sBS[(i * 256 + t) * 8]);
#pragma unroll
  for (int i = 0; i < 4; i++) GLL(xsrc + (i * 256 + t) * 8, &sXH[(i * 256 + t) * 8]);

  size_t dto = ((size_t)b * NHEADS + h) * SEQ + c * CHUNK;
  float cum2_t[8], cum2_tau[8], dt_tau[8];
#pragma unroll
  for (int fm = 0; fm < 2; fm++)
#pragma unroll
    for (int r = 0; r < 4; r++)
      cum2_t[fm * 4 + r] = cum2buf[dto + w * 32 + fm * 16 + (l >> 4) * 4 + r];
#pragma unroll
  for (int fc = 0; fc < 8; fc++) {
    cum2_tau[fc] = cum2buf[dto + fc * 16 + (l & 15)];
    dt_tau[fc] = dtbuf[dto + fc * 16 + (l & 15)];
  }
  float Dh = D_skip[h];
  __syncthreads();

  f32x4 g[2][8];
#pragma unroll
  for (int i = 0; i < 2; i++)
#pragma unroll
    for (int j = 0; j < 8; j++) g[i][j] = (f32x4)0.f;
#pragma unroll
  for (int kk = 0; kk < 4; kk++) {
    int ko = kk * 4 + (l >> 4);
    bf16x8 a0 = *(const bf16x8*)&sC[(ko * 128 + w * 32 + (l & 15)) * 8];
    bf16x8 a1 = *(const bf16x8*)&sC[(ko * 128 + w * 32 + 16 + (l & 15)) * 8];
#pragma unroll
    for (int fc = 0; fc < 8; fc++) {
      bf16x8 bv = *(const bf16x8*)&sBS[(ko * 128 + fc * 16 + (l & 15)) * 8];
      g[0][fc] = __builtin_amdgcn_mfma_f32_16x16x32_bf16(a0, bv, g[0][fc], 0, 0, 0);
      g[1][fc] = __builtin_amdgcn_mfma_f32_16x16x32_bf16(a1, bv, g[1][fc], 0, 0, 0);
    }
  }
  __syncthreads();  // all waves done reading B before S overwrites it

#pragma unroll
  for (int fm = 0; fm < 2; fm++)
#pragma unroll
    for (int fc = 0; fc < 8; fc++) {
      int tau = fc * 16 + (l & 15);
#pragma unroll
      for (int r = 0; r < 4; r++) {
        int tt = w * 32 + fm * 16 + (l >> 4) * 4 + r;
        float v = 0.f;
        if (tt >= tau) {
          v = exp2f(cum2_t[fm * 4 + r] - cum2_tau[fc]) * dt_tau[fc] * g[fm][fc][r];
          if (tt == tau) v += Dh;
        }
        sBS[((tau >> 3) * 128 + tt) * 8 + (tau & 7)] = (__bf16)v;
      }
    }
  f32x4 y1[2][4];
#pragma unroll
  for (int i = 0; i < 2; i++)
#pragma unroll
    for (int j = 0; j < 4; j++) y1[i][j] = (f32x4)0.f;
#pragma unroll
  for (int kk = 0; kk < 4; kk++) {
    int ko = kk * 4 + (l >> 4);
    bf16x8 a0 = *(const bf16x8*)&sBS[(ko * 128 + w * 32 + (l & 15)) * 8];
    bf16x8 a1 = *(const bf16x8*)&sBS[(ko * 128 + w * 32 + 16 + (l & 15)) * 8];
#pragma unroll
    for (int fc = 0; fc < 4; fc++) {
      bf16x8 bv = *(const bf16x8*)&sXH[(ko * 64 + fc * 16 + (l & 15)) * 8];
      y1[0][fc] = __builtin_amdgcn_mfma_f32_16x16x32_bf16(a0, bv, y1[0][fc], 0, 0, 0);
      y1[1][fc] = __builtin_amdgcn_mfma_f32_16x16x32_bf16(a1, bv, y1[1][fc], 0, 0, 0);
    }
  }
  __syncthreads();  // all waves done with x before h_prev overwrites it
  const __hip_bfloat16* hsrc = states + (((size_t)b * NHEADS + h) * 16 + c) * 8192;
#pragma unroll
  for (int i = 0; i < 4; i++) GLL(hsrc + (i * 256 + t) * 8, &sXH[(i * 256 + t) * 8]);
  __syncthreads();

  f32x4 y2[2][4];
#pragma unroll
  for (int i = 0; i < 2; i++)
#pragma unroll
    for (int j = 0; j < 4; j++) y2[i][j] = (f32x4)0.f;
#pragma unroll
  for (int kk = 0; kk < 4; kk++) {
    int ko = kk * 4 + (l >> 4);
    bf16x8 a0 = *(const bf16x8*)&sC[(ko * 128 + w * 32 + (l & 15)) * 8];
    bf16x8 a1 = *(const bf16x8*)&sC[(ko * 128 + w * 32 + 16 + (l & 15)) * 8];
#pragma unroll
    for (int fc = 0; fc < 4; fc++) {
      bf16x8 bv = *(const bf16x8*)&sXH[(ko * 64 + fc * 16 + (l & 15)) * 8];
      y2[0][fc] = __builtin_amdgcn_mfma_f32_16x16x32_bf16(a0, bv, y2[0][fc], 0, 0, 0);
      y2[1][fc] = __builtin_amdgcn_mfma_f32_16x16x32_bf16(a1, bv, y2[1][fc], 0, 0, 0);
    }
  }

  __hip_bfloat16* yr = y + ((size_t)b * SEQ + c * CHUNK) * D_INNER + h * 64;
#pragma unroll
  for (int fm = 0; fm < 2; fm++)
#pragma unroll
    for (int r = 0; r < 4; r++) {
      int tt = w * 32 + fm * 16 + (l >> 4) * 4 + r;
      float sdec = exp2f(cum2_t[fm * 4 + r]);
#pragma unroll
      for (int fc = 0; fc < 4; fc++) {
        int p = fc * 16 + (l & 15);
        yr[(size_t)tt * D_INNER + p] =
            __float2bfloat16(y1[fm][fc][r] + sdec * y2[fm][fc][r]);
      }
    }
}

// ---- y(bf16) * silu(z bf16) then rmsnorm(1536); 192 thr, bf16x8 ----------
__global__ __launch_bounds__(192) void gate_norm_kernel(
    __hip_bfloat16* __restrict__ y, const __hip_bfloat16* __restrict__ z,
    const float* __restrict__ gw) {
  int row = blockIdx.x;
  const __hip_bfloat16* zr = z + (size_t)row * D_INNER;
  __hip_bfloat16* yr = y + (size_t)row * D_INNER;
  int t = threadIdx.x;
  bf16x8 yv = *(const bf16x8*)&yr[t * 8];
  bf16x8 zv = *(const bf16x8*)&zr[t * 8];
  float vals[8];
  float ss = 0.f;
#pragma unroll
  for (int j = 0; j < 8; j++) {
    float zf = (float)zv[j];
    float v = (float)yv[j] * siluf(zf);
    vals[j] = v;
    ss += v * v;
  }
  __shared__ float sred[3];
  ss = warp_reduce_sum(ss);
  if ((t & 63) == 0) sred[t >> 6] = ss;
  __syncthreads();
  float tot = sred[0] + sred[1] + sred[2];
  float inv = rsqrtf(tot / (float)D_INNER + 1e-5f);
  bf16x8 o;
#pragma unroll
  for (int j = 0; j < 8; j++)
    o[j] = (__bf16)(gw[t * 8 + j] * vals[j] * inv);
  *(bf16x8*)&yr[t * 8] = o;
}

// ---------------------------------------------------------------------------
extern "C" void kernel_launch(void* const* d_in, const int* in_sizes, int n_in,
                              void* d_out, int out_size, void* d_ws, size_t ws_size,
                              hipStream_t stream) {
  const float* x          = (const float*)d_in[0];
  const float* in_proj_w  = (const float*)d_in[1];
  const float* conv_w     = (const float*)d_in[2];
  const float* conv_b     = (const float*)d_in[3];
  const float* dt_bias    = (const float*)d_in[4];
  const float* A_log      = (const float*)d_in[5];
  const float* D_skip     = (const float*)d_in[6];
  const float* gnorm_w    = (const float*)d_in[7];
  const float* out_proj_w = (const float*)d_in[8];
  const float* ln_w       = (const float*)d_in[9];
  const float* final_ln_w = (const float*)d_in[10];

  // ws total ~206 MB
  float* ws = (float*)d_ws;
  float* curx   = ws; ws += (size_t)NROWS * D_MODEL;           // 25.2 MB
  float* dtraw  = ws; ws += (size_t)NROWS * 24;                // 0.8
  float* dtbuf  = ws; ws += (size_t)BATCH * NHEADS * SEQ;      // 0.8
  float* cum2   = ws; ws += (size_t)BATCH * NHEADS * SEQ;      // 0.8
  __hip_bfloat16* zbuf   = (__hip_bfloat16*)ws; ws += (size_t)NROWS * D_INNER / 2;   // 25.2
  __hip_bfloat16* xbcbuf = (__hip_bfloat16*)ws; ws += (size_t)NROWS * CONV_DIM / 2;  // 29.4
  __hip_bfloat16* hbuf_b = (__hip_bfloat16*)ws; ws += (size_t)NROWS * D_MODEL / 2;   // 12.6
  __hip_bfloat16* ybuf_b = (__hip_bfloat16*)ws; ws += (size_t)NROWS * D_INNER / 2;   // 25.2
  __hip_bfloat16* wi_b   = (__hip_bfloat16*)ws; ws += (size_t)NUM_LAYERS * D_PROJ * D_MODEL / 2;   // 20.6
  __hip_bfloat16* wo_b   = (__hip_bfloat16*)ws; ws += (size_t)NUM_LAYERS * D_MODEL * D_INNER / 2;  // 9.4
  __hip_bfloat16* xAb    = (__hip_bfloat16*)ws; ws += (size_t)BATCH * NCHUNK * 24 * 8192 / 2; // 25.2
  __hip_bfloat16* Bkt    = (__hip_bfloat16*)ws; ws += (size_t)BATCH * NCHUNK * 16384 / 2;     // 2.1
  __hip_bfloat16* Bkn    = (__hip_bfloat16*)ws; ws += (size_t)BATCH * NCHUNK * 16384 / 2;     // 2.1
  __hip_bfloat16* Ckn    = (__hip_bfloat16*)ws; ws += (size_t)BATCH * NCHUNK * 16384 / 2;     // 2.1
  __hip_bfloat16* states = (__hip_bfloat16*)ws;                                               // 25.2

  f32_to_bf16_kernel<<<1024, 256, 0, stream>>>(
      in_proj_w, wi_b, (size_t)NUM_LAYERS * D_PROJ * D_MODEL);
  f32_to_bf16_kernel<<<1024, 256, 0, stream>>>(
      out_proj_w, wo_b, (size_t)NUM_LAYERS * D_MODEL * D_INNER);

  for (int l = 0; l < NUM_LAYERS; l++) {
    const float* xin = (l == 0) ? x : curx;
    rmsnorm768_kernel<__hip_bfloat16><<<NROWS, 256, 0, stream>>>(
        xin, ln_w + (size_t)l * D_MODEL, hbuf_b, 1e-6f);

    gemm_inproj_kernel<<<448, 512, 0, stream>>>(
        hbuf_b, wi_b + (size_t)l * D_PROJ * D_MODEL, zbuf, xbcbuf, dtraw);

    dt_kernel<<<BATCH * NHEADS * NCHUNK, 128, 0, stream>>>(
        dtraw, dt_bias + l * NHEADS, A_log + l * NHEADS, dtbuf, cum2);

    conv_tiles_kernel<<<BATCH * NCHUNK * 16, 256, 0, stream>>>(
        xbcbuf, conv_w + (size_t)l * CONV_DIM * D_CONV,
        conv_b + (size_t)l * CONV_DIM, xAb, Bkt, Bkn, Ckn);

    ssd_state_kernel<<<BATCH * NHEADS * NCHUNK, 256, 0, stream>>>(
        xAb, Bkt, dtbuf, cum2, states);

    ssd_chunkscan_kernel<<<BATCH * NHEADS * 4, 256, 0, stream>>>(states, cum2);

    ssd_output_kernel<<<BATCH * NHEADS * NCHUNK, 256, 0, stream>>>(
        Ckn, Bkn, xAb, states, dtbuf, cum2, D_skip + l * NHEADS, ybuf_b);

    gate_norm_kernel<<<NROWS, 192, 0, stream>>>(
        ybuf_b, zbuf, gnorm_w + (size_t)l * D_INNER);

    gemm_bf16_kernel<<<64 * 6, 256, 0, stream>>>(
        ybuf_b, wo_b + (size_t)l * D_MODEL * D_INNER, xin, curx,
        NROWS, D_MODEL, D_INNER);
  }
  rmsnorm768_kernel<float><<<NROWS, 256, 0, stream>>>(
      curx, final_ln_w, (float*)d_out, 1e-6f);
}